// Round 2
// baseline (2556.280 us; speedup 1.0000x reference)
//
#include <hip/hip_runtime.h>

typedef float f4 __attribute__((ext_vector_type(4)));
typedef float f32x4 __attribute__((ext_vector_type(4)));
typedef unsigned short us8 __attribute__((ext_vector_type(8)));
typedef __bf16 bf8 __attribute__((ext_vector_type(8)));

static constexpr int B_ = 2, S_ = 1024, H_ = 2048, T_ = B_ * S_;
static constexpr int NH_ = 16, DN_ = 128, DR_ = 64, DV_ = 128, DQK_ = 192;
static constexpr int KVL_ = 512, QL_ = 1536, INTER_ = 768, NEXP_ = 8;
static constexpr float SCALING_ = 0.07216878364870322f; // 192^-0.5
static constexpr float EPS_ = 1e-6f;

__device__ __forceinline__ unsigned short f2bf(float f) {
    unsigned u = __float_as_uint(f);
    u += 0x7fffu + ((u >> 16) & 1u);
    return (unsigned short)(u >> 16);
}
__device__ __forceinline__ float bf2f(unsigned short h) {
    return __uint_as_float(((unsigned)h) << 16);
}
__device__ __forceinline__ us8 pack8(f4 a, f4 b) {
    us8 r;
    r[0] = f2bf(a[0]); r[1] = f2bf(a[1]); r[2] = f2bf(a[2]); r[3] = f2bf(a[3]);
    r[4] = f2bf(b[0]); r[5] = f2bf(b[1]); r[6] = f2bf(b[2]); r[7] = f2bf(b[3]);
    return r;
}

// ---------------------------------------------------------------------------
// Generic MFMA GEMM: C[M,N] = A[M,K] * B[N,K]^T   (all row-major)
// A/B fp32 (converted to bf16 in LDS staging) or bf16(ushort).
// Requires M%128==0, N%64==0, K%32==0 (all call sites comply).
// Epilogue (checked in order):
//   perm_bh0 >= 0   : attention store -> C[(b*S+row)*H + h*DV + col] = acc
//                     with bh = perm_bh0 + blockIdx.z, b=bh>>4, h=bh&15
//   Cb != null      : bf16 store
//   rowscale != null: C[idx] += rowscale[row*rs_stride] * acc   (MoE down)
//   add != null     : C[idx] = acc + add[idx]                   (residual)
//   else            : C[idx] = acc
// ---------------------------------------------------------------------------
template <int AF32, int BF32>
__global__ __launch_bounds__(256, 2) void gemm_bt(
    const void* __restrict__ Av, const void* __restrict__ Bv,
    float* __restrict__ C, unsigned short* __restrict__ Cb,
    const float* __restrict__ add, const float* __restrict__ rowscale, int rs_stride,
    int perm_bh0, int M, int N, int K, long sA, long sB, long sC)
{
    constexpr int BM = 128, BN = 64, BK = 32;
    __shared__ __align__(16) unsigned short As[BM][BK + 8];
    __shared__ __align__(16) unsigned short Bs[BN][BK + 8];
    const int tid = threadIdx.x;
    const int lane = tid & 63, wv = tid >> 6;
    const int wm = (wv >> 1) * 64, wn = (wv & 1) * 32;
    const int m0 = blockIdx.x * BM, n0 = blockIdx.y * BN;
    const long zA = (long)blockIdx.z * sA;
    const long zB = (long)blockIdx.z * sB;
    const long zC = (long)blockIdx.z * sC;
    const int ar = tid >> 1, ac = (tid & 1) * 16; // A: 2 thr/row, 16 cols each
    const int br = tid >> 2, bc = (tid & 3) * 8;  // B: 4 thr/row, 8 cols each

    f32x4 acc[4][2];
#pragma unroll
    for (int m = 0; m < 4; m++) {
        acc[m][0] = f32x4{0.f, 0.f, 0.f, 0.f};
        acc[m][1] = f32x4{0.f, 0.f, 0.f, 0.f};
    }

    for (int k0 = 0; k0 < K; k0 += BK) {
        if constexpr (AF32) {
            const float* src = (const float*)Av + zA + (long)(m0 + ar) * K + (k0 + ac);
            const f4* p = (const f4*)src;
            f4 v0 = p[0], v1 = p[1], v2 = p[2], v3 = p[3];
            *(us8*)&As[ar][ac]     = pack8(v0, v1);
            *(us8*)&As[ar][ac + 8] = pack8(v2, v3);
        } else {
            const unsigned short* src = (const unsigned short*)Av + zA + (long)(m0 + ar) * K + (k0 + ac);
            const us8* p = (const us8*)src;
            *(us8*)&As[ar][ac]     = p[0];
            *(us8*)&As[ar][ac + 8] = p[1];
        }
        if constexpr (BF32) {
            const float* src = (const float*)Bv + zB + (long)(n0 + br) * K + (k0 + bc);
            const f4* p = (const f4*)src;
            *(us8*)&Bs[br][bc] = pack8(p[0], p[1]);
        } else {
            const unsigned short* src = (const unsigned short*)Bv + zB + (long)(n0 + br) * K + (k0 + bc);
            *(us8*)&Bs[br][bc] = *(const us8*)src;
        }
        __syncthreads();

        const int fr = lane & 15, ko = (lane >> 4) * 8;
        bf8 af[4], bfr[2];
#pragma unroll
        for (int m = 0; m < 4; m++) af[m] = *(const bf8*)&As[wm + m * 16 + fr][ko];
#pragma unroll
        for (int n = 0; n < 2; n++) bfr[n] = *(const bf8*)&Bs[wn + n * 16 + fr][ko];
#pragma unroll
        for (int m = 0; m < 4; m++)
#pragma unroll
            for (int n = 0; n < 2; n++)
                acc[m][n] = __builtin_amdgcn_mfma_f32_16x16x32_bf16(af[m], bfr[n], acc[m][n], 0, 0, 0);
        __syncthreads();
    }

#pragma unroll
    for (int m = 0; m < 4; m++) {
#pragma unroll
        for (int n = 0; n < 2; n++) {
#pragma unroll
            for (int i = 0; i < 4; i++) {
                int row = m0 + wm + m * 16 + (lane >> 4) * 4 + i;
                int col = n0 + wn + n * 16 + (lane & 15);
                float v = acc[m][n][i];
                if (perm_bh0 >= 0) {
                    int bh = perm_bh0 + blockIdx.z;
                    int b = bh >> 4, h = bh & 15;
                    C[((long)(b * S_ + row)) * H_ + h * DV_ + col] = v;
                } else {
                    long idx = zC + (long)row * N + col;
                    if (Cb) {
                        Cb[idx] = f2bf(v);
                    } else if (rowscale) {
                        C[idx] += rowscale[(long)row * rs_stride] * v;
                    } else if (add) {
                        C[idx] = v + add[idx];
                    } else {
                        C[idx] = v;
                    }
                }
            }
        }
    }
}

// ---------------------------------------------------------------------------
// RMSNorm: out[r, :cols] = in[r, :cols] * rsqrt(mean(in^2)+eps) * w
// istride/ostride allow reading/writing a prefix of a wider row, and
// in == out (in-place) is safe: each element is read before written by
// the same thread.
// ---------------------------------------------------------------------------
__global__ __launch_bounds__(256) void rmsnorm_k(
    const float* __restrict__ in, const float* __restrict__ w,
    float* __restrict__ out, int cols, int istride, int ostride)
{
    const long ib = (long)blockIdx.x * istride;
    const long ob = (long)blockIdx.x * ostride;
    float ss = 0.f;
    for (int c = threadIdx.x; c < cols; c += 256) {
        float v = in[ib + c];
        ss += v * v;
    }
#pragma unroll
    for (int o = 32; o; o >>= 1) ss += __shfl_down(ss, o);
    __shared__ float red[4];
    if ((threadIdx.x & 63) == 0) red[threadIdx.x >> 6] = ss;
    __syncthreads();
    float tot = red[0] + red[1] + red[2] + red[3];
    float r = rsqrtf(tot / cols + EPS_);
    for (int c = threadIdx.x; c < cols; c += 256) out[ob + c] = in[ib + c] * r * w[c];
}

// ---------------------------------------------------------------------------
// RoPE for q: q (B,S,NH,192) fp32 -> qs (B,NH,S,192) bf16
// ---------------------------------------------------------------------------
__global__ __launch_bounds__(64) void rope_q_k(
    const float* __restrict__ q, const float* __restrict__ cs, const float* __restrict__ sn,
    unsigned short* __restrict__ qs)
{
    int t = blockIdx.x;            // (b*S+s)*16 + h
    int h = t & 15;
    int bs = t >> 4;               // b*S+s
    int s = bs & (S_ - 1);
    int b = bs >> 10;
    const float* qrow = q + (long)bs * (NH_ * DQK_) + h * DQK_;
    unsigned short* orow = qs + ((long)(b * NH_ + h) * S_ + s) * DQK_;
    int l = threadIdx.x;
    orow[l] = f2bf(qrow[l]);
    orow[l + 64] = f2bf(qrow[l + 64]);
    const float* cr = cs + (long)bs * DR_;
    const float* sr = sn + (long)bs * DR_;
    int j = l & 31;
    float x0 = qrow[DN_ + 2 * j], x1 = qrow[DN_ + 2 * j + 1];
    float c = cr[j], si = sr[j];
    if (l < 32) orow[DN_ + j] = f2bf(x0 * c - x1 * si);
    else        orow[DN_ + 32 + j] = f2bf(x1 * c + x0 * si);
}

// RoPE for k: ckv[:,512:576] -> broadcast roped k_rot into all 16 heads of ks
__global__ __launch_bounds__(64) void rope_k_k(
    const float* __restrict__ ckv, const float* __restrict__ cs, const float* __restrict__ sn,
    unsigned short* __restrict__ ks)
{
    int bs = blockIdx.x;
    int s = bs & (S_ - 1);
    int b = bs >> 10;
    const float* kr = ckv + (long)bs * 576 + KVL_;
    int l = threadIdx.x;
    int j = l & 31;
    float x0 = kr[2 * j], x1 = kr[2 * j + 1];
    float c = cs[(long)bs * DR_ + j], si = sn[(long)bs * DR_ + j];
    float val = (l < 32) ? (x0 * c - x1 * si) : (x1 * c + x0 * si);
    int off = (l < 32) ? (DN_ + j) : (DN_ + 32 + j);
    unsigned short bv = f2bf(val);
    for (int h = 0; h < NH_; h++)
        ks[((long)(b * NH_ + h) * S_ + s) * DQK_ + off] = bv;
}

// k_pass: kv (B,S,NH,256)[:, :128] -> ks (B,NH,S,192)[:, :128]
__global__ __launch_bounds__(128) void kpass_k(
    const float* __restrict__ kv, unsigned short* __restrict__ ks)
{
    int t = blockIdx.x; // (b*S+s)*16 + h
    int h = t & 15;
    int bs = t >> 4;
    int s = bs & (S_ - 1);
    int b = bs >> 10;
    ks[((long)(b * NH_ + h) * S_ + s) * DQK_ + threadIdx.x] = f2bf(kv[(long)t * 256 + threadIdx.x]);
}

// V transpose: kv (B,S,NH,256)[:,128:] -> vt (B,NH,DV,S) bf16
__global__ __launch_bounds__(256) void vt_k(
    const float* __restrict__ kv, unsigned short* __restrict__ vt)
{
    __shared__ unsigned short tile[64][DV_ + 8];
    int s0 = blockIdx.x * 64;
    int bh = blockIdx.y;
    int b = bh >> 4, h = bh & 15;
    for (int it = 0; it < 32; it++) {
        int idx = it * 256 + threadIdx.x;
        int sl = idx >> 7, d = idx & 127;
        float v = kv[((long)(b * S_ + s0 + sl) * NH_ + h) * 256 + DN_ + d];
        tile[sl][d] = f2bf(v);
    }
    __syncthreads();
    for (int it = 0; it < 32; it++) {
        int idx = it * 256 + threadIdx.x;
        int d = idx >> 6, sl = idx & 63;
        vt[((long)bh * DV_ + d) * S_ + s0 + sl] = tile[sl][d];
    }
}

// causal softmax in-place on bf16 scores rows (applies SCALING_)
__global__ __launch_bounds__(256) void softmax_k(unsigned short* __restrict__ p)
{
    long row = blockIdx.x;          // bh_local*S + q
    int q = (int)(row & (S_ - 1));
    unsigned short* pr = p + row * S_;
    float v[4];
    float mx = -3e38f;
#pragma unroll
    for (int i = 0; i < 4; i++) {
        int k = threadIdx.x + i * 256;
        float val = (k <= q) ? bf2f(pr[k]) * SCALING_ : -3e38f;
        v[i] = val;
        mx = fmaxf(mx, val);
    }
#pragma unroll
    for (int o = 32; o; o >>= 1) mx = fmaxf(mx, __shfl_down(mx, o));
    __shared__ float red[4];
    if ((threadIdx.x & 63) == 0) red[threadIdx.x >> 6] = mx;
    __syncthreads();
    mx = fmaxf(fmaxf(red[0], red[1]), fmaxf(red[2], red[3]));
    float sum = 0.f;
#pragma unroll
    for (int i = 0; i < 4; i++) {
        float e = (v[i] > -1e38f) ? __expf(v[i] - mx) : 0.f;
        v[i] = e;
        sum += e;
    }
#pragma unroll
    for (int o = 32; o; o >>= 1) sum += __shfl_down(sum, o);
    __syncthreads();
    if ((threadIdx.x & 63) == 0) red[threadIdx.x >> 6] = sum;
    __syncthreads();
    sum = red[0] + red[1] + red[2] + red[3];
    float inv = 1.f / sum;
#pragma unroll
    for (int i = 0; i < 4; i++) {
        int k = threadIdx.x + i * 256;
        pr[k] = f2bf(v[i] * inv);
    }
}

// router: dots + sigmoid + group-top2 + expert-top2 -> dense weights w8 (T,8)
__global__ __launch_bounds__(64) void router_k(
    const float* __restrict__ h, const float* __restrict__ rw,
    const float* __restrict__ rb, float* __restrict__ w8)
{
    int t = blockIdx.x;
    int l = threadIdx.x;
    const float* hr = h + (long)t * H_;
    float pe[8] = {0, 0, 0, 0, 0, 0, 0, 0};
    for (int k = l; k < H_; k += 64) {
        float hv = hr[k];
#pragma unroll
        for (int e = 0; e < 8; e++) pe[e] += hv * rw[e * H_ + k];
    }
#pragma unroll
    for (int e = 0; e < 8; e++)
        for (int o = 32; o; o >>= 1) pe[e] += __shfl_down(pe[e], o);
    if (l == 0) {
        float sr[8], sc[8];
#pragma unroll
        for (int e = 0; e < 8; e++) {
            sr[e] = 1.f / (1.f + __expf(-pe[e]));
            sc[e] = sr[e] + rb[e];
        }
        float gs[4];
        for (int g = 0; g < 4; g++) gs[g] = sc[2 * g] + sc[2 * g + 1];
        int g0 = 0;
        for (int g = 1; g < 4; g++) if (gs[g] > gs[g0]) g0 = g;
        int g1 = -1;
        for (int g = 0; g < 4; g++) {
            if (g == g0) continue;
            if (g1 < 0 || gs[g] > gs[g1]) g1 = g;
        }
        int i0 = -1, i1 = -1;
        for (int e = 0; e < 8; e++) {
            int g = e >> 1;
            if (g != g0 && g != g1) continue;
            if (i0 < 0 || sc[e] > sc[i0]) i0 = e;
        }
        for (int e = 0; e < 8; e++) {
            int g = e >> 1;
            if (g != g0 && g != g1) continue;
            if (e == i0) continue;
            if (i1 < 0 || sc[e] > sc[i1]) i1 = e;
        }
        float w0 = sr[i0], w1 = sr[i1];
        float inv = 2.5f / (w0 + w1 + 1e-20f);
#pragma unroll
        for (int e = 0; e < 8; e++) w8[(long)t * 8 + e] = 0.f;
        w8[(long)t * 8 + i0] = w0 * inv;
        w8[(long)t * 8 + i1] = w1 * inv;
    }
}

__global__ __launch_bounds__(256) void silumul_k(
    const float* __restrict__ g, const float* __restrict__ u,
    float* __restrict__ o, int n)
{
    int i = blockIdx.x * 256 + threadIdx.x;
    if (i < n) {
        float x = g[i];
        float s = x / (1.f + __expf(-x));
        o[i] = s * u[i];
    }
}

// ---------------------------------------------------------------------------
extern "C" void kernel_launch(void* const* d_in, const int* in_sizes, int n_in,
                              void* d_out, int out_size, void* d_ws, size_t ws_size,
                              hipStream_t stream)
{
    const float* hidden = (const float*)d_in[0];
    const float* cosb   = (const float*)d_in[1];
    const float* sinb   = (const float*)d_in[2];
    const float* ln1w   = (const float*)d_in[3];
    const float* qaw    = (const float*)d_in[4];
    const float* qalnw  = (const float*)d_in[5];
    const float* qbw    = (const float*)d_in[6];
    const float* kvaw   = (const float*)d_in[7];
    const float* kvalnw = (const float*)d_in[8];
    const float* kvbw   = (const float*)d_in[9];
    const float* ow     = (const float*)d_in[10];
    const float* ln2w   = (const float*)d_in[11];
    const float* rw     = (const float*)d_in[12];
    const float* rb     = (const float*)d_in[13];
    const float* gw     = (const float*)d_in[14];
    const float* uw     = (const float*)d_in[15];
    const float* dwn    = (const float*)d_in[16];
    const float* sgw    = (const float*)d_in[17];
    const float* suw    = (const float*)d_in[18];
    const float* sdw    = (const float*)d_in[19];
    float* out = (float*)d_out;
    (void)in_sizes; (void)n_in; (void)out_size; (void)ws_size;

    // ---- static workspace plan (peak 105 MB), alias-checked by liveness ----
    // [0,16)   x        (dead after kv_a GEMM)      -> vt [0,8), w8 [8,9), ge [9,15)
    // [16,28)  qa       (in-place norm; dead after q_b GEMM) -> qs, later ue/act
    // [28,52)  q        (dead after rope_q)         -> pr [28,44), ab tail
    // [52,57)  ckv      (dead after rope_k)         -> ab
    // [57,61)  ckvn     (dead after kv_b GEMM)      -> ab
    // [61,93)  kv       (dead after kpass/vt)       -> x2 [61,77), hbuf [77,93)
    // [93,105) ks       (dead after attention)
    char* ws = (char*)d_ws;
    const size_t MB = 1u << 20;
    float* x    = (float*)(ws + 0 * MB);
    float* qa   = (float*)(ws + 16 * MB);
    float* q    = (float*)(ws + 28 * MB);
    float* ckv  = (float*)(ws + 52 * MB);
    float* ckvn = (float*)(ws + 57 * MB);
    float* kv   = (float*)(ws + 61 * MB);
    unsigned short* qs = (unsigned short*)(ws + 16 * MB);
    unsigned short* ks = (unsigned short*)(ws + 93 * MB);
    unsigned short* vt = (unsigned short*)(ws + 0 * MB);
    unsigned short* pr = (unsigned short*)(ws + 28 * MB);
    float* ab   = (float*)(ws + 44 * MB);
    float* x2   = (float*)(ws + 61 * MB);
    float* hbuf = (float*)(ws + 77 * MB);
    float* w8   = (float*)(ws + 8 * MB);
    float* ge   = (float*)(ws + 9 * MB);
    float* ue   = (float*)(ws + 16 * MB);
    float* act  = (float*)(ws + 22 * MB);

    // ---- attention input projections ----
    rmsnorm_k<<<T_, 256, 0, stream>>>(hidden, ln1w, x, H_, H_, H_);

    gemm_bt<1, 1><<<dim3(T_ / 128, QL_ / 64, 1), 256, 0, stream>>>(
        x, qaw, qa, nullptr, nullptr, nullptr, 0, -1, T_, QL_, H_, 0, 0, 0);
    rmsnorm_k<<<T_, 256, 0, stream>>>(qa, qalnw, qa, QL_, QL_, QL_);
    gemm_bt<1, 1><<<dim3(T_ / 128, (NH_ * DQK_) / 64, 1), 256, 0, stream>>>(
        qa, qbw, q, nullptr, nullptr, nullptr, 0, -1, T_, NH_ * DQK_, QL_, 0, 0, 0);

    gemm_bt<1, 1><<<dim3(T_ / 128, 576 / 64, 1), 256, 0, stream>>>(
        x, kvaw, ckv, nullptr, nullptr, nullptr, 0, -1, T_, 576, H_, 0, 0, 0);
    rmsnorm_k<<<T_, 256, 0, stream>>>(ckv, kvalnw, ckvn, KVL_, 576, KVL_);
    gemm_bt<1, 1><<<dim3(T_ / 128, (NH_ * 256) / 64, 1), 256, 0, stream>>>(
        ckvn, kvbw, kv, nullptr, nullptr, nullptr, 0, -1, T_, NH_ * 256, KVL_, 0, 0, 0);

    // ---- assemble qs / ks / vt ----
    rope_q_k<<<T_ * NH_, 64, 0, stream>>>(q, cosb, sinb, qs);
    rope_k_k<<<T_, 64, 0, stream>>>(ckv, cosb, sinb, ks);
    kpass_k<<<T_ * NH_, 128, 0, stream>>>(kv, ks);
    vt_k<<<dim3(S_ / 64, B_ * NH_), 256, 0, stream>>>(kv, vt);

    // ---- attention: 4 chunks of 8 heads (pr chunk = 16 MB) ----
    for (int c = 0; c < 4; c++) {
        const unsigned short* qs_c = qs + (long)c * 8 * S_ * DQK_;
        const unsigned short* ks_c = ks + (long)c * 8 * S_ * DQK_;
        const unsigned short* vt_c = vt + (long)c * 8 * DV_ * S_;
        gemm_bt<0, 0><<<dim3(S_ / 128, S_ / 64, 8), 256, 0, stream>>>(
            qs_c, ks_c, nullptr, pr, nullptr, nullptr, 0, -1,
            S_, S_, DQK_, (long)S_ * DQK_, (long)S_ * DQK_, (long)S_ * S_);
        softmax_k<<<8 * S_, 256, 0, stream>>>(pr);
        gemm_bt<0, 0><<<dim3(S_ / 128, DV_ / 64, 8), 256, 0, stream>>>(
            pr, vt_c, ab, nullptr, nullptr, nullptr, 0, c * 8,
            S_, DV_, S_, (long)S_ * S_, (long)DV_ * S_, 0);
    }

    // ---- o-proj + residual ----
    gemm_bt<1, 1><<<dim3(T_ / 128, H_ / 64, 1), 256, 0, stream>>>(
        ab, ow, x2, nullptr, hidden, nullptr, 0, -1, T_, H_, H_, 0, 0, 0);

    // ---- MoE prep ----
    rmsnorm_k<<<T_, 256, 0, stream>>>(x2, ln2w, hbuf, H_, H_, H_);
    router_k<<<T_, 64, 0, stream>>>(hbuf, rw, rb, w8);

    // ---- shared expert first: out = x2 + shared (full overwrite of d_out) ----
    gemm_bt<1, 1><<<dim3(T_ / 128, INTER_ / 64, 1), 256, 0, stream>>>(
        hbuf, sgw, ge, nullptr, nullptr, nullptr, 0, -1, T_, INTER_, H_, 0, 0, 0);
    gemm_bt<1, 1><<<dim3(T_ / 128, INTER_ / 64, 1), 256, 0, stream>>>(
        hbuf, suw, ue, nullptr, nullptr, nullptr, 0, -1, T_, INTER_, H_, 0, 0, 0);
    silumul_k<<<(T_ * INTER_ + 255) / 256, 256, 0, stream>>>(ge, ue, act, T_ * INTER_);
    gemm_bt<1, 1><<<dim3(T_ / 128, H_ / 64, 1), 256, 0, stream>>>(
        act, sdw, out, nullptr, x2, nullptr, 0, -1, T_, H_, INTER_, 0, 0, 0);

    // ---- routed experts accumulate: out += w8[:,e] * expert_e(hbuf) ----
    for (int e = 0; e < NEXP_; e++) {
        const float* gwe = gw + (size_t)e * INTER_ * H_;
        const float* uwe = uw + (size_t)e * INTER_ * H_;
        const float* dwe = dwn + (size_t)e * H_ * INTER_;
        gemm_bt<1, 1><<<dim3(T_ / 128, INTER_ / 64, 1), 256, 0, stream>>>(
            hbuf, gwe, ge, nullptr, nullptr, nullptr, 0, -1, T_, INTER_, H_, 0, 0, 0);
        gemm_bt<1, 1><<<dim3(T_ / 128, INTER_ / 64, 1), 256, 0, stream>>>(
            hbuf, uwe, ue, nullptr, nullptr, nullptr, 0, -1, T_, INTER_, H_, 0, 0, 0);
        silumul_k<<<(T_ * INTER_ + 255) / 256, 256, 0, stream>>>(ge, ue, act, T_ * INTER_);
        gemm_bt<1, 1><<<dim3(T_ / 128, H_ / 64, 1), 256, 0, stream>>>(
            act, dwe, out, nullptr, nullptr, w8 + e, 8, -1, T_, H_, INTER_, 0, 0, 0);
    }
}

// Round 3
// 1431.046 us; speedup vs baseline: 1.7863x; 1.7863x over previous
//
#include <hip/hip_runtime.h>

typedef float f4 __attribute__((ext_vector_type(4)));
typedef float f32x4 __attribute__((ext_vector_type(4)));
typedef unsigned short us8 __attribute__((ext_vector_type(8)));
typedef __bf16 bf8 __attribute__((ext_vector_type(8)));

static constexpr int B_ = 2, S_ = 1024, H_ = 2048, T_ = B_ * S_;
static constexpr int NH_ = 16, DN_ = 128, DR_ = 64, DV_ = 128, DQK_ = 192;
static constexpr int KVL_ = 512, QL_ = 1536, INTER_ = 768, NEXP_ = 8;
static constexpr float SCALING_ = 0.07216878364870322f; // 192^-0.5
static constexpr float EPS_ = 1e-6f;

__device__ __forceinline__ unsigned short f2bf(float f) {
    unsigned u = __float_as_uint(f);
    u += 0x7fffu + ((u >> 16) & 1u);
    return (unsigned short)(u >> 16);
}
__device__ __forceinline__ float bf2f(unsigned short h) {
    return __uint_as_float(((unsigned)h) << 16);
}
__device__ __forceinline__ us8 pack8(f4 a, f4 b) {
    us8 r;
    r[0] = f2bf(a[0]); r[1] = f2bf(a[1]); r[2] = f2bf(a[2]); r[3] = f2bf(a[3]);
    r[4] = f2bf(b[0]); r[5] = f2bf(b[1]); r[6] = f2bf(b[2]); r[7] = f2bf(b[3]);
    return r;
}

// ---------------------------------------------------------------------------
// Generic MFMA GEMM: C[M,N] = A[M,K] * B[N,K]^T   (all row-major)
// ---------------------------------------------------------------------------
template <int AF32, int BF32>
__global__ __launch_bounds__(256, 2) void gemm_bt(
    const void* __restrict__ Av, const void* __restrict__ Bv,
    float* __restrict__ C, unsigned short* __restrict__ Cb,
    const float* __restrict__ add, int perm_bh0,
    int M, int N, int K, long sA, long sB, long sC)
{
    constexpr int BM = 128, BN = 64, BK = 32;
    __shared__ __align__(16) unsigned short As[BM][BK + 8];
    __shared__ __align__(16) unsigned short Bs[BN][BK + 8];
    const int tid = threadIdx.x;
    const int lane = tid & 63, wv = tid >> 6;
    const int wm = (wv >> 1) * 64, wn = (wv & 1) * 32;
    const int m0 = blockIdx.x * BM, n0 = blockIdx.y * BN;
    const long zA = (long)blockIdx.z * sA;
    const long zB = (long)blockIdx.z * sB;
    const long zC = (long)blockIdx.z * sC;
    const int ar = tid >> 1, ac = (tid & 1) * 16;
    const int br = tid >> 2, bc = (tid & 3) * 8;

    f32x4 acc[4][2];
#pragma unroll
    for (int m = 0; m < 4; m++) {
        acc[m][0] = f32x4{0.f, 0.f, 0.f, 0.f};
        acc[m][1] = f32x4{0.f, 0.f, 0.f, 0.f};
    }

    for (int k0 = 0; k0 < K; k0 += BK) {
        if constexpr (AF32) {
            const float* src = (const float*)Av + zA + (long)(m0 + ar) * K + (k0 + ac);
            const f4* p = (const f4*)src;
            *(us8*)&As[ar][ac]     = pack8(p[0], p[1]);
            *(us8*)&As[ar][ac + 8] = pack8(p[2], p[3]);
        } else {
            const unsigned short* src = (const unsigned short*)Av + zA + (long)(m0 + ar) * K + (k0 + ac);
            const us8* p = (const us8*)src;
            *(us8*)&As[ar][ac]     = p[0];
            *(us8*)&As[ar][ac + 8] = p[1];
        }
        if constexpr (BF32) {
            const float* src = (const float*)Bv + zB + (long)(n0 + br) * K + (k0 + bc);
            const f4* p = (const f4*)src;
            *(us8*)&Bs[br][bc] = pack8(p[0], p[1]);
        } else {
            const unsigned short* src = (const unsigned short*)Bv + zB + (long)(n0 + br) * K + (k0 + bc);
            *(us8*)&Bs[br][bc] = *(const us8*)src;
        }
        __syncthreads();

        const int fr = lane & 15, ko = (lane >> 4) * 8;
        bf8 af[4], bfr[2];
#pragma unroll
        for (int m = 0; m < 4; m++) af[m] = *(const bf8*)&As[wm + m * 16 + fr][ko];
#pragma unroll
        for (int n = 0; n < 2; n++) bfr[n] = *(const bf8*)&Bs[wn + n * 16 + fr][ko];
#pragma unroll
        for (int m = 0; m < 4; m++)
#pragma unroll
            for (int n = 0; n < 2; n++)
                acc[m][n] = __builtin_amdgcn_mfma_f32_16x16x32_bf16(af[m], bfr[n], acc[m][n], 0, 0, 0);
        __syncthreads();
    }

#pragma unroll
    for (int m = 0; m < 4; m++) {
#pragma unroll
        for (int n = 0; n < 2; n++) {
#pragma unroll
            for (int i = 0; i < 4; i++) {
                int row = m0 + wm + m * 16 + (lane >> 4) * 4 + i;
                int col = n0 + wn + n * 16 + (lane & 15);
                float v = acc[m][n][i];
                if (perm_bh0 >= 0) {
                    int bh = perm_bh0 + blockIdx.z;
                    int b = bh >> 4, h = bh & 15;
                    C[((long)(b * S_ + row)) * H_ + h * DV_ + col] = v;
                } else {
                    long idx = zC + (long)row * N + col;
                    if (Cb)       Cb[idx] = f2bf(v);
                    else if (add) C[idx] = v + add[idx];
                    else          C[idx] = v;
                }
            }
        }
    }
}

// ---------------------------------------------------------------------------
// MoE fused gate+up GEMM, indexed-A (gather rows of hb by token list).
// grid (16, 24, 8): z=expert, y: cols [0,768)=gate, [768,1536)=up.
// Output gu compacted at row off[e]+local, write guarded to local<cnt[e].
// ---------------------------------------------------------------------------
__global__ __launch_bounds__(256, 2) void moe_gu_k(
    const float* __restrict__ hb, const float* __restrict__ gw,
    const float* __restrict__ uw, float* __restrict__ gu,
    const int* __restrict__ cnt, const int* __restrict__ off,
    const int* __restrict__ idxl)
{
    constexpr int BM = 128, BN = 64, BK = 32;
    const int e = blockIdx.z;
    const int mcnt = cnt[e];
    const int m0 = blockIdx.x * BM;
    if (m0 >= mcnt) return;
    const int obase = off[e];
    const int n0 = blockIdx.y * BN;
    const float* Bw = (n0 < INTER_)
        ? (gw + (size_t)e * INTER_ * H_ + (size_t)n0 * H_)
        : (uw + (size_t)e * INTER_ * H_ + (size_t)(n0 - INTER_) * H_);

    __shared__ __align__(16) unsigned short As[BM][BK + 8];
    __shared__ __align__(16) unsigned short Bs[BN][BK + 8];
    const int tid = threadIdx.x;
    const int lane = tid & 63, wv = tid >> 6;
    const int wm = (wv >> 1) * 64, wn = (wv & 1) * 32;
    const int ar = tid >> 1, ac = (tid & 1) * 16;
    const int br = tid >> 2, bc = (tid & 3) * 8;

    const int arow = m0 + ar;
    const int tokA = (arow < mcnt) ? idxl[e * T_ + arow] : 0;
    const float* Arow = hb + (long)tokA * H_;

    f32x4 acc[4][2];
#pragma unroll
    for (int m = 0; m < 4; m++) {
        acc[m][0] = f32x4{0.f, 0.f, 0.f, 0.f};
        acc[m][1] = f32x4{0.f, 0.f, 0.f, 0.f};
    }

    for (int k0 = 0; k0 < H_; k0 += BK) {
        const f4* pa = (const f4*)(Arow + k0 + ac);
        *(us8*)&As[ar][ac]     = pack8(pa[0], pa[1]);
        *(us8*)&As[ar][ac + 8] = pack8(pa[2], pa[3]);
        const f4* pb = (const f4*)(Bw + (long)br * H_ + k0 + bc);
        *(us8*)&Bs[br][bc] = pack8(pb[0], pb[1]);
        __syncthreads();

        const int fr = lane & 15, ko = (lane >> 4) * 8;
        bf8 af[4], bfr[2];
#pragma unroll
        for (int m = 0; m < 4; m++) af[m] = *(const bf8*)&As[wm + m * 16 + fr][ko];
#pragma unroll
        for (int n = 0; n < 2; n++) bfr[n] = *(const bf8*)&Bs[wn + n * 16 + fr][ko];
#pragma unroll
        for (int m = 0; m < 4; m++)
#pragma unroll
            for (int n = 0; n < 2; n++)
                acc[m][n] = __builtin_amdgcn_mfma_f32_16x16x32_bf16(af[m], bfr[n], acc[m][n], 0, 0, 0);
        __syncthreads();
    }

#pragma unroll
    for (int m = 0; m < 4; m++)
#pragma unroll
        for (int n = 0; n < 2; n++)
#pragma unroll
            for (int i = 0; i < 4; i++) {
                int rl = wm + m * 16 + (lane >> 4) * 4 + i;
                int cl = n0 + wn + n * 16 + (lane & 15);
                if (m0 + rl < mcnt)
                    gu[(long)(obase + m0 + rl) * (2 * INTER_) + cl] = acc[m][n][i];
            }
}

// ---------------------------------------------------------------------------
// MoE down GEMM: A = compacted bf16 act rows, scatter out[tok] += w * acc.
// grid (16, 32, 8), K=768.
// ---------------------------------------------------------------------------
__global__ __launch_bounds__(256, 2) void moe_down_k(
    const unsigned short* __restrict__ act, const float* __restrict__ dw,
    float* __restrict__ out, const int* __restrict__ cnt, const int* __restrict__ off,
    const int* __restrict__ idxl, const float* __restrict__ wl)
{
    constexpr int BM = 128, BN = 64, BK = 32;
    const int e = blockIdx.z;
    const int mcnt = cnt[e];
    const int m0 = blockIdx.x * BM;
    if (m0 >= mcnt) return;
    const int obase = off[e];
    const int n0 = blockIdx.y * BN;
    const float* Bw = dw + (size_t)e * H_ * INTER_ + (size_t)n0 * INTER_;

    __shared__ __align__(16) unsigned short As[BM][BK + 8];
    __shared__ __align__(16) unsigned short Bs[BN][BK + 8];
    const int tid = threadIdx.x;
    const int lane = tid & 63, wv = tid >> 6;
    const int wm = (wv >> 1) * 64, wn = (wv & 1) * 32;
    const int ar = tid >> 1, ac = (tid & 1) * 16;
    const int br = tid >> 2, bc = (tid & 3) * 8;

    f32x4 acc[4][2];
#pragma unroll
    for (int m = 0; m < 4; m++) {
        acc[m][0] = f32x4{0.f, 0.f, 0.f, 0.f};
        acc[m][1] = f32x4{0.f, 0.f, 0.f, 0.f};
    }

    for (int k0 = 0; k0 < INTER_; k0 += BK) {
        const us8* pa = (const us8*)(act + (long)(obase + m0 + ar) * INTER_ + k0 + ac);
        *(us8*)&As[ar][ac]     = pa[0];
        *(us8*)&As[ar][ac + 8] = pa[1];
        const f4* pb = (const f4*)(Bw + (long)br * INTER_ + k0 + bc);
        *(us8*)&Bs[br][bc] = pack8(pb[0], pb[1]);
        __syncthreads();

        const int fr = lane & 15, ko = (lane >> 4) * 8;
        bf8 af[4], bfr[2];
#pragma unroll
        for (int m = 0; m < 4; m++) af[m] = *(const bf8*)&As[wm + m * 16 + fr][ko];
#pragma unroll
        for (int n = 0; n < 2; n++) bfr[n] = *(const bf8*)&Bs[wn + n * 16 + fr][ko];
#pragma unroll
        for (int m = 0; m < 4; m++)
#pragma unroll
            for (int n = 0; n < 2; n++)
                acc[m][n] = __builtin_amdgcn_mfma_f32_16x16x32_bf16(af[m], bfr[n], acc[m][n], 0, 0, 0);
        __syncthreads();
    }

#pragma unroll
    for (int m = 0; m < 4; m++)
#pragma unroll
        for (int n = 0; n < 2; n++)
#pragma unroll
            for (int i = 0; i < 4; i++) {
                int rl = wm + m * 16 + (lane >> 4) * 4 + i;
                int cl = n0 + wn + n * 16 + (lane & 15);
                if (m0 + rl < mcnt) {
                    int tok = idxl[e * T_ + m0 + rl];
                    float w = wl[e * T_ + m0 + rl];
                    atomicAdd(&out[(long)tok * H_ + cl], w * acc[m][n][i]);
                }
            }
}

// ---------------------------------------------------------------------------
__global__ __launch_bounds__(256) void rmsnorm_k(
    const float* __restrict__ in, const float* __restrict__ w,
    float* __restrict__ out, int cols, int istride, int ostride)
{
    const long ib = (long)blockIdx.x * istride;
    const long ob = (long)blockIdx.x * ostride;
    float ss = 0.f;
    for (int c = threadIdx.x; c < cols; c += 256) {
        float v = in[ib + c];
        ss += v * v;
    }
#pragma unroll
    for (int o = 32; o; o >>= 1) ss += __shfl_down(ss, o);
    __shared__ float red[4];
    if ((threadIdx.x & 63) == 0) red[threadIdx.x >> 6] = ss;
    __syncthreads();
    float tot = red[0] + red[1] + red[2] + red[3];
    float r = rsqrtf(tot / cols + EPS_);
    for (int c = threadIdx.x; c < cols; c += 256) out[ob + c] = in[ib + c] * r * w[c];
}

__global__ __launch_bounds__(64) void rope_q_k(
    const float* __restrict__ q, const float* __restrict__ cs, const float* __restrict__ sn,
    unsigned short* __restrict__ qs)
{
    int t = blockIdx.x;
    int h = t & 15;
    int bs = t >> 4;
    int s = bs & (S_ - 1);
    int b = bs >> 10;
    const float* qrow = q + (long)bs * (NH_ * DQK_) + h * DQK_;
    unsigned short* orow = qs + ((long)(b * NH_ + h) * S_ + s) * DQK_;
    int l = threadIdx.x;
    orow[l] = f2bf(qrow[l]);
    orow[l + 64] = f2bf(qrow[l + 64]);
    const float* cr = cs + (long)bs * DR_;
    const float* sr = sn + (long)bs * DR_;
    int j = l & 31;
    float x0 = qrow[DN_ + 2 * j], x1 = qrow[DN_ + 2 * j + 1];
    float c = cr[j], si = sr[j];
    if (l < 32) orow[DN_ + j] = f2bf(x0 * c - x1 * si);
    else        orow[DN_ + 32 + j] = f2bf(x1 * c + x0 * si);
}

__global__ __launch_bounds__(64) void rope_k_k(
    const float* __restrict__ ckv, const float* __restrict__ cs, const float* __restrict__ sn,
    unsigned short* __restrict__ ks)
{
    int bs = blockIdx.x;
    int s = bs & (S_ - 1);
    int b = bs >> 10;
    const float* kr = ckv + (long)bs * 576 + KVL_;
    int l = threadIdx.x;
    int j = l & 31;
    float x0 = kr[2 * j], x1 = kr[2 * j + 1];
    float c = cs[(long)bs * DR_ + j], si = sn[(long)bs * DR_ + j];
    float val = (l < 32) ? (x0 * c - x1 * si) : (x1 * c + x0 * si);
    int off = (l < 32) ? (DN_ + j) : (DN_ + 32 + j);
    unsigned short bv = f2bf(val);
    for (int h = 0; h < NH_; h++)
        ks[((long)(b * NH_ + h) * S_ + s) * DQK_ + off] = bv;
}

__global__ __launch_bounds__(128) void kpass_k(
    const float* __restrict__ kv, unsigned short* __restrict__ ks)
{
    int t = blockIdx.x;
    int h = t & 15;
    int bs = t >> 4;
    int s = bs & (S_ - 1);
    int b = bs >> 10;
    ks[((long)(b * NH_ + h) * S_ + s) * DQK_ + threadIdx.x] = f2bf(kv[(long)t * 256 + threadIdx.x]);
}

__global__ __launch_bounds__(256) void vt_k(
    const float* __restrict__ kv, unsigned short* __restrict__ vt)
{
    __shared__ unsigned short tile[64][DV_ + 8];
    int s0 = blockIdx.x * 64;
    int bh = blockIdx.y;
    int b = bh >> 4, h = bh & 15;
    for (int it = 0; it < 32; it++) {
        int idx = it * 256 + threadIdx.x;
        int sl = idx >> 7, d = idx & 127;
        float v = kv[((long)(b * S_ + s0 + sl) * NH_ + h) * 256 + DN_ + d];
        tile[sl][d] = f2bf(v);
    }
    __syncthreads();
    for (int it = 0; it < 32; it++) {
        int idx = it * 256 + threadIdx.x;
        int d = idx >> 6, sl = idx & 63;
        vt[((long)bh * DV_ + d) * S_ + s0 + sl] = tile[sl][d];
    }
}

__global__ __launch_bounds__(256) void softmax_k(unsigned short* __restrict__ p)
{
    long row = blockIdx.x;
    int q = (int)(row & (S_ - 1));
    unsigned short* pr = p + row * S_;
    float v[4];
    float mx = -3e38f;
#pragma unroll
    for (int i = 0; i < 4; i++) {
        int k = threadIdx.x + i * 256;
        float val = (k <= q) ? bf2f(pr[k]) * SCALING_ : -3e38f;
        v[i] = val;
        mx = fmaxf(mx, val);
    }
#pragma unroll
    for (int o = 32; o; o >>= 1) mx = fmaxf(mx, __shfl_down(mx, o));
    __shared__ float red[4];
    if ((threadIdx.x & 63) == 0) red[threadIdx.x >> 6] = mx;
    __syncthreads();
    mx = fmaxf(fmaxf(red[0], red[1]), fmaxf(red[2], red[3]));
    float sum = 0.f;
#pragma unroll
    for (int i = 0; i < 4; i++) {
        float e = (v[i] > -1e38f) ? __expf(v[i] - mx) : 0.f;
        v[i] = e;
        sum += e;
    }
#pragma unroll
    for (int o = 32; o; o >>= 1) sum += __shfl_down(sum, o);
    __syncthreads();
    if ((threadIdx.x & 63) == 0) red[threadIdx.x >> 6] = sum;
    __syncthreads();
    sum = red[0] + red[1] + red[2] + red[3];
    float inv = 1.f / sum;
#pragma unroll
    for (int i = 0; i < 4; i++) {
        int k = threadIdx.x + i * 256;
        pr[k] = f2bf(v[i] * inv);
    }
}

__global__ void zero8_k(int* __restrict__ cnt)
{
    if (threadIdx.x < NEXP_) cnt[threadIdx.x] = 0;
}

__global__ void offs_k(const int* __restrict__ cnt, int* __restrict__ off)
{
    if (threadIdx.x == 0) {
        int a = 0;
        for (int e = 0; e < NEXP_; e++) { off[e] = a; a += cnt[e]; }
    }
}

// router: top-2-of-grouped-8 -> scatter (token, weight) into per-expert lists
__global__ __launch_bounds__(64) void router_k(
    const float* __restrict__ h, const float* __restrict__ rw,
    const float* __restrict__ rb, int* __restrict__ cnt,
    int* __restrict__ idxl, float* __restrict__ wl)
{
    int t = blockIdx.x;
    int l = threadIdx.x;
    const float* hr = h + (long)t * H_;
    float pe[8] = {0, 0, 0, 0, 0, 0, 0, 0};
    for (int k = l; k < H_; k += 64) {
        float hv = hr[k];
#pragma unroll
        for (int e = 0; e < 8; e++) pe[e] += hv * rw[e * H_ + k];
    }
#pragma unroll
    for (int e = 0; e < 8; e++)
        for (int o = 32; o; o >>= 1) pe[e] += __shfl_down(pe[e], o);
    if (l == 0) {
        float sr[8], sc[8];
#pragma unroll
        for (int e = 0; e < 8; e++) {
            sr[e] = 1.f / (1.f + __expf(-pe[e]));
            sc[e] = sr[e] + rb[e];
        }
        float gs[4];
        for (int g = 0; g < 4; g++) gs[g] = sc[2 * g] + sc[2 * g + 1];
        int g0 = 0;
        for (int g = 1; g < 4; g++) if (gs[g] > gs[g0]) g0 = g;
        int g1 = -1;
        for (int g = 0; g < 4; g++) {
            if (g == g0) continue;
            if (g1 < 0 || gs[g] > gs[g1]) g1 = g;
        }
        int i0 = -1, i1 = -1;
        for (int e = 0; e < 8; e++) {
            int g = e >> 1;
            if (g != g0 && g != g1) continue;
            if (i0 < 0 || sc[e] > sc[i0]) i0 = e;
        }
        for (int e = 0; e < 8; e++) {
            int g = e >> 1;
            if (g != g0 && g != g1) continue;
            if (e == i0) continue;
            if (i1 < 0 || sc[e] > sc[i1]) i1 = e;
        }
        float w0 = sr[i0], w1 = sr[i1];
        float inv = 2.5f / (w0 + w1 + 1e-20f);
        int p0 = atomicAdd(&cnt[i0], 1);
        idxl[i0 * T_ + p0] = t;
        wl[i0 * T_ + p0] = w0 * inv;
        int p1 = atomicAdd(&cnt[i1], 1);
        idxl[i1 * T_ + p1] = t;
        wl[i1 * T_ + p1] = w1 * inv;
    }
}

__global__ __launch_bounds__(256) void silumul_k(
    const float* __restrict__ g, const float* __restrict__ u,
    float* __restrict__ o, int n)
{
    int i = blockIdx.x * 256 + threadIdx.x;
    if (i < n) {
        float x = g[i];
        o[i] = x / (1.f + __expf(-x)) * u[i];
    }
}

// silu(gu[:, :768]) * gu[:, 768:] -> bf16 act (compacted rows)
__global__ __launch_bounds__(256) void silugu_k(
    const float* __restrict__ gu, unsigned short* __restrict__ act, long n)
{
    long i = (long)blockIdx.x * 256 + threadIdx.x;
    if (i < n) {
        long r = i / INTER_;
        int c = (int)(i - r * INTER_);
        float g = gu[r * (2 * INTER_) + c];
        float u = gu[r * (2 * INTER_) + INTER_ + c];
        act[i] = f2bf(g / (1.f + __expf(-g)) * u);
    }
}

// ---------------------------------------------------------------------------
extern "C" void kernel_launch(void* const* d_in, const int* in_sizes, int n_in,
                              void* d_out, int out_size, void* d_ws, size_t ws_size,
                              hipStream_t stream)
{
    const float* hidden = (const float*)d_in[0];
    const float* cosb   = (const float*)d_in[1];
    const float* sinb   = (const float*)d_in[2];
    const float* ln1w   = (const float*)d_in[3];
    const float* qaw    = (const float*)d_in[4];
    const float* qalnw  = (const float*)d_in[5];
    const float* qbw    = (const float*)d_in[6];
    const float* kvaw   = (const float*)d_in[7];
    const float* kvalnw = (const float*)d_in[8];
    const float* kvbw   = (const float*)d_in[9];
    const float* ow     = (const float*)d_in[10];
    const float* ln2w   = (const float*)d_in[11];
    const float* rw     = (const float*)d_in[12];
    const float* rb     = (const float*)d_in[13];
    const float* gw     = (const float*)d_in[14];
    const float* uw     = (const float*)d_in[15];
    const float* dwn    = (const float*)d_in[16];
    const float* sgw    = (const float*)d_in[17];
    const float* suw    = (const float*)d_in[18];
    const float* sdw    = (const float*)d_in[19];
    float* out = (float*)d_out;
    (void)in_sizes; (void)n_in; (void)out_size; (void)ws_size;

    // ---- static workspace plan (peak 105 MB), alias-checked by liveness ----
    // attention phase:
    //   x [0,16) ; qa/qs [16,28) ; q/pr [28,44) ; ckv [52,57) ; ckvn [57,61)
    //   kv [61,93) ; ks [93,105) ; vt [0,8) ; ab [44,61) ; x2 [61,77) ; hbuf [77,93)
    // MoE phase (attention buffers dead):
    //   act_moe [0,7) ; lists [8,9) ; ge [9,16) ; ue [16,23) ; act_sh [23,30)
    //   gu [30,56) ; x2/hbuf live
    char* ws = (char*)d_ws;
    const size_t MB = 1u << 20;
    float* x    = (float*)(ws + 0 * MB);
    float* qa   = (float*)(ws + 16 * MB);
    float* q    = (float*)(ws + 28 * MB);
    float* ckv  = (float*)(ws + 52 * MB);
    float* ckvn = (float*)(ws + 57 * MB);
    float* kv   = (float*)(ws + 61 * MB);
    unsigned short* qs = (unsigned short*)(ws + 16 * MB);
    unsigned short* ks = (unsigned short*)(ws + 93 * MB);
    unsigned short* vt = (unsigned short*)(ws + 0 * MB);
    unsigned short* pr = (unsigned short*)(ws + 28 * MB);
    float* ab   = (float*)(ws + 44 * MB);
    float* x2   = (float*)(ws + 61 * MB);
    float* hbuf = (float*)(ws + 77 * MB);
    unsigned short* actm = (unsigned short*)(ws + 0 * MB);   // (4096+128) x 768 bf16
    int*   cnt  = (int*)(ws + 8 * MB);
    int*   offb = (int*)(ws + 8 * MB + 256);
    int*   idxl = (int*)(ws + 8 * MB + 512);                 // 8*2048*4 = 64 KB
    float* wl   = (float*)(ws + 8 * MB + 512 + 65536);
    float* ge   = (float*)(ws + 9 * MB);
    float* ue   = (float*)(ws + 16 * MB);
    float* acts = (float*)(ws + 23 * MB);
    float* gu   = (float*)(ws + 30 * MB);                    // (4096+128) x 1536 fp32

    // ---- attention input projections ----
    rmsnorm_k<<<T_, 256, 0, stream>>>(hidden, ln1w, x, H_, H_, H_);

    gemm_bt<1, 1><<<dim3(T_ / 128, QL_ / 64, 1), 256, 0, stream>>>(
        x, qaw, qa, nullptr, nullptr, -1, T_, QL_, H_, 0, 0, 0);
    rmsnorm_k<<<T_, 256, 0, stream>>>(qa, qalnw, qa, QL_, QL_, QL_);
    gemm_bt<1, 1><<<dim3(T_ / 128, (NH_ * DQK_) / 64, 1), 256, 0, stream>>>(
        qa, qbw, q, nullptr, nullptr, -1, T_, NH_ * DQK_, QL_, 0, 0, 0);

    gemm_bt<1, 1><<<dim3(T_ / 128, 576 / 64, 1), 256, 0, stream>>>(
        x, kvaw, ckv, nullptr, nullptr, -1, T_, 576, H_, 0, 0, 0);
    rmsnorm_k<<<T_, 256, 0, stream>>>(ckv, kvalnw, ckvn, KVL_, 576, KVL_);
    gemm_bt<1, 1><<<dim3(T_ / 128, (NH_ * 256) / 64, 1), 256, 0, stream>>>(
        ckvn, kvbw, kv, nullptr, nullptr, -1, T_, NH_ * 256, KVL_, 0, 0, 0);

    // ---- assemble qs / ks / vt ----
    rope_q_k<<<T_ * NH_, 64, 0, stream>>>(q, cosb, sinb, qs);
    rope_k_k<<<T_, 64, 0, stream>>>(ckv, cosb, sinb, ks);
    kpass_k<<<T_ * NH_, 128, 0, stream>>>(kv, ks);
    vt_k<<<dim3(S_ / 64, B_ * NH_), 256, 0, stream>>>(kv, vt);

    // ---- attention: 4 chunks of 8 heads ----
    for (int c = 0; c < 4; c++) {
        const unsigned short* qs_c = qs + (long)c * 8 * S_ * DQK_;
        const unsigned short* ks_c = ks + (long)c * 8 * S_ * DQK_;
        const unsigned short* vt_c = vt + (long)c * 8 * DV_ * S_;
        gemm_bt<0, 0><<<dim3(S_ / 128, S_ / 64, 8), 256, 0, stream>>>(
            qs_c, ks_c, nullptr, pr, nullptr, -1,
            S_, S_, DQK_, (long)S_ * DQK_, (long)S_ * DQK_, (long)S_ * S_);
        softmax_k<<<8 * S_, 256, 0, stream>>>(pr);
        gemm_bt<0, 0><<<dim3(S_ / 128, DV_ / 64, 8), 256, 0, stream>>>(
            pr, vt_c, ab, nullptr, nullptr, c * 8,
            S_, DV_, S_, (long)S_ * S_, (long)DV_ * S_, 0);
    }

    // ---- o-proj + residual ----
    gemm_bt<1, 1><<<dim3(T_ / 128, H_ / 64, 1), 256, 0, stream>>>(
        ab, ow, x2, nullptr, hidden, -1, T_, H_, H_, 0, 0, 0);

    // ---- MoE prep ----
    rmsnorm_k<<<T_, 256, 0, stream>>>(x2, ln2w, hbuf, H_, H_, H_);
    zero8_k<<<1, 64, 0, stream>>>(cnt);
    router_k<<<T_, 64, 0, stream>>>(hbuf, rw, rb, cnt, idxl, wl);
    offs_k<<<1, 64, 0, stream>>>(cnt, offb);

    // ---- shared expert: out = x2 + shared (full overwrite of d_out) ----
    gemm_bt<1, 1><<<dim3(T_ / 128, INTER_ / 64, 1), 256, 0, stream>>>(
        hbuf, sgw, ge, nullptr, nullptr, -1, T_, INTER_, H_, 0, 0, 0);
    gemm_bt<1, 1><<<dim3(T_ / 128, INTER_ / 64, 1), 256, 0, stream>>>(
        hbuf, suw, ue, nullptr, nullptr, -1, T_, INTER_, H_, 0, 0, 0);
    silumul_k<<<(T_ * INTER_ + 255) / 256, 256, 0, stream>>>(ge, ue, acts, T_ * INTER_);
    gemm_bt<1, 1><<<dim3(T_ / 128, H_ / 64, 1), 256, 0, stream>>>(
        acts, sdw, out, nullptr, x2, -1, T_, H_, INTER_, 0, 0, 0);

    // ---- routed experts (sparse top-2): gather -> gate+up -> silu -> down+scatter
    moe_gu_k<<<dim3(T_ / 128, (2 * INTER_) / 64, NEXP_), 256, 0, stream>>>(
        hbuf, gw, uw, gu, cnt, offb, idxl);
    silugu_k<<<(int)(((long)(2 * T_ + 128) * INTER_ + 255) / 256), 256, 0, stream>>>(
        gu, actm, (long)(2 * T_ + 128) * INTER_);
    moe_down_k<<<dim3(T_ / 128, H_ / 64, NEXP_), 256, 0, stream>>>(
        actm, dwn, out, cnt, offb, idxl, wl);
}

// Round 4
// 1014.561 us; speedup vs baseline: 2.5196x; 1.4105x over previous
//
#include <hip/hip_runtime.h>

typedef float f4 __attribute__((ext_vector_type(4)));
typedef float f32x4 __attribute__((ext_vector_type(4)));
typedef unsigned short us8 __attribute__((ext_vector_type(8)));
typedef __bf16 bf8 __attribute__((ext_vector_type(8)));

static constexpr int B_ = 2, S_ = 1024, H_ = 2048, T_ = B_ * S_;
static constexpr int NH_ = 16, DN_ = 128, DR_ = 64, DV_ = 128, DQK_ = 192;
static constexpr int KVL_ = 512, QL_ = 1536, INTER_ = 768, NEXP_ = 8;
static constexpr float SCALING_ = 0.07216878364870322f; // 192^-0.5
static constexpr float EPS_ = 1e-6f;

__device__ __forceinline__ unsigned short f2bf(float f) {
    unsigned u = __float_as_uint(f);
    u += 0x7fffu + ((u >> 16) & 1u);
    return (unsigned short)(u >> 16);
}
__device__ __forceinline__ float bf2f(unsigned short h) {
    return __uint_as_float(((unsigned)h) << 16);
}

// async 16B/lane global->LDS. LDS dest = wave-uniform base + lane*16 (HW).
__device__ __forceinline__ void gload16(const unsigned short* g, unsigned short* lds) {
    __builtin_amdgcn_global_load_lds(
        (const __attribute__((address_space(1))) void*)g,
        (__attribute__((address_space(3))) void*)lds, 16, 0, 0);
}

// ---------------------------------------------------------------------------
// gemm2: C[M,N] = A[M,K] * B[N,K]^T, A/B bf16, 128x128 tile, BK=32,
// 4 waves (2x2) x acc 4x4 of 16x16x32 MFMA. m97 structure: global_load_lds
// staging (linear LDS), 2 barriers per K-step.
// MODE 0: plain / batched-z. Epilogue: perm_bh0>=0 -> attention bf16 perm
//         store; else Cb -> bf16; else Cf (+add) fp32.
// MODE 1: MoE gate+up. z=expert, A rows gathered via idxl, C bf16 compacted
//         at off[e], writes guarded to cnt[e].
// MODE 2: MoE down. A rows compacted at off[e], C fp32 scatter
//         atomicAdd(out[tok]) * wl, guarded.
// ---------------------------------------------------------------------------
template <int MODE>
__global__ __launch_bounds__(256) void gemm2(
    const unsigned short* __restrict__ A, const unsigned short* __restrict__ Bw,
    float* __restrict__ Cf, unsigned short* __restrict__ Cb,
    const float* __restrict__ add,
    const int* __restrict__ cnt, const int* __restrict__ off,
    const int* __restrict__ idxl, const float* __restrict__ wl,
    int M, int N, int K, long sA, long sB, long sC, int perm_bh0)
{
    constexpr int BM = 128, BN = 128, BK = 32;
    __shared__ __align__(16) unsigned short As[BM * BK];
    __shared__ __align__(16) unsigned short Bs[BN * BK];
    const int tid = threadIdx.x, lane = tid & 63, wv = tid >> 6;
    const int wm = (wv >> 1) * 64, wn = (wv & 1) * 64;
    const int m0 = blockIdx.x * BM, n0 = blockIdx.y * BN;

    int mcnt = M, obase = 0;
    if constexpr (MODE != 0) {
        mcnt = cnt[blockIdx.z];
        if (m0 >= mcnt) return;
        obase = off[blockIdx.z];
    }

    // staging addresses: thread t covers row (t>>2) [+64 for site 1],
    // 8 bf16 cols starting at (t&3)*8; LDS linear offset = t*16 bytes.
    const int srow = tid >> 2, scol = (tid & 3) * 8;
    long aoff0, aoff1;
    if constexpr (MODE == 1) {
        const int e = blockIdx.z;
        int r0 = m0 + srow, r1 = r0 + 64;
        int t0 = idxl[(long)e * T_ + (r0 < mcnt ? r0 : mcnt - 1)];
        int t1 = idxl[(long)e * T_ + (r1 < mcnt ? r1 : mcnt - 1)];
        aoff0 = (long)t0 * K + scol;
        aoff1 = (long)t1 * K + scol;
    } else if constexpr (MODE == 2) {
        aoff0 = (long)(obase + m0 + srow) * K + scol;
        aoff1 = aoff0 + 64L * K;
    } else {
        aoff0 = (long)blockIdx.z * sA + (long)(m0 + srow) * K + scol;
        aoff1 = aoff0 + 64L * K;
    }
    long boff0 = (long)blockIdx.z * sB + (long)(n0 + srow) * K + scol;
    long boff1 = boff0 + 64L * K;

    unsigned short* ldsA0 = &As[wv * 512];
    unsigned short* ldsA1 = &As[2048 + wv * 512];
    unsigned short* ldsB0 = &Bs[wv * 512];
    unsigned short* ldsB1 = &Bs[2048 + wv * 512];

    f32x4 acc[4][4];
#pragma unroll
    for (int m = 0; m < 4; m++)
#pragma unroll
        for (int n = 0; n < 4; n++) acc[m][n] = f32x4{0.f, 0.f, 0.f, 0.f};

    const int fr = lane & 15, ko = (lane >> 4) * 8;
    for (int k0 = 0; k0 < K; k0 += BK) {
        gload16(A + aoff0 + k0, ldsA0);
        gload16(A + aoff1 + k0, ldsA1);
        gload16(Bw + boff0 + k0, ldsB0);
        gload16(Bw + boff1 + k0, ldsB1);
        __syncthreads();

        bf8 af[4], bfv[4];
#pragma unroll
        for (int m = 0; m < 4; m++) af[m] = *(const bf8*)&As[(wm + m * 16 + fr) * 32 + ko];
#pragma unroll
        for (int n = 0; n < 4; n++) bfv[n] = *(const bf8*)&Bs[(wn + n * 16 + fr) * 32 + ko];
#pragma unroll
        for (int m = 0; m < 4; m++)
#pragma unroll
            for (int n = 0; n < 4; n++)
                acc[m][n] = __builtin_amdgcn_mfma_f32_16x16x32_bf16(af[m], bfv[n], acc[m][n], 0, 0, 0);
        __syncthreads();
    }

#pragma unroll
    for (int m = 0; m < 4; m++) {
#pragma unroll
        for (int n = 0; n < 4; n++) {
#pragma unroll
            for (int i = 0; i < 4; i++) {
                int row = wm + m * 16 + (lane >> 4) * 4 + i;   // local row
                int col = n0 + wn + n * 16 + (lane & 15);
                float v = acc[m][n][i];
                if constexpr (MODE == 0) {
                    int grow = m0 + row;
                    if (perm_bh0 >= 0) {
                        int bh = perm_bh0 + blockIdx.z;
                        int b = bh >> 4, h = bh & 15;
                        Cb[((long)(b * S_ + grow)) * H_ + h * DV_ + col] = f2bf(v);
                    } else {
                        long idx = (long)blockIdx.z * sC + (long)grow * N + col;
                        if (Cb)       Cb[idx] = f2bf(v);
                        else if (add) Cf[idx] = v + add[idx];
                        else          Cf[idx] = v;
                    }
                } else if constexpr (MODE == 1) {
                    if (m0 + row < mcnt)
                        Cb[(long)(obase + m0 + row) * N + col] = f2bf(v);
                } else {
                    if (m0 + row < mcnt) {
                        int e = blockIdx.z;
                        int tok = idxl[(long)e * T_ + m0 + row];
                        float w = wl[(long)e * T_ + m0 + row];
                        atomicAdd(&Cf[(long)tok * N + col], w * v);
                    }
                }
            }
        }
    }
}

// ---------------------------------------------------------------------------
// weight conversion kernels (fp32 -> bf16), vectorized x4
// ---------------------------------------------------------------------------
__global__ __launch_bounds__(256) void cvt_k(
    const float* __restrict__ s, unsigned short* __restrict__ d, long n)
{
    long i = ((long)blockIdx.x * 256 + threadIdx.x) * 4;
    if (i < n) {
        f4 v = *(const f4*)(s + i);
        d[i] = f2bf(v[0]); d[i + 1] = f2bf(v[1]); d[i + 2] = f2bf(v[2]); d[i + 3] = f2bf(v[3]);
    }
}

// kvaw (576 x 2048) -> padded (640 x 2048), rows >= 576 zero
__global__ __launch_bounds__(256) void cvt_pad_k(
    const float* __restrict__ s, unsigned short* __restrict__ d)
{
    long i = ((long)blockIdx.x * 256 + threadIdx.x) * 4;   // over 640*2048
    long row = i >> 11;
    if (row < 576) {
        f4 v = *(const f4*)(s + i);
        d[i] = f2bf(v[0]); d[i + 1] = f2bf(v[1]); d[i + 2] = f2bf(v[2]); d[i + 3] = f2bf(v[3]);
    } else {
        d[i] = 0; d[i + 1] = 0; d[i + 2] = 0; d[i + 3] = 0;
    }
}

// concat gate|up per expert: d[e][0:768] = g[e], d[e][768:1536] = u[e]; C=2048
__global__ __launch_bounds__(256) void cvt_cat_k(
    const float* __restrict__ g, const float* __restrict__ u,
    unsigned short* __restrict__ d)
{
    long ii = ((long)blockIdx.x * 256 + threadIdx.x) * 4;   // within expert, 1536*2048
    int e = blockIdx.y;
    long row = ii >> 11, col = ii & 2047;
    const float* src = (row < INTER_)
        ? (g + ((long)e * INTER_ + row) * H_ + col)
        : (u + ((long)e * INTER_ + row - INTER_) * H_ + col);
    f4 v = *(const f4*)src;
    unsigned short* dd = d + (long)e * (2 * INTER_) * H_ + ii;
    dd[0] = f2bf(v[0]); dd[1] = f2bf(v[1]); dd[2] = f2bf(v[2]); dd[3] = f2bf(v[3]);
}

// ---------------------------------------------------------------------------
// rmsnorm: fp32 in -> bf16 out (+ optional fp32 out); row per block
__global__ __launch_bounds__(256) void rmsnorm_f2b(
    const float* __restrict__ in, const float* __restrict__ w,
    unsigned short* __restrict__ ob, float* __restrict__ of, int cols)
{
    const long base = (long)blockIdx.x * cols;
    float ss = 0.f;
    for (int c = threadIdx.x; c < cols; c += 256) {
        float v = in[base + c];
        ss += v * v;
    }
#pragma unroll
    for (int o = 32; o; o >>= 1) ss += __shfl_down(ss, o);
    __shared__ float red[4];
    if ((threadIdx.x & 63) == 0) red[threadIdx.x >> 6] = ss;
    __syncthreads();
    float r = rsqrtf((red[0] + red[1] + red[2] + red[3]) / cols + EPS_);
    for (int c = threadIdx.x; c < cols; c += 256) {
        float v = in[base + c] * r * w[c];
        ob[base + c] = f2bf(v);
        if (of) of[base + c] = v;
    }
}

// rmsnorm: bf16 in (istride) -> bf16 out (cols); in-place safe
__global__ __launch_bounds__(256) void rmsnorm_b2b(
    const unsigned short* __restrict__ in, const float* __restrict__ w,
    unsigned short* __restrict__ out, int cols, int istride)
{
    const long ib = (long)blockIdx.x * istride;
    const long ob = (long)blockIdx.x * cols;
    float ss = 0.f;
    for (int c = threadIdx.x; c < cols; c += 256) {
        float v = bf2f(in[ib + c]);
        ss += v * v;
    }
#pragma unroll
    for (int o = 32; o; o >>= 1) ss += __shfl_down(ss, o);
    __shared__ float red[4];
    if ((threadIdx.x & 63) == 0) red[threadIdx.x >> 6] = ss;
    __syncthreads();
    float r = rsqrtf((red[0] + red[1] + red[2] + red[3]) / cols + EPS_);
    for (int c = threadIdx.x; c < cols; c += 256)
        out[ob + c] = f2bf(bf2f(in[ib + c]) * r * w[c]);
}

// ---------------------------------------------------------------------------
__global__ __launch_bounds__(64) void rope_q_k(
    const unsigned short* __restrict__ q, const float* __restrict__ cs,
    const float* __restrict__ sn, unsigned short* __restrict__ qs)
{
    int t = blockIdx.x;            // (b*S+s)*16 + h
    int h = t & 15;
    int bs = t >> 4;
    int s = bs & (S_ - 1);
    int b = bs >> 10;
    const unsigned short* qrow = q + (long)bs * (NH_ * DQK_) + h * DQK_;
    unsigned short* orow = qs + ((long)(b * NH_ + h) * S_ + s) * DQK_;
    int l = threadIdx.x;
    orow[l] = qrow[l];
    orow[l + 64] = qrow[l + 64];
    int j = l & 31;
    float x0 = bf2f(qrow[DN_ + 2 * j]), x1 = bf2f(qrow[DN_ + 2 * j + 1]);
    float c = cs[(long)bs * DR_ + j], si = sn[(long)bs * DR_ + j];
    if (l < 32) orow[DN_ + j] = f2bf(x0 * c - x1 * si);
    else        orow[DN_ + 32 + j] = f2bf(x1 * c + x0 * si);
}

__global__ __launch_bounds__(64) void rope_k_k(
    const unsigned short* __restrict__ ckv, const float* __restrict__ cs,
    const float* __restrict__ sn, unsigned short* __restrict__ ks)
{
    int bs = blockIdx.x;
    int s = bs & (S_ - 1);
    int b = bs >> 10;
    const unsigned short* kr = ckv + (long)bs * 640 + KVL_;
    int l = threadIdx.x;
    int j = l & 31;
    float x0 = bf2f(kr[2 * j]), x1 = bf2f(kr[2 * j + 1]);
    float c = cs[(long)bs * DR_ + j], si = sn[(long)bs * DR_ + j];
    float val = (l < 32) ? (x0 * c - x1 * si) : (x1 * c + x0 * si);
    int off = (l < 32) ? (DN_ + j) : (DN_ + 32 + j);
    unsigned short bv = f2bf(val);
    for (int h = 0; h < NH_; h++)
        ks[((long)(b * NH_ + h) * S_ + s) * DQK_ + off] = bv;
}

__global__ __launch_bounds__(128) void kpass_k(
    const unsigned short* __restrict__ kv, unsigned short* __restrict__ ks)
{
    int t = blockIdx.x; // (b*S+s)*16 + h
    int h = t & 15;
    int bs = t >> 4;
    int s = bs & (S_ - 1);
    int b = bs >> 10;
    ks[((long)(b * NH_ + h) * S_ + s) * DQK_ + threadIdx.x] = kv[(long)t * 256 + threadIdx.x];
}

__global__ __launch_bounds__(256) void vt_k(
    const unsigned short* __restrict__ kv, unsigned short* __restrict__ vt)
{
    __shared__ unsigned short tile[64][DV_ + 8];
    int s0 = blockIdx.x * 64;
    int bh = blockIdx.y;
    int b = bh >> 4, h = bh & 15;
    for (int it = 0; it < 32; it++) {
        int idx = it * 256 + threadIdx.x;
        int sl = idx >> 7, d = idx & 127;
        tile[sl][d] = kv[((long)(b * S_ + s0 + sl) * NH_ + h) * 256 + DN_ + d];
    }
    __syncthreads();
    for (int it = 0; it < 32; it++) {
        int idx = it * 256 + threadIdx.x;
        int d = idx >> 6, sl = idx & 63;
        vt[((long)bh * DV_ + d) * S_ + s0 + sl] = tile[sl][d];
    }
}

__global__ __launch_bounds__(256) void softmax_k(unsigned short* __restrict__ p)
{
    long row = blockIdx.x;
    int q = (int)(row & (S_ - 1));
    unsigned short* pr = p + row * S_;
    float v[4];
    float mx = -3e38f;
#pragma unroll
    for (int i = 0; i < 4; i++) {
        int k = threadIdx.x + i * 256;
        float val = (k <= q) ? bf2f(pr[k]) * SCALING_ : -3e38f;
        v[i] = val;
        mx = fmaxf(mx, val);
    }
#pragma unroll
    for (int o = 32; o; o >>= 1) mx = fmaxf(mx, __shfl_down(mx, o));
    __shared__ float red[4];
    if ((threadIdx.x & 63) == 0) red[threadIdx.x >> 6] = mx;
    __syncthreads();
    mx = fmaxf(fmaxf(red[0], red[1]), fmaxf(red[2], red[3]));
    float sum = 0.f;
#pragma unroll
    for (int i = 0; i < 4; i++) {
        float e = (v[i] > -1e38f) ? __expf(v[i] - mx) : 0.f;
        v[i] = e;
        sum += e;
    }
#pragma unroll
    for (int o = 32; o; o >>= 1) sum += __shfl_down(sum, o);
    __syncthreads();
    if ((threadIdx.x & 63) == 0) red[threadIdx.x >> 6] = sum;
    __syncthreads();
    sum = red[0] + red[1] + red[2] + red[3];
    float inv = 1.f / sum;
#pragma unroll
    for (int i = 0; i < 4; i++) {
        int k = threadIdx.x + i * 256;
        pr[k] = f2bf(v[i] * inv);
    }
}

__global__ void zero8_k(int* __restrict__ cnt)
{
    if (threadIdx.x < NEXP_) cnt[threadIdx.x] = 0;
}

__global__ void offs_k(const int* __restrict__ cnt, int* __restrict__ off)
{
    if (threadIdx.x == 0) {
        int a = 0;
        for (int e = 0; e < NEXP_; e++) { off[e] = a; a += cnt[e]; }
    }
}

__global__ __launch_bounds__(64) void router_k(
    const float* __restrict__ h, const float* __restrict__ rw,
    const float* __restrict__ rb, int* __restrict__ cnt,
    int* __restrict__ idxl, float* __restrict__ wl)
{
    int t = blockIdx.x;
    int l = threadIdx.x;
    const float* hr = h + (long)t * H_;
    float pe[8] = {0, 0, 0, 0, 0, 0, 0, 0};
    for (int k = l; k < H_; k += 64) {
        float hv = hr[k];
#pragma unroll
        for (int e = 0; e < 8; e++) pe[e] += hv * rw[e * H_ + k];
    }
#pragma unroll
    for (int e = 0; e < 8; e++)
        for (int o = 32; o; o >>= 1) pe[e] += __shfl_down(pe[e], o);
    if (l == 0) {
        float sr[8], sc[8];
#pragma unroll
        for (int e = 0; e < 8; e++) {
            sr[e] = 1.f / (1.f + __expf(-pe[e]));
            sc[e] = sr[e] + rb[e];
        }
        float gs[4];
        for (int g = 0; g < 4; g++) gs[g] = sc[2 * g] + sc[2 * g + 1];
        int g0 = 0;
        for (int g = 1; g < 4; g++) if (gs[g] > gs[g0]) g0 = g;
        int g1 = -1;
        for (int g = 0; g < 4; g++) {
            if (g == g0) continue;
            if (g1 < 0 || gs[g] > gs[g1]) g1 = g;
        }
        int i0 = -1, i1 = -1;
        for (int e = 0; e < 8; e++) {
            int g = e >> 1;
            if (g != g0 && g != g1) continue;
            if (i0 < 0 || sc[e] > sc[i0]) i0 = e;
        }
        for (int e = 0; e < 8; e++) {
            int g = e >> 1;
            if (g != g0 && g != g1) continue;
            if (e == i0) continue;
            if (i1 < 0 || sc[e] > sc[i1]) i1 = e;
        }
        float w0 = sr[i0], w1 = sr[i1];
        float inv = 2.5f / (w0 + w1 + 1e-20f);
        int p0 = atomicAdd(&cnt[i0], 1);
        idxl[i0 * T_ + p0] = t;
        wl[i0 * T_ + p0] = w0 * inv;
        int p1 = atomicAdd(&cnt[i1], 1);
        idxl[i1 * T_ + p1] = t;
        wl[i1 * T_ + p1] = w1 * inv;
    }
}

// act[r][c] = silu(gu[r][c]) * gu[r][768+c], bf16; grid (rows, 3) x 256
__global__ __launch_bounds__(256) void silugu_k(
    const unsigned short* __restrict__ gu, unsigned short* __restrict__ act)
{
    int r = blockIdx.x;
    int c = blockIdx.y * 256 + threadIdx.x;
    float g = bf2f(gu[(long)r * (2 * INTER_) + c]);
    float u = bf2f(gu[(long)r * (2 * INTER_) + INTER_ + c]);
    act[(long)r * INTER_ + c] = f2bf(g / (1.f + __expf(-g)) * u);
}

// ---------------------------------------------------------------------------
extern "C" void kernel_launch(void* const* d_in, const int* in_sizes, int n_in,
                              void* d_out, int out_size, void* d_ws, size_t ws_size,
                              hipStream_t stream)
{
    const float* hidden = (const float*)d_in[0];
    const float* cosb   = (const float*)d_in[1];
    const float* sinb   = (const float*)d_in[2];
    const float* ln1w   = (const float*)d_in[3];
    const float* qaw    = (const float*)d_in[4];
    const float* qalnw  = (const float*)d_in[5];
    const float* qbw    = (const float*)d_in[6];
    const float* kvaw   = (const float*)d_in[7];
    const float* kvalnw = (const float*)d_in[8];
    const float* kvbw   = (const float*)d_in[9];
    const float* ow     = (const float*)d_in[10];
    const float* ln2w   = (const float*)d_in[11];
    const float* rw     = (const float*)d_in[12];
    const float* rb     = (const float*)d_in[13];
    const float* gw     = (const float*)d_in[14];
    const float* uw     = (const float*)d_in[15];
    const float* dwn    = (const float*)d_in[16];
    const float* sgw    = (const float*)d_in[17];
    const float* suw    = (const float*)d_in[18];
    const float* sdw    = (const float*)d_in[19];
    float* out = (float*)d_out;
    (void)in_sizes; (void)n_in; (void)out_size; (void)ws_size;

    char* ws = (char*)d_ws;
    const size_t MB = 1u << 20;
    // ---- phase A (attention) layout, MiB offsets, peak 101 ----
    unsigned short* qawb  = (unsigned short*)(ws + 0 * MB);   // 6
    unsigned short* qbwb  = (unsigned short*)(ws + 6 * MB);   // 9
    unsigned short* kvawb = (unsigned short*)(ws + 15 * MB);  // 2.5 (640x2048)
    unsigned short* kvbwb = (unsigned short*)(ws + 18 * MB);  // 4
    unsigned short* owb   = (unsigned short*)(ws + 22 * MB);  // 8
    unsigned short* xb    = (unsigned short*)(ws + 30 * MB);  // 8
    unsigned short* qab   = (unsigned short*)(ws + 38 * MB);  // 6
    unsigned short* qb16  = (unsigned short*)(ws + 44 * MB);  // 12
    unsigned short* ckvb  = (unsigned short*)(ws + 56 * MB);  // 2.5 (T x 640)
    unsigned short* ckvnb = (unsigned short*)(ws + 59 * MB);  // 2
    unsigned short* kvb   = (unsigned short*)(ws + 61 * MB);  // 16
    unsigned short* qs    = (unsigned short*)(ws + 77 * MB);  // 12
    unsigned short* ks    = (unsigned short*)(ws + 89 * MB);  // 12
    unsigned short* vt    = (unsigned short*)(ws + 30 * MB);  // 8  (alias xb)
    unsigned short* pr    = (unsigned short*)(ws + 38 * MB);  // 16 (alias qab/qb16)
    unsigned short* ab    = (unsigned short*)(ws + 56 * MB);  // 8  (alias ckv*/kvb)
    // ---- phase B (MoE) layout, peak 102 ----
    float* hbuf = (float*)(ws + 0 * MB);                      // 16
    unsigned short* hb16 = (unsigned short*)(ws + 16 * MB);   // 8
    int*   cnt  = (int*)(ws + 24 * MB);
    int*   offb = (int*)(ws + 24 * MB + 256);
    int*   idxl = (int*)(ws + 24 * MB + 512);                 // 64 KB
    float* wl   = (float*)(ws + 24 * MB + 512 + 65536);       // 64 KB
    unsigned short* sguwb = (unsigned short*)(ws + 25 * MB);  // 6 (1536x2048)
    unsigned short* sdwb  = (unsigned short*)(ws + 31 * MB);  // 3
    unsigned short* guwb  = (unsigned short*)(ws + 34 * MB);  // 48 (8x1536x2048)
    unsigned short* gu    = (unsigned short*)(ws + 82 * MB);  // 12.4 (4224x1536)
    unsigned short* actm  = (unsigned short*)(ws + 95 * MB);  // 6.2 (4224x768)
    unsigned short* dwnb  = (unsigned short*)(ws + 34 * MB);  // 24 (after guwb dead)

    // ---- convert attention weights to bf16 ----
    cvt_k<<<(QL_ * H_) / 1024, 256, 0, stream>>>(qaw, qawb, (long)QL_ * H_);
    cvt_k<<<(NH_ * DQK_ * QL_) / 1024, 256, 0, stream>>>(qbw, qbwb, (long)NH_ * DQK_ * QL_);
    cvt_pad_k<<<(640 * H_) / 1024, 256, 0, stream>>>(kvaw, kvawb);
    cvt_k<<<(NH_ * 256 * KVL_) / 1024, 256, 0, stream>>>(kvbw, kvbwb, (long)NH_ * 256 * KVL_);
    cvt_k<<<(H_ * H_) / 1024, 256, 0, stream>>>(ow, owb, (long)H_ * H_);

    // ---- attention projections ----
    rmsnorm_f2b<<<T_, 256, 0, stream>>>(hidden, ln1w, xb, nullptr, H_);

    gemm2<0><<<dim3(T_ / 128, QL_ / 128, 1), 256, 0, stream>>>(
        xb, qawb, nullptr, qab, nullptr, nullptr, nullptr, nullptr, nullptr,
        T_, QL_, H_, 0, 0, 0, -1);
    rmsnorm_b2b<<<T_, 256, 0, stream>>>(qab, qalnw, qab, QL_, QL_);
    gemm2<0><<<dim3(T_ / 128, (NH_ * DQK_) / 128, 1), 256, 0, stream>>>(
        qab, qbwb, nullptr, qb16, nullptr, nullptr, nullptr, nullptr, nullptr,
        T_, NH_ * DQK_, QL_, 0, 0, 0, -1);

    gemm2<0><<<dim3(T_ / 128, 640 / 128, 1), 256, 0, stream>>>(
        xb, kvawb, nullptr, ckvb, nullptr, nullptr, nullptr, nullptr, nullptr,
        T_, 640, H_, 0, 0, 0, -1);
    rmsnorm_b2b<<<T_, 256, 0, stream>>>(ckvb, kvalnw, ckvnb, KVL_, 640);
    gemm2<0><<<dim3(T_ / 128, (NH_ * 256) / 128, 1), 256, 0, stream>>>(
        ckvnb, kvbwb, nullptr, kvb, nullptr, nullptr, nullptr, nullptr, nullptr,
        T_, NH_ * 256, KVL_, 0, 0, 0, -1);

    // ---- assemble qs / ks / vt ----
    rope_q_k<<<T_ * NH_, 64, 0, stream>>>(qb16, cosb, sinb, qs);
    rope_k_k<<<T_, 64, 0, stream>>>(ckvb, cosb, sinb, ks);
    kpass_k<<<T_ * NH_, 128, 0, stream>>>(kvb, ks);
    vt_k<<<dim3(S_ / 64, B_ * NH_), 256, 0, stream>>>(kvb, vt);

    // ---- attention: 4 chunks of 8 heads ----
    for (int c = 0; c < 4; c++) {
        const unsigned short* qs_c = qs + (long)c * 8 * S_ * DQK_;
        const unsigned short* ks_c = ks + (long)c * 8 * S_ * DQK_;
        const unsigned short* vt_c = vt + (long)c * 8 * DV_ * S_;
        gemm2<0><<<dim3(S_ / 128, S_ / 128, 8), 256, 0, stream>>>(
            qs_c, ks_c, nullptr, pr, nullptr, nullptr, nullptr, nullptr, nullptr,
            S_, S_, DQK_, (long)S_ * DQK_, (long)S_ * DQK_, (long)S_ * S_, -1);
        softmax_k<<<8 * S_, 256, 0, stream>>>(pr);
        gemm2<0><<<dim3(S_ / 128, 1, 8), 256, 0, stream>>>(
            pr, vt_c, nullptr, ab, nullptr, nullptr, nullptr, nullptr, nullptr,
            S_, DV_, S_, (long)S_ * S_, (long)DV_ * S_, 0, c * 8);
    }

    // ---- o-proj + residual: out = attn @ ow^T + hidden ----
    gemm2<0><<<dim3(T_ / 128, H_ / 128, 1), 256, 0, stream>>>(
        ab, owb, out, nullptr, hidden, nullptr, nullptr, nullptr, nullptr,
        T_, H_, H_, 0, 0, 0, -1);

    // ---- MoE prep ----
    rmsnorm_f2b<<<T_, 256, 0, stream>>>(out, ln2w, hb16, hbuf, H_);
    zero8_k<<<1, 64, 0, stream>>>(cnt);
    router_k<<<T_, 64, 0, stream>>>(hbuf, rw, rb, cnt, idxl, wl);
    offs_k<<<1, 64, 0, stream>>>(cnt, offb);

    // ---- convert MoE/shared weights ----
    cvt_cat_k<<<dim3((2 * INTER_ * H_) / 1024, 1), 256, 0, stream>>>(sgw, suw, sguwb);
    cvt_k<<<(H_ * INTER_) / 1024, 256, 0, stream>>>(sdw, sdwb, (long)H_ * INTER_);
    cvt_cat_k<<<dim3((2 * INTER_ * H_) / 1024, NEXP_), 256, 0, stream>>>(gw, uw, guwb);

    // ---- shared expert: out += silu(h@sgw^T)*(h@suw^T) @ sdw^T ----
    gemm2<0><<<dim3(T_ / 128, (2 * INTER_) / 128, 1), 256, 0, stream>>>(
        hb16, sguwb, nullptr, gu, nullptr, nullptr, nullptr, nullptr, nullptr,
        T_, 2 * INTER_, H_, 0, 0, 0, -1);
    silugu_k<<<dim3(T_, INTER_ / 256), 256, 0, stream>>>(gu, actm);
    gemm2<0><<<dim3(T_ / 128, H_ / 128, 1), 256, 0, stream>>>(
        actm, sdwb, out, nullptr, out, nullptr, nullptr, nullptr, nullptr,
        T_, H_, INTER_, 0, 0, 0, -1);

    // ---- routed experts (top-2): gather -> gate+up -> silu -> down+scatter ----
    gemm2<1><<<dim3(T_ / 128, (2 * INTER_) / 128, NEXP_), 256, 0, stream>>>(
        hb16, guwb, nullptr, gu, nullptr, cnt, offb, idxl, nullptr,
        T_, 2 * INTER_, H_, 0, (long)(2 * INTER_) * H_, 0, -1);
    silugu_k<<<dim3(2 * T_ + 128, INTER_ / 256), 256, 0, stream>>>(gu, actm);
    cvt_k<<<(NEXP_ * H_ * INTER_) / 1024, 256, 0, stream>>>(dwn, dwnb, (long)NEXP_ * H_ * INTER_);
    gemm2<2><<<dim3(T_ / 128, H_ / 128, NEXP_), 256, 0, stream>>>(
        actm, dwnb, out, nullptr, nullptr, cnt, offb, idxl, wl,
        T_, H_, INTER_, 0, (long)H_ * INTER_, 0, -1);
}

// Round 5
// 819.590 us; speedup vs baseline: 3.1190x; 1.2379x over previous
//
#include <hip/hip_runtime.h>

typedef float f4 __attribute__((ext_vector_type(4)));
typedef float f32x4 __attribute__((ext_vector_type(4)));
typedef unsigned short us8 __attribute__((ext_vector_type(8)));
typedef __bf16 bf8 __attribute__((ext_vector_type(8)));

static constexpr int B_ = 2, S_ = 1024, H_ = 2048, T_ = B_ * S_;
static constexpr int NH_ = 16, DN_ = 128, DR_ = 64, DV_ = 128, DQK_ = 192;
static constexpr int KVL_ = 512, QL_ = 1536, INTER_ = 768, NEXP_ = 8;
static constexpr float SCALING_ = 0.07216878364870322f; // 192^-0.5
static constexpr float EPS_ = 1e-6f;

__device__ __forceinline__ unsigned short f2bf(float f) {
    unsigned u = __float_as_uint(f);
    u += 0x7fffu + ((u >> 16) & 1u);
    return (unsigned short)(u >> 16);
}
__device__ __forceinline__ float bf2f(unsigned short h) {
    return __uint_as_float(((unsigned)h) << 16);
}

// async 16B/lane global->LDS. LDS dest = wave-uniform base + lane*16 (HW).
__device__ __forceinline__ void gload16(const unsigned short* g, unsigned short* lds) {
    __builtin_amdgcn_global_load_lds(
        (const __attribute__((address_space(1))) void*)g,
        (__attribute__((address_space(3))) void*)lds, 16, 0, 0);
}

// ---------------------------------------------------------------------------
// gemm2: C[M,N] = A[M,K] * B[N,K]^T, bf16 in, 128x128 tile, BK=32,
// 2-phase double-buffered prefetch: stage(t+1) issued before compute(t),
// one __syncthreads (vmcnt+lgkm drain) per K-step.
// MODE 0: plain / batched-z. Cb -> bf16; else Cf (+add) fp32.
// MODE 1: MoE gate+up: A gathered via idxl, C bf16 compacted at off[e].
// MODE 2: MoE down: A compacted at off[e], atomic scatter out[tok] += w*acc.
// ---------------------------------------------------------------------------
template <int MODE>
__global__ __launch_bounds__(256) void gemm2(
    const unsigned short* __restrict__ A, const unsigned short* __restrict__ Bw,
    float* __restrict__ Cf, unsigned short* __restrict__ Cb,
    const float* __restrict__ add,
    const int* __restrict__ cnt, const int* __restrict__ off,
    const int* __restrict__ idxl, const float* __restrict__ wl,
    int M, int N, int K, long sA, long sB, long sC)
{
    constexpr int BM = 128, BN = 128, BK = 32;
    __shared__ __align__(16) unsigned short As[2][BM * BK];
    __shared__ __align__(16) unsigned short Bs[2][BN * BK];
    const int tid = threadIdx.x, lane = tid & 63, wv = tid >> 6;
    const int wm = (wv >> 1) * 64, wn = (wv & 1) * 64;
    const int m0 = blockIdx.x * BM, n0 = blockIdx.y * BN;

    int mcnt = M, obase = 0;
    if constexpr (MODE != 0) {
        mcnt = cnt[blockIdx.z];
        if (m0 >= mcnt) return;
        obase = off[blockIdx.z];
    }

    const int srow = tid >> 2, scol = (tid & 3) * 8;
    long aoff0, aoff1;
    if constexpr (MODE == 1) {
        const int e = blockIdx.z;
        int r0 = m0 + srow, r1 = r0 + 64;
        int t0 = idxl[(long)e * T_ + (r0 < mcnt ? r0 : mcnt - 1)];
        int t1 = idxl[(long)e * T_ + (r1 < mcnt ? r1 : mcnt - 1)];
        aoff0 = (long)t0 * K + scol;
        aoff1 = (long)t1 * K + scol;
    } else if constexpr (MODE == 2) {
        aoff0 = (long)(obase + m0 + srow) * K + scol;
        aoff1 = aoff0 + 64L * K;
    } else {
        aoff0 = (long)blockIdx.z * sA + (long)(m0 + srow) * K + scol;
        aoff1 = aoff0 + 64L * K;
    }
    long boff0 = (long)blockIdx.z * sB + (long)(n0 + srow) * K + scol;
    long boff1 = boff0 + 64L * K;

    f32x4 acc[4][4];
#pragma unroll
    for (int m = 0; m < 4; m++)
#pragma unroll
        for (int n = 0; n < 4; n++) acc[m][n] = f32x4{0.f, 0.f, 0.f, 0.f};

    const int fr = lane & 15, ko = (lane >> 4) * 8;

    auto stage = [&](int buf, int k0) {
        gload16(A + aoff0 + k0, &As[buf][wv * 512]);
        gload16(A + aoff1 + k0, &As[buf][2048 + wv * 512]);
        gload16(Bw + boff0 + k0, &Bs[buf][wv * 512]);
        gload16(Bw + boff1 + k0, &Bs[buf][2048 + wv * 512]);
    };
    auto compute = [&](int buf) {
        bf8 af[4], bfv[4];
#pragma unroll
        for (int m = 0; m < 4; m++) af[m] = *(const bf8*)&As[buf][(wm + m * 16 + fr) * 32 + ko];
#pragma unroll
        for (int n = 0; n < 4; n++) bfv[n] = *(const bf8*)&Bs[buf][(wn + n * 16 + fr) * 32 + ko];
#pragma unroll
        for (int m = 0; m < 4; m++)
#pragma unroll
            for (int n = 0; n < 4; n++)
                acc[m][n] = __builtin_amdgcn_mfma_f32_16x16x32_bf16(af[m], bfv[n], acc[m][n], 0, 0, 0);
    };

    stage(0, 0);
    __syncthreads();
    int cur = 0;
    for (int k0 = BK; k0 < K; k0 += BK) {
        stage(cur ^ 1, k0);   // prefetch next tile (in flight during compute)
        compute(cur);
        __syncthreads();      // drains vmcnt (prefetch) + lgkm; barrier
        cur ^= 1;
    }
    compute(cur);

#pragma unroll
    for (int m = 0; m < 4; m++) {
#pragma unroll
        for (int n = 0; n < 4; n++) {
#pragma unroll
            for (int i = 0; i < 4; i++) {
                int row = wm + m * 16 + (lane >> 4) * 4 + i;   // local row
                int col = n0 + wn + n * 16 + (lane & 15);
                float v = acc[m][n][i];
                if constexpr (MODE == 0) {
                    long idx = (long)blockIdx.z * sC + (long)(m0 + row) * N + col;
                    if (Cb)       Cb[idx] = f2bf(v);
                    else if (add) Cf[idx] = v + add[idx];
                    else          Cf[idx] = v;
                } else if constexpr (MODE == 1) {
                    if (m0 + row < mcnt)
                        Cb[(long)(obase + m0 + row) * N + col] = f2bf(v);
                } else {
                    if (m0 + row < mcnt) {
                        int e = blockIdx.z;
                        int tok = idxl[(long)e * T_ + m0 + row];
                        float w = wl[(long)e * T_ + m0 + row];
                        atomicAdd(&Cf[(long)tok * N + col], w * v);
                    }
                }
            }
        }
    }
}

// ---------------------------------------------------------------------------
// Flash attention (causal). grid (S/64, B*NH), 256 threads (4 waves).
// Wave wv owns q rows [q0+wv*16, q0+wv*16+16). KV tiles of 64, online softmax.
// qs (B,NH,S,192), ks (B,NH,S,192), vt (B,NH,128,S), ab (B,S,NH*128) bf16.
// ---------------------------------------------------------------------------
__global__ __launch_bounds__(256) void fa_k(
    const unsigned short* __restrict__ qs, const unsigned short* __restrict__ ks,
    const unsigned short* __restrict__ vt, unsigned short* __restrict__ ab)
{
    constexpr int KB = 64;
    const int q0 = blockIdx.x * 64;
    const int bh = blockIdx.y;
    const int b = bh >> 4, h = bh & 15;
    const int tid = threadIdx.x, lane = tid & 63, wv = tid >> 6;
    const int fr = lane & 15, lg = lane >> 4;
    const int ko = lg * 8;

    __shared__ __align__(16) unsigned short Kl[KB][200];   // +8 pad: bank-balanced
    __shared__ __align__(16) unsigned short Vl[128][72];   // V^T tile, +8 pad
    __shared__ __align__(16) unsigned short Pl[4][16][72]; // per-wave P slice

    // Q fragments (A-layout: row=fr, k=lg*8+j), 6 k-slabs of 32
    const unsigned short* qp = qs + ((long)bh * S_ + q0 + wv * 16 + fr) * DQK_ + ko;
    bf8 qf[6];
#pragma unroll
    for (int s = 0; s < 6; s++) qf[s] = *(const bf8*)(qp + s * 32);

    f32x4 o[8];
#pragma unroll
    for (int n = 0; n < 8; n++) o[n] = f32x4{0.f, 0.f, 0.f, 0.f};
    float mrow[4] = {-3e38f, -3e38f, -3e38f, -3e38f};
    float lrow[4] = {0.f, 0.f, 0.f, 0.f};

    const int nt = q0 / KB + 1;   // causal: skip tiles above diagonal

    // staging pointers: K row tid>>2 (48 cols per quarter), V^T row tid>>1
    const unsigned short* kg = ks + ((long)bh * S_ + (tid >> 2)) * DQK_ + (tid & 3) * 48;
    const unsigned short* vg = vt + ((long)bh * DV_ + (tid >> 1)) * S_ + (tid & 1) * 32;

    us8 krg[6], vrg[4];
#pragma unroll
    for (int j = 0; j < 6; j++) krg[j] = *(const us8*)(kg + j * 8);
#pragma unroll
    for (int j = 0; j < 4; j++) vrg[j] = *(const us8*)(vg + j * 8);

    for (int t = 0; t < nt; t++) {
        __syncthreads();   // everyone done reading Kl/Vl of previous tile
        {
            int r = tid >> 2, c = (tid & 3) * 48;
#pragma unroll
            for (int j = 0; j < 6; j++) *(us8*)&Kl[r][c + j * 8] = krg[j];
            int dv = tid >> 1, c2 = (tid & 1) * 32;
#pragma unroll
            for (int j = 0; j < 4; j++) *(us8*)&Vl[dv][c2 + j * 8] = vrg[j];
        }
        __syncthreads();
        if (t + 1 < nt) {  // T14: issue next tile's loads now, land during compute
            long kof = (long)(t + 1) * KB;
#pragma unroll
            for (int j = 0; j < 6; j++) krg[j] = *(const us8*)(kg + kof * DQK_ + j * 8);
#pragma unroll
            for (int j = 0; j < 4; j++) vrg[j] = *(const us8*)(vg + kof + j * 8);
        }
        // ---- QK^T: 4 col-tiles of 16 kv ----
        f32x4 ps[4];
#pragma unroll
        for (int ct = 0; ct < 4; ct++) {
            f32x4 a = f32x4{0.f, 0.f, 0.f, 0.f};
#pragma unroll
            for (int s = 0; s < 6; s++) {
                bf8 kf = *(const bf8*)&Kl[ct * 16 + fr][s * 32 + ko];
                a = __builtin_amdgcn_mfma_f32_16x16x32_bf16(qf[s], kf, a, 0, 0, 0);
            }
            ps[ct] = a;
        }
        const int kv0 = t * KB;
        const bool diag = (kv0 == q0);
#pragma unroll
        for (int ct = 0; ct < 4; ct++)
#pragma unroll
            for (int i = 0; i < 4; i++) {
                float v = ps[ct][i] * SCALING_;
                if (diag && (kv0 + ct * 16 + fr) > (q0 + wv * 16 + lg * 4 + i)) v = -3e38f;
                ps[ct][i] = v;
            }
        // ---- online softmax (rows lg*4+i, reduce across 16 fr lanes) ----
        float scl[4];
#pragma unroll
        for (int i = 0; i < 4; i++) {
            float v = fmaxf(fmaxf(ps[0][i], ps[1][i]), fmaxf(ps[2][i], ps[3][i]));
#pragma unroll
            for (int x = 8; x; x >>= 1) v = fmaxf(v, __shfl_xor(v, x, 16));
            float mn = fmaxf(mrow[i], v);
            scl[i] = __expf(mrow[i] - mn);
            mrow[i] = mn;
        }
        float tsum[4] = {0.f, 0.f, 0.f, 0.f};
#pragma unroll
        for (int ct = 0; ct < 4; ct++)
#pragma unroll
            for (int i = 0; i < 4; i++) {
                float e = __expf(ps[ct][i] - mrow[i]);
                tsum[i] += e;
                Pl[wv][lg * 4 + i][ct * 16 + fr] = f2bf(e);
            }
#pragma unroll
        for (int i = 0; i < 4; i++) {
            float v = tsum[i];
#pragma unroll
            for (int x = 8; x; x >>= 1) v += __shfl_xor(v, x, 16);
            lrow[i] = lrow[i] * scl[i] + v;
        }
#pragma unroll
        for (int n = 0; n < 8; n++)
#pragma unroll
            for (int i = 0; i < 4; i++) o[n][i] *= scl[i];
        // ---- PV: P (A-frag from Pl) x V^T (B-frag from Vl) ----
        bf8 pf[2];
#pragma unroll
        for (int ksl = 0; ksl < 2; ksl++)
            pf[ksl] = *(const bf8*)&Pl[wv][fr][ksl * 32 + ko];
#pragma unroll
        for (int n = 0; n < 8; n++)
#pragma unroll
            for (int ksl = 0; ksl < 2; ksl++) {
                bf8 vf = *(const bf8*)&Vl[n * 16 + fr][ksl * 32 + ko];
                o[n] = __builtin_amdgcn_mfma_f32_16x16x32_bf16(pf[ksl], vf, o[n], 0, 0, 0);
            }
    }
    // ---- epilogue: normalize, store to (B,S,NH*DV) ----
#pragma unroll
    for (int i = 0; i < 4; i++) {
        float inv = 1.f / lrow[i];
        long rbase = ((long)b * S_ + q0 + wv * 16 + lg * 4 + i) * H_ + h * DV_;
#pragma unroll
        for (int n = 0; n < 8; n++)
            ab[rbase + n * 16 + fr] = f2bf(o[n][i] * inv);
    }
}

// ---------------------------------------------------------------------------
// weight conversion kernels (fp32 -> bf16), vectorized x4
// ---------------------------------------------------------------------------
__global__ __launch_bounds__(256) void cvt_k(
    const float* __restrict__ s, unsigned short* __restrict__ d, long n)
{
    long i = ((long)blockIdx.x * 256 + threadIdx.x) * 4;
    if (i < n) {
        f4 v = *(const f4*)(s + i);
        d[i] = f2bf(v[0]); d[i + 1] = f2bf(v[1]); d[i + 2] = f2bf(v[2]); d[i + 3] = f2bf(v[3]);
    }
}

__global__ __launch_bounds__(256) void cvt_pad_k(
    const float* __restrict__ s, unsigned short* __restrict__ d)
{
    long i = ((long)blockIdx.x * 256 + threadIdx.x) * 4;   // over 640*2048
    long row = i >> 11;
    if (row < 576) {
        f4 v = *(const f4*)(s + i);
        d[i] = f2bf(v[0]); d[i + 1] = f2bf(v[1]); d[i + 2] = f2bf(v[2]); d[i + 3] = f2bf(v[3]);
    } else {
        d[i] = 0; d[i + 1] = 0; d[i + 2] = 0; d[i + 3] = 0;
    }
}

__global__ __launch_bounds__(256) void cvt_cat_k(
    const float* __restrict__ g, const float* __restrict__ u,
    unsigned short* __restrict__ d)
{
    long ii = ((long)blockIdx.x * 256 + threadIdx.x) * 4;   // 1536*2048 per expert
    int e = blockIdx.y;
    long row = ii >> 11, col = ii & 2047;
    const float* src = (row < INTER_)
        ? (g + ((long)e * INTER_ + row) * H_ + col)
        : (u + ((long)e * INTER_ + row - INTER_) * H_ + col);
    f4 v = *(const f4*)src;
    unsigned short* dd = d + (long)e * (2 * INTER_) * H_ + ii;
    dd[0] = f2bf(v[0]); dd[1] = f2bf(v[1]); dd[2] = f2bf(v[2]); dd[3] = f2bf(v[3]);
}

// ---------------------------------------------------------------------------
__global__ __launch_bounds__(256) void rmsnorm_f2b(
    const float* __restrict__ in, const float* __restrict__ w,
    unsigned short* __restrict__ ob, float* __restrict__ of, int cols)
{
    const long base = (long)blockIdx.x * cols;
    float ss = 0.f;
    for (int c = threadIdx.x; c < cols; c += 256) {
        float v = in[base + c];
        ss += v * v;
    }
#pragma unroll
    for (int o = 32; o; o >>= 1) ss += __shfl_down(ss, o);
    __shared__ float red[4];
    if ((threadIdx.x & 63) == 0) red[threadIdx.x >> 6] = ss;
    __syncthreads();
    float r = rsqrtf((red[0] + red[1] + red[2] + red[3]) / cols + EPS_);
    for (int c = threadIdx.x; c < cols; c += 256) {
        float v = in[base + c] * r * w[c];
        ob[base + c] = f2bf(v);
        if (of) of[base + c] = v;
    }
}

__global__ __launch_bounds__(256) void rmsnorm_b2b(
    const unsigned short* __restrict__ in, const float* __restrict__ w,
    unsigned short* __restrict__ out, int cols, int istride)
{
    const long ib = (long)blockIdx.x * istride;
    const long ob = (long)blockIdx.x * cols;
    float ss = 0.f;
    for (int c = threadIdx.x; c < cols; c += 256) {
        float v = bf2f(in[ib + c]);
        ss += v * v;
    }
#pragma unroll
    for (int o = 32; o; o >>= 1) ss += __shfl_down(ss, o);
    __shared__ float red[4];
    if ((threadIdx.x & 63) == 0) red[threadIdx.x >> 6] = ss;
    __syncthreads();
    float r = rsqrtf((red[0] + red[1] + red[2] + red[3]) / cols + EPS_);
    for (int c = threadIdx.x; c < cols; c += 256)
        out[ob + c] = f2bf(bf2f(in[ib + c]) * r * w[c]);
}

// ---------------------------------------------------------------------------
__global__ __launch_bounds__(64) void rope_q_k(
    const unsigned short* __restrict__ q, const float* __restrict__ cs,
    const float* __restrict__ sn, unsigned short* __restrict__ qs)
{
    int t = blockIdx.x;            // (b*S+s)*16 + h
    int h = t & 15;
    int bs = t >> 4;
    int s = bs & (S_ - 1);
    int b = bs >> 10;
    const unsigned short* qrow = q + (long)bs * (NH_ * DQK_) + h * DQK_;
    unsigned short* orow = qs + ((long)(b * NH_ + h) * S_ + s) * DQK_;
    int l = threadIdx.x;
    orow[l] = qrow[l];
    orow[l + 64] = qrow[l + 64];
    int j = l & 31;
    float x0 = bf2f(qrow[DN_ + 2 * j]), x1 = bf2f(qrow[DN_ + 2 * j + 1]);
    float c = cs[(long)bs * DR_ + j], si = sn[(long)bs * DR_ + j];
    if (l < 32) orow[DN_ + j] = f2bf(x0 * c - x1 * si);
    else        orow[DN_ + 32 + j] = f2bf(x1 * c + x0 * si);
}

__global__ __launch_bounds__(64) void rope_k_k(
    const unsigned short* __restrict__ ckv, const float* __restrict__ cs,
    const float* __restrict__ sn, unsigned short* __restrict__ ks)
{
    int bs = blockIdx.x;
    int s = bs & (S_ - 1);
    int b = bs >> 10;
    const unsigned short* kr = ckv + (long)bs * 640 + KVL_;
    int l = threadIdx.x;
    int j = l & 31;
    float x0 = bf2f(kr[2 * j]), x1 = bf2f(kr[2 * j + 1]);
    float c = cs[(long)bs * DR_ + j], si = sn[(long)bs * DR_ + j];
    float val = (l < 32) ? (x0 * c - x1 * si) : (x1 * c + x0 * si);
    int off = (l < 32) ? (DN_ + j) : (DN_ + 32 + j);
    unsigned short bv = f2bf(val);
    for (int h = 0; h < NH_; h++)
        ks[((long)(b * NH_ + h) * S_ + s) * DQK_ + off] = bv;
}

__global__ __launch_bounds__(128) void kpass_k(
    const unsigned short* __restrict__ kv, unsigned short* __restrict__ ks)
{
    int t = blockIdx.x; // (b*S+s)*16 + h
    int h = t & 15;
    int bs = t >> 4;
    int s = bs & (S_ - 1);
    int b = bs >> 10;
    ks[((long)(b * NH_ + h) * S_ + s) * DQK_ + threadIdx.x] = kv[(long)t * 256 + threadIdx.x];
}

__global__ __launch_bounds__(256) void vt_k(
    const unsigned short* __restrict__ kv, unsigned short* __restrict__ vt)
{
    __shared__ unsigned short tile[64][DV_ + 8];
    int s0 = blockIdx.x * 64;
    int bh = blockIdx.y;
    int b = bh >> 4, h = bh & 15;
    for (int it = 0; it < 32; it++) {
        int idx = it * 256 + threadIdx.x;
        int sl = idx >> 7, d = idx & 127;
        tile[sl][d] = kv[((long)(b * S_ + s0 + sl) * NH_ + h) * 256 + DN_ + d];
    }
    __syncthreads();
    for (int it = 0; it < 32; it++) {
        int idx = it * 256 + threadIdx.x;
        int d = idx >> 6, sl = idx & 63;
        vt[((long)bh * DV_ + d) * S_ + s0 + sl] = tile[sl][d];
    }
}

__global__ void zero8_k(int* __restrict__ cnt)
{
    if (threadIdx.x < NEXP_) cnt[threadIdx.x] = 0;
}

__global__ void offs_k(const int* __restrict__ cnt, int* __restrict__ off)
{
    if (threadIdx.x == 0) {
        int a = 0;
        for (int e = 0; e < NEXP_; e++) { off[e] = a; a += cnt[e]; }
    }
}

__global__ __launch_bounds__(64) void router_k(
    const float* __restrict__ h, const float* __restrict__ rw,
    const float* __restrict__ rb, int* __restrict__ cnt,
    int* __restrict__ idxl, float* __restrict__ wl)
{
    int t = blockIdx.x;
    int l = threadIdx.x;
    const float* hr = h + (long)t * H_;
    float pe[8] = {0, 0, 0, 0, 0, 0, 0, 0};
    for (int k = l; k < H_; k += 64) {
        float hv = hr[k];
#pragma unroll
        for (int e = 0; e < 8; e++) pe[e] += hv * rw[e * H_ + k];
    }
#pragma unroll
    for (int e = 0; e < 8; e++)
        for (int o = 32; o; o >>= 1) pe[e] += __shfl_down(pe[e], o);
    if (l == 0) {
        float sr[8], sc[8];
#pragma unroll
        for (int e = 0; e < 8; e++) {
            sr[e] = 1.f / (1.f + __expf(-pe[e]));
            sc[e] = sr[e] + rb[e];
        }
        float gs[4];
        for (int g = 0; g < 4; g++) gs[g] = sc[2 * g] + sc[2 * g + 1];
        int g0 = 0;
        for (int g = 1; g < 4; g++) if (gs[g] > gs[g0]) g0 = g;
        int g1 = -1;
        for (int g = 0; g < 4; g++) {
            if (g == g0) continue;
            if (g1 < 0 || gs[g] > gs[g1]) g1 = g;
        }
        int i0 = -1, i1 = -1;
        for (int e = 0; e < 8; e++) {
            int g = e >> 1;
            if (g != g0 && g != g1) continue;
            if (i0 < 0 || sc[e] > sc[i0]) i0 = e;
        }
        for (int e = 0; e < 8; e++) {
            int g = e >> 1;
            if (g != g0 && g != g1) continue;
            if (e == i0) continue;
            if (i1 < 0 || sc[e] > sc[i1]) i1 = e;
        }
        float w0 = sr[i0], w1 = sr[i1];
        float inv = 2.5f / (w0 + w1 + 1e-20f);
        int p0 = atomicAdd(&cnt[i0], 1);
        idxl[i0 * T_ + p0] = t;
        wl[i0 * T_ + p0] = w0 * inv;
        int p1 = atomicAdd(&cnt[i1], 1);
        idxl[i1 * T_ + p1] = t;
        wl[i1 * T_ + p1] = w1 * inv;
    }
}

// act[r][c] = silu(gu[r][c]) * gu[r][768+c], bf16; grid (rows, 3) x 256
__global__ __launch_bounds__(256) void silugu_k(
    const unsigned short* __restrict__ gu, unsigned short* __restrict__ act)
{
    int r = blockIdx.x;
    int c = blockIdx.y * 256 + threadIdx.x;
    float g = bf2f(gu[(long)r * (2 * INTER_) + c]);
    float u = bf2f(gu[(long)r * (2 * INTER_) + INTER_ + c]);
    act[(long)r * INTER_ + c] = f2bf(g / (1.f + __expf(-g)) * u);
}

// ---------------------------------------------------------------------------
extern "C" void kernel_launch(void* const* d_in, const int* in_sizes, int n_in,
                              void* d_out, int out_size, void* d_ws, size_t ws_size,
                              hipStream_t stream)
{
    const float* hidden = (const float*)d_in[0];
    const float* cosb   = (const float*)d_in[1];
    const float* sinb   = (const float*)d_in[2];
    const float* ln1w   = (const float*)d_in[3];
    const float* qaw    = (const float*)d_in[4];
    const float* qalnw  = (const float*)d_in[5];
    const float* qbw    = (const float*)d_in[6];
    const float* kvaw   = (const float*)d_in[7];
    const float* kvalnw = (const float*)d_in[8];
    const float* kvbw   = (const float*)d_in[9];
    const float* ow     = (const float*)d_in[10];
    const float* ln2w   = (const float*)d_in[11];
    const float* rw     = (const float*)d_in[12];
    const float* rb     = (const float*)d_in[13];
    const float* gw     = (const float*)d_in[14];
    const float* uw     = (const float*)d_in[15];
    const float* dwn    = (const float*)d_in[16];
    const float* sgw    = (const float*)d_in[17];
    const float* suw    = (const float*)d_in[18];
    const float* sdw    = (const float*)d_in[19];
    float* out = (float*)d_out;
    (void)in_sizes; (void)n_in; (void)out_size; (void)ws_size;

    char* ws = (char*)d_ws;
    const size_t MB = 1u << 20;
    // ---- phase A (attention) layout, MiB offsets, peak ~101 ----
    unsigned short* qawb  = (unsigned short*)(ws + 0 * MB);   // 6
    unsigned short* qbwb  = (unsigned short*)(ws + 6 * MB);   // 9
    unsigned short* kvawb = (unsigned short*)(ws + 15 * MB);  // 2.5 (640x2048)
    unsigned short* kvbwb = (unsigned short*)(ws + 18 * MB);  // 4
    unsigned short* owb   = (unsigned short*)(ws + 22 * MB);  // 8
    unsigned short* xb    = (unsigned short*)(ws + 30 * MB);  // 8
    unsigned short* qab   = (unsigned short*)(ws + 38 * MB);  // 6
    unsigned short* qb16  = (unsigned short*)(ws + 44 * MB);  // 12
    unsigned short* ckvb  = (unsigned short*)(ws + 56 * MB);  // 2.5 (T x 640)
    unsigned short* ckvnb = (unsigned short*)(ws + 59 * MB);  // 2
    unsigned short* kvb   = (unsigned short*)(ws + 61 * MB);  // 16
    unsigned short* qs    = (unsigned short*)(ws + 77 * MB);  // 12
    unsigned short* ks    = (unsigned short*)(ws + 89 * MB);  // 12
    unsigned short* vt    = (unsigned short*)(ws + 30 * MB);  // 8  (alias xb)
    unsigned short* ab    = (unsigned short*)(ws + 38 * MB);  // 8  (alias qab/qb16)
    // ---- phase B (MoE) layout, peak ~102 ----
    float* hbuf = (float*)(ws + 0 * MB);                      // 16
    unsigned short* hb16 = (unsigned short*)(ws + 16 * MB);   // 8
    int*   cnt  = (int*)(ws + 24 * MB);
    int*   offb = (int*)(ws + 24 * MB + 256);
    int*   idxl = (int*)(ws + 24 * MB + 512);                 // 64 KB
    float* wl   = (float*)(ws + 24 * MB + 512 + 65536);       // 64 KB
    unsigned short* sguwb = (unsigned short*)(ws + 25 * MB);  // 6 (1536x2048)
    unsigned short* sdwb  = (unsigned short*)(ws + 31 * MB);  // 3
    unsigned short* guwb  = (unsigned short*)(ws + 34 * MB);  // 48 (8x1536x2048)
    unsigned short* gu    = (unsigned short*)(ws + 82 * MB);  // 12.4 (4224x1536)
    unsigned short* actm  = (unsigned short*)(ws + 95 * MB);  // 6.2 (4224x768)
    unsigned short* dwnb  = (unsigned short*)(ws + 34 * MB);  // 24 (after guwb dead)

    // ---- convert attention weights to bf16 ----
    cvt_k<<<(QL_ * H_) / 1024, 256, 0, stream>>>(qaw, qawb, (long)QL_ * H_);
    cvt_k<<<(NH_ * DQK_ * QL_) / 1024, 256, 0, stream>>>(qbw, qbwb, (long)NH_ * DQK_ * QL_);
    cvt_pad_k<<<(640 * H_) / 1024, 256, 0, stream>>>(kvaw, kvawb);
    cvt_k<<<(NH_ * 256 * KVL_) / 1024, 256, 0, stream>>>(kvbw, kvbwb, (long)NH_ * 256 * KVL_);
    cvt_k<<<(H_ * H_) / 1024, 256, 0, stream>>>(ow, owb, (long)H_ * H_);

    // ---- attention projections ----
    rmsnorm_f2b<<<T_, 256, 0, stream>>>(hidden, ln1w, xb, nullptr, H_);

    gemm2<0><<<dim3(T_ / 128, QL_ / 128, 1), 256, 0, stream>>>(
        xb, qawb, nullptr, qab, nullptr, nullptr, nullptr, nullptr, nullptr,
        T_, QL_, H_, 0, 0, 0);
    rmsnorm_b2b<<<T_, 256, 0, stream>>>(qab, qalnw, qab, QL_, QL_);
    gemm2<0><<<dim3(T_ / 128, (NH_ * DQK_) / 128, 1), 256, 0, stream>>>(
        qab, qbwb, nullptr, qb16, nullptr, nullptr, nullptr, nullptr, nullptr,
        T_, NH_ * DQK_, QL_, 0, 0, 0);

    gemm2<0><<<dim3(T_ / 128, 640 / 128, 1), 256, 0, stream>>>(
        xb, kvawb, nullptr, ckvb, nullptr, nullptr, nullptr, nullptr, nullptr,
        T_, 640, H_, 0, 0, 0);
    rmsnorm_b2b<<<T_, 256, 0, stream>>>(ckvb, kvalnw, ckvnb, KVL_, 640);
    gemm2<0><<<dim3(T_ / 128, (NH_ * 256) / 128, 1), 256, 0, stream>>>(
        ckvnb, kvbwb, nullptr, kvb, nullptr, nullptr, nullptr, nullptr, nullptr,
        T_, NH_ * 256, KVL_, 0, 0, 0);

    // ---- assemble qs / ks / vt ----
    rope_q_k<<<T_ * NH_, 64, 0, stream>>>(qb16, cosb, sinb, qs);
    rope_k_k<<<T_, 64, 0, stream>>>(ckvb, cosb, sinb, ks);
    kpass_k<<<T_ * NH_, 128, 0, stream>>>(kvb, ks);
    vt_k<<<dim3(S_ / 64, B_ * NH_), 256, 0, stream>>>(kvb, vt);

    // ---- flash attention (causal, online softmax) ----
    fa_k<<<dim3(S_ / 64, B_ * NH_), 256, 0, stream>>>(qs, ks, vt, ab);

    // ---- o-proj + residual: out = attn @ ow^T + hidden ----
    gemm2<0><<<dim3(T_ / 128, H_ / 128, 1), 256, 0, stream>>>(
        ab, owb, out, nullptr, hidden, nullptr, nullptr, nullptr, nullptr,
        T_, H_, H_, 0, 0, 0);

    // ---- MoE prep ----
    rmsnorm_f2b<<<T_, 256, 0, stream>>>(out, ln2w, hb16, hbuf, H_);
    zero8_k<<<1, 64, 0, stream>>>(cnt);
    router_k<<<T_, 64, 0, stream>>>(hbuf, rw, rb, cnt, idxl, wl);
    offs_k<<<1, 64, 0, stream>>>(cnt, offb);

    // ---- convert MoE/shared weights ----
    cvt_cat_k<<<dim3((2 * INTER_ * H_) / 1024, 1), 256, 0, stream>>>(sgw, suw, sguwb);
    cvt_k<<<(H_ * INTER_) / 1024, 256, 0, stream>>>(sdw, sdwb, (long)H_ * INTER_);
    cvt_cat_k<<<dim3((2 * INTER_ * H_) / 1024, NEXP_), 256, 0, stream>>>(gw, uw, guwb);

    // ---- shared expert: out += silu(h@sgw^T)*(h@suw^T) @ sdw^T ----
    gemm2<0><<<dim3(T_ / 128, (2 * INTER_) / 128, 1), 256, 0, stream>>>(
        hb16, sguwb, nullptr, gu, nullptr, nullptr, nullptr, nullptr, nullptr,
        T_, 2 * INTER_, H_, 0, 0, 0);
    silugu_k<<<dim3(T_, INTER_ / 256), 256, 0, stream>>>(gu, actm);
    gemm2<0><<<dim3(T_ / 128, H_ / 128, 1), 256, 0, stream>>>(
        actm, sdwb, out, nullptr, out, nullptr, nullptr, nullptr, nullptr,
        T_, H_, INTER_, 0, 0, 0);

    // ---- routed experts (top-2): gather -> gate+up -> silu -> down+scatter ----
    gemm2<1><<<dim3(T_ / 128, (2 * INTER_) / 128, NEXP_), 256, 0, stream>>>(
        hb16, guwb, nullptr, gu, nullptr, cnt, offb, idxl, nullptr,
        T_, 2 * INTER_, H_, 0, (long)(2 * INTER_) * H_, 0);
    silugu_k<<<dim3(2 * T_ + 128, INTER_ / 256), 256, 0, stream>>>(gu, actm);
    cvt_k<<<(NEXP_ * H_ * INTER_) / 1024, 256, 0, stream>>>(dwn, dwnb, (long)NEXP_ * H_ * INTER_);
    gemm2<2><<<dim3(T_ / 128, H_ / 128, NEXP_), 256, 0, stream>>>(
        actm, dwnb, out, nullptr, nullptr, cnt, offb, idxl, wl,
        T_, H_, INTER_, 0, (long)H_ * INTER_, 0);
}

// Round 6
// 729.045 us; speedup vs baseline: 3.5063x; 1.1242x over previous
//
#include <hip/hip_runtime.h>

typedef float f4 __attribute__((ext_vector_type(4)));
typedef float f32x4 __attribute__((ext_vector_type(4)));
typedef unsigned short us8 __attribute__((ext_vector_type(8)));
typedef __bf16 bf8 __attribute__((ext_vector_type(8)));

static constexpr int B_ = 2, S_ = 1024, H_ = 2048, T_ = B_ * S_;
static constexpr int NH_ = 16, DN_ = 128, DR_ = 64, DV_ = 128, DQK_ = 192;
static constexpr int KVL_ = 512, QL_ = 1536, INTER_ = 768, NEXP_ = 8, NE9_ = 9;
static constexpr int QKA_ = 2176;  // 1536 (q_a) + 576 (kv_a) + 64 pad
static constexpr float SCALING_ = 0.07216878364870322f; // 192^-0.5
static constexpr float EPS_ = 1e-6f;

__device__ __forceinline__ unsigned short f2bf(float f) {
    unsigned u = __float_as_uint(f);
    u += 0x7fffu + ((u >> 16) & 1u);
    return (unsigned short)(u >> 16);
}
__device__ __forceinline__ float bf2f(unsigned short h) {
    return __uint_as_float(((unsigned)h) << 16);
}

// async 16B/lane global->LDS. LDS dest = wave-uniform base + lane*16 (HW).
__device__ __forceinline__ void gload16(const unsigned short* g, unsigned short* lds) {
    __builtin_amdgcn_global_load_lds(
        (const __attribute__((address_space(1))) void*)g,
        (__attribute__((address_space(3))) void*)lds, 16, 0, 0);
}

// ---------------------------------------------------------------------------
// gemm2: C[M,N] = A[M,K] * B[N,K]^T, bf16 in, 128x128 tile, BK=32.
// 3-buffer depth-2 pipeline with COUNTED vmcnt (T4): per K-step
//   waitcnt vmcnt(4) -> s_barrier -> stage(t+2) -> compute(t)
// so the t+1 tile's 4 global_load_lds stay in flight across the barrier.
// A row stride = ldA (allows strided views of a wider matrix).
// MODE 0: plain. Cb -> bf16; else Cf (+add) fp32.
// MODE 1: MoE gate+up: A rows gathered via idxl[e], C bf16 compacted at off[e].
// MODE 2: MoE down: A rows compacted at off[e], atomic scatter out[tok] += w*acc.
// ---------------------------------------------------------------------------
template <int MODE>
__global__ __launch_bounds__(256) void gemm2(
    const unsigned short* __restrict__ A, const unsigned short* __restrict__ Bw,
    float* __restrict__ Cf, unsigned short* __restrict__ Cb,
    const float* __restrict__ add,
    const int* __restrict__ cnt, const int* __restrict__ off,
    const int* __restrict__ idxl, const float* __restrict__ wl,
    int M, int N, int K, int ldA, long sB)
{
    constexpr int BM = 128, BN = 128, BK = 32;
    __shared__ __align__(16) unsigned short As[3][BM * BK];
    __shared__ __align__(16) unsigned short Bs[3][BN * BK];
    const int tid = threadIdx.x, lane = tid & 63, wv = tid >> 6;
    const int wm = (wv >> 1) * 64, wn = (wv & 1) * 64;
    const int m0 = blockIdx.x * BM, n0 = blockIdx.y * BN;

    int mcnt = M, obase = 0;
    if constexpr (MODE != 0) {
        mcnt = cnt[blockIdx.z];
        if (m0 >= mcnt) return;
        obase = off[blockIdx.z];
    }

    const int srow = tid >> 2, scol = (tid & 3) * 8;
    long aoff0, aoff1;
    if constexpr (MODE == 1) {
        const int e = blockIdx.z;
        int r0 = m0 + srow, r1 = r0 + 64;
        int t0 = idxl[(long)e * T_ + (r0 < mcnt ? r0 : mcnt - 1)];
        int t1 = idxl[(long)e * T_ + (r1 < mcnt ? r1 : mcnt - 1)];
        aoff0 = (long)t0 * ldA + scol;
        aoff1 = (long)t1 * ldA + scol;
    } else if constexpr (MODE == 2) {
        aoff0 = (long)(obase + m0 + srow) * ldA + scol;
        aoff1 = aoff0 + 64L * ldA;
    } else {
        aoff0 = (long)(m0 + srow) * ldA + scol;
        aoff1 = aoff0 + 64L * ldA;
    }
    long boff0 = (long)blockIdx.z * sB + (long)(n0 + srow) * K + scol;
    long boff1 = boff0 + 64L * K;

    f32x4 acc[4][4];
#pragma unroll
    for (int m = 0; m < 4; m++)
#pragma unroll
        for (int n = 0; n < 4; n++) acc[m][n] = f32x4{0.f, 0.f, 0.f, 0.f};

    const int fr = lane & 15, ko = (lane >> 4) * 8;

    auto stage = [&](int buf, int k0) {
        gload16(A + aoff0 + k0, &As[buf][wv * 512]);
        gload16(A + aoff1 + k0, &As[buf][2048 + wv * 512]);
        gload16(Bw + boff0 + k0, &Bs[buf][wv * 512]);
        gload16(Bw + boff1 + k0, &Bs[buf][2048 + wv * 512]);
    };
    auto compute = [&](int buf) {
        bf8 af[4], bfv[4];
#pragma unroll
        for (int m = 0; m < 4; m++) af[m] = *(const bf8*)&As[buf][(wm + m * 16 + fr) * 32 + ko];
#pragma unroll
        for (int n = 0; n < 4; n++) bfv[n] = *(const bf8*)&Bs[buf][(wn + n * 16 + fr) * 32 + ko];
#pragma unroll
        for (int m = 0; m < 4; m++)
#pragma unroll
            for (int n = 0; n < 4; n++)
                acc[m][n] = __builtin_amdgcn_mfma_f32_16x16x32_bf16(af[m], bfv[n], acc[m][n], 0, 0, 0);
    };

    const int nt = K / BK;     // >= 16 at every call site
    stage(0, 0);
    stage(1, BK);
    for (int t = 0; t < nt; t++) {
        if (t < nt - 1) {
            asm volatile("s_waitcnt vmcnt(4)" ::: "memory");   // tile t landed; t+1 in flight
        } else {
            asm volatile("s_waitcnt vmcnt(0)" ::: "memory");
        }
        __builtin_amdgcn_s_barrier();
        if (t + 2 < nt) stage((t + 2) % 3, (t + 2) * BK);
        compute(t % 3);
    }

#pragma unroll
    for (int m = 0; m < 4; m++) {
#pragma unroll
        for (int n = 0; n < 4; n++) {
#pragma unroll
            for (int i = 0; i < 4; i++) {
                int row = wm + m * 16 + (lane >> 4) * 4 + i;   // local row
                int col = n0 + wn + n * 16 + (lane & 15);
                float v = acc[m][n][i];
                if constexpr (MODE == 0) {
                    long idx = (long)(m0 + row) * N + col;
                    if (Cb)       Cb[idx] = f2bf(v);
                    else if (add) Cf[idx] = v + add[idx];
                    else          Cf[idx] = v;
                } else if constexpr (MODE == 1) {
                    if (m0 + row < mcnt)
                        Cb[(long)(obase + m0 + row) * N + col] = f2bf(v);
                } else {
                    if (m0 + row < mcnt) {
                        int e = blockIdx.z;
                        int tok = idxl[(long)e * T_ + m0 + row];
                        float w = wl[(long)e * T_ + m0 + row];
                        atomicAdd(&Cf[(long)tok * N + col], w * v);
                    }
                }
            }
        }
    }
}

// ---------------------------------------------------------------------------
// Flash attention (causal). grid (S/64, B*NH), 256 threads (4 waves).
// ---------------------------------------------------------------------------
__global__ __launch_bounds__(256) void fa_k(
    const unsigned short* __restrict__ qs, const unsigned short* __restrict__ ks,
    const unsigned short* __restrict__ vt, unsigned short* __restrict__ ab)
{
    constexpr int KB = 64;
    const int q0 = blockIdx.x * 64;
    const int bh = blockIdx.y;
    const int b = bh >> 4, h = bh & 15;
    const int tid = threadIdx.x, lane = tid & 63, wv = tid >> 6;
    const int fr = lane & 15, lg = lane >> 4;
    const int ko = lg * 8;

    __shared__ __align__(16) unsigned short Kl[KB][200];
    __shared__ __align__(16) unsigned short Vl[128][72];
    __shared__ __align__(16) unsigned short Pl[4][16][72];

    const unsigned short* qp = qs + ((long)bh * S_ + q0 + wv * 16 + fr) * DQK_ + ko;
    bf8 qf[6];
#pragma unroll
    for (int s = 0; s < 6; s++) qf[s] = *(const bf8*)(qp + s * 32);

    f32x4 o[8];
#pragma unroll
    for (int n = 0; n < 8; n++) o[n] = f32x4{0.f, 0.f, 0.f, 0.f};
    float mrow[4] = {-3e38f, -3e38f, -3e38f, -3e38f};
    float lrow[4] = {0.f, 0.f, 0.f, 0.f};

    const int nt = q0 / KB + 1;

    const unsigned short* kg = ks + ((long)bh * S_ + (tid >> 2)) * DQK_ + (tid & 3) * 48;
    const unsigned short* vg = vt + ((long)bh * DV_ + (tid >> 1)) * S_ + (tid & 1) * 32;

    us8 krg[6], vrg[4];
#pragma unroll
    for (int j = 0; j < 6; j++) krg[j] = *(const us8*)(kg + j * 8);
#pragma unroll
    for (int j = 0; j < 4; j++) vrg[j] = *(const us8*)(vg + j * 8);

    for (int t = 0; t < nt; t++) {
        __syncthreads();
        {
            int r = tid >> 2, c = (tid & 3) * 48;
#pragma unroll
            for (int j = 0; j < 6; j++) *(us8*)&Kl[r][c + j * 8] = krg[j];
            int dv = tid >> 1, c2 = (tid & 1) * 32;
#pragma unroll
            for (int j = 0; j < 4; j++) *(us8*)&Vl[dv][c2 + j * 8] = vrg[j];
        }
        __syncthreads();
        if (t + 1 < nt) {
            long kof = (long)(t + 1) * KB;
#pragma unroll
            for (int j = 0; j < 6; j++) krg[j] = *(const us8*)(kg + kof * DQK_ + j * 8);
#pragma unroll
            for (int j = 0; j < 4; j++) vrg[j] = *(const us8*)(vg + kof + j * 8);
        }
        f32x4 ps[4];
#pragma unroll
        for (int ct = 0; ct < 4; ct++) {
            f32x4 a = f32x4{0.f, 0.f, 0.f, 0.f};
#pragma unroll
            for (int s = 0; s < 6; s++) {
                bf8 kf = *(const bf8*)&Kl[ct * 16 + fr][s * 32 + ko];
                a = __builtin_amdgcn_mfma_f32_16x16x32_bf16(qf[s], kf, a, 0, 0, 0);
            }
            ps[ct] = a;
        }
        const int kv0 = t * KB;
        const bool diag = (kv0 == q0);
#pragma unroll
        for (int ct = 0; ct < 4; ct++)
#pragma unroll
            for (int i = 0; i < 4; i++) {
                float v = ps[ct][i] * SCALING_;
                if (diag && (kv0 + ct * 16 + fr) > (q0 + wv * 16 + lg * 4 + i)) v = -3e38f;
                ps[ct][i] = v;
            }
        float scl[4];
#pragma unroll
        for (int i = 0; i < 4; i++) {
            float v = fmaxf(fmaxf(ps[0][i], ps[1][i]), fmaxf(ps[2][i], ps[3][i]));
#pragma unroll
            for (int x = 8; x; x >>= 1) v = fmaxf(v, __shfl_xor(v, x, 16));
            float mn = fmaxf(mrow[i], v);
            scl[i] = __expf(mrow[i] - mn);
            mrow[i] = mn;
        }
        float tsum[4] = {0.f, 0.f, 0.f, 0.f};
#pragma unroll
        for (int ct = 0; ct < 4; ct++)
#pragma unroll
            for (int i = 0; i < 4; i++) {
                float e = __expf(ps[ct][i] - mrow[i]);
                tsum[i] += e;
                Pl[wv][lg * 4 + i][ct * 16 + fr] = f2bf(e);
            }
#pragma unroll
        for (int i = 0; i < 4; i++) {
            float v = tsum[i];
#pragma unroll
            for (int x = 8; x; x >>= 1) v += __shfl_xor(v, x, 16);
            lrow[i] = lrow[i] * scl[i] + v;
        }
#pragma unroll
        for (int n = 0; n < 8; n++)
#pragma unroll
            for (int i = 0; i < 4; i++) o[n][i] *= scl[i];
        bf8 pf[2];
#pragma unroll
        for (int ksl = 0; ksl < 2; ksl++)
            pf[ksl] = *(const bf8*)&Pl[wv][fr][ksl * 32 + ko];
#pragma unroll
        for (int n = 0; n < 8; n++)
#pragma unroll
            for (int ksl = 0; ksl < 2; ksl++) {
                bf8 vf = *(const bf8*)&Vl[n * 16 + fr][ksl * 32 + ko];
                o[n] = __builtin_amdgcn_mfma_f32_16x16x32_bf16(pf[ksl], vf, o[n], 0, 0, 0);
            }
    }
#pragma unroll
    for (int i = 0; i < 4; i++) {
        float inv = 1.f / lrow[i];
        long rbase = ((long)b * S_ + q0 + wv * 16 + lg * 4 + i) * H_ + h * DV_;
#pragma unroll
        for (int n = 0; n < 8; n++)
            ab[rbase + n * 16 + fr] = f2bf(o[n][i] * inv);
    }
}

// ---------------------------------------------------------------------------
// conversion kernels (fp32 -> bf16)
// ---------------------------------------------------------------------------
__global__ __launch_bounds__(256) void cvt_k(
    const float* __restrict__ s, unsigned short* __restrict__ d, long n)
{
    long i = ((long)blockIdx.x * 256 + threadIdx.x) * 4;
    if (i < n) {
        f4 v = *(const f4*)(s + i);
        d[i] = f2bf(v[0]); d[i + 1] = f2bf(v[1]); d[i + 2] = f2bf(v[2]); d[i + 3] = f2bf(v[3]);
    }
}

// merged q_a|kv_a weights: rows [0,1536)=qaw, [1536,2112)=kvaw, [2112,2176)=0
__global__ __launch_bounds__(256) void cvt_qka_k(
    const float* __restrict__ qa, const float* __restrict__ kva,
    unsigned short* __restrict__ d)
{
    long i = ((long)blockIdx.x * 256 + threadIdx.x) * 4;   // over 2176*2048
    long row = i >> 11, col = i & 2047;
    unsigned short* dd = d + i;
    if (row < QL_) {
        f4 v = *(const f4*)(qa + row * H_ + col);
        dd[0] = f2bf(v[0]); dd[1] = f2bf(v[1]); dd[2] = f2bf(v[2]); dd[3] = f2bf(v[3]);
    } else if (row < QL_ + 576) {
        f4 v = *(const f4*)(kva + (row - QL_) * H_ + col);
        dd[0] = f2bf(v[0]); dd[1] = f2bf(v[1]); dd[2] = f2bf(v[2]); dd[3] = f2bf(v[3]);
    } else {
        dd[0] = 0; dd[1] = 0; dd[2] = 0; dd[3] = 0;
    }
}

// 9-expert gate|up concat: z<8 routed (gw/uw), z==8 shared (sgw/suw)
__global__ __launch_bounds__(256) void cvt_cat9_k(
    const float* __restrict__ g, const float* __restrict__ u,
    const float* __restrict__ sg, const float* __restrict__ su,
    unsigned short* __restrict__ d)
{
    long ii = ((long)blockIdx.x * 256 + threadIdx.x) * 4;   // 1536*2048 per expert
    int e = blockIdx.y;
    long row = ii >> 11, col = ii & 2047;
    const float* src;
    if (row < INTER_)
        src = (e < 8) ? (g + ((long)e * INTER_ + row) * H_ + col) : (sg + row * H_ + col);
    else
        src = (e < 8) ? (u + ((long)e * INTER_ + row - INTER_) * H_ + col)
                      : (su + (row - INTER_) * H_ + col);
    f4 v = *(const f4*)src;
    unsigned short* dd = d + (long)e * (2 * INTER_) * H_ + ii;
    dd[0] = f2bf(v[0]); dd[1] = f2bf(v[1]); dd[2] = f2bf(v[2]); dd[3] = f2bf(v[3]);
}

// ---------------------------------------------------------------------------
__global__ __launch_bounds__(256) void rmsnorm_f2b(
    const float* __restrict__ in, const float* __restrict__ w,
    unsigned short* __restrict__ ob, float* __restrict__ of, int cols)
{
    const long base = (long)blockIdx.x * cols;
    float ss = 0.f;
    for (int c = threadIdx.x; c < cols; c += 256) {
        float v = in[base + c];
        ss += v * v;
    }
#pragma unroll
    for (int o = 32; o; o >>= 1) ss += __shfl_down(ss, o);
    __shared__ float red[4];
    if ((threadIdx.x & 63) == 0) red[threadIdx.x >> 6] = ss;
    __syncthreads();
    float r = rsqrtf((red[0] + red[1] + red[2] + red[3]) / cols + EPS_);
    for (int c = threadIdx.x; c < cols; c += 256) {
        float v = in[base + c] * r * w[c];
        ob[base + c] = f2bf(v);
        if (of) of[base + c] = v;
    }
}

// bf16 in (istride) -> bf16 out (ostride); in==out (same strides) is safe
__global__ __launch_bounds__(256) void rmsnorm_b2b(
    const unsigned short* __restrict__ in, const float* __restrict__ w,
    unsigned short* __restrict__ out, int cols, int istride, int ostride)
{
    const long ib = (long)blockIdx.x * istride;
    const long ob = (long)blockIdx.x * ostride;
    float ss = 0.f;
    for (int c = threadIdx.x; c < cols; c += 256) {
        float v = bf2f(in[ib + c]);
        ss += v * v;
    }
#pragma unroll
    for (int o = 32; o; o >>= 1) ss += __shfl_down(ss, o);
    __shared__ float red[4];
    if ((threadIdx.x & 63) == 0) red[threadIdx.x >> 6] = ss;
    __syncthreads();
    float r = rsqrtf((red[0] + red[1] + red[2] + red[3]) / cols + EPS_);
    for (int c = threadIdx.x; c < cols; c += 256)
        out[ob + c] = f2bf(bf2f(in[ib + c]) * r * w[c]);
}

// ---------------------------------------------------------------------------
__global__ __launch_bounds__(64) void rope_q_k(
    const unsigned short* __restrict__ q, const float* __restrict__ cs,
    const float* __restrict__ sn, unsigned short* __restrict__ qs)
{
    int t = blockIdx.x;            // (b*S+s)*16 + h
    int h = t & 15;
    int bs = t >> 4;
    int s = bs & (S_ - 1);
    int b = bs >> 10;
    const unsigned short* qrow = q + (long)bs * (NH_ * DQK_) + h * DQK_;
    unsigned short* orow = qs + ((long)(b * NH_ + h) * S_ + s) * DQK_;
    int l = threadIdx.x;
    orow[l] = qrow[l];
    orow[l + 64] = qrow[l + 64];
    int j = l & 31;
    float x0 = bf2f(qrow[DN_ + 2 * j]), x1 = bf2f(qrow[DN_ + 2 * j + 1]);
    float c = cs[(long)bs * DR_ + j], si = sn[(long)bs * DR_ + j];
    if (l < 32) orow[DN_ + j] = f2bf(x0 * c - x1 * si);
    else        orow[DN_ + 32 + j] = f2bf(x1 * c + x0 * si);
}

// k_rot lives in qkab cols [QL_+512, QL_+576), row stride QKA_
__global__ __launch_bounds__(64) void rope_k_k(
    const unsigned short* __restrict__ qkab, const float* __restrict__ cs,
    const float* __restrict__ sn, unsigned short* __restrict__ ks)
{
    int bs = blockIdx.x;
    int s = bs & (S_ - 1);
    int b = bs >> 10;
    const unsigned short* kr = qkab + (long)bs * QKA_ + QL_ + KVL_;
    int l = threadIdx.x;
    int j = l & 31;
    float x0 = bf2f(kr[2 * j]), x1 = bf2f(kr[2 * j + 1]);
    float c = cs[(long)bs * DR_ + j], si = sn[(long)bs * DR_ + j];
    float val = (l < 32) ? (x0 * c - x1 * si) : (x1 * c + x0 * si);
    int off = (l < 32) ? (DN_ + j) : (DN_ + 32 + j);
    unsigned short bv = f2bf(val);
    for (int h = 0; h < NH_; h++)
        ks[((long)(b * NH_ + h) * S_ + s) * DQK_ + off] = bv;
}

__global__ __launch_bounds__(128) void kpass_k(
    const unsigned short* __restrict__ kv, unsigned short* __restrict__ ks)
{
    int t = blockIdx.x; // (b*S+s)*16 + h
    int h = t & 15;
    int bs = t >> 4;
    int s = bs & (S_ - 1);
    int b = bs >> 10;
    ks[((long)(b * NH_ + h) * S_ + s) * DQK_ + threadIdx.x] = kv[(long)t * 256 + threadIdx.x];
}

__global__ __launch_bounds__(256) void vt_k(
    const unsigned short* __restrict__ kv, unsigned short* __restrict__ vt)
{
    __shared__ unsigned short tile[64][DV_ + 8];
    int s0 = blockIdx.x * 64;
    int bh = blockIdx.y;
    int b = bh >> 4, h = bh & 15;
    for (int it = 0; it < 32; it++) {
        int idx = it * 256 + threadIdx.x;
        int sl = idx >> 7, d = idx & 127;
        tile[sl][d] = kv[((long)(b * S_ + s0 + sl) * NH_ + h) * 256 + DN_ + d];
    }
    __syncthreads();
    for (int it = 0; it < 32; it++) {
        int idx = it * 256 + threadIdx.x;
        int d = idx >> 6, sl = idx & 63;
        vt[((long)bh * DV_ + d) * S_ + s0 + sl] = tile[sl][d];
    }
}

__global__ void zero9_k(int* __restrict__ cnt)
{
    if (threadIdx.x < NE9_) cnt[threadIdx.x] = (threadIdx.x == 8) ? T_ : 0;
}

__global__ void offs_k(const int* __restrict__ cnt, int* __restrict__ off)
{
    if (threadIdx.x == 0) {
        int a = 0;
        for (int e = 0; e < NE9_; e++) { off[e] = a; a += cnt[e]; }
    }
}

// router: top-2-of-grouped-8 scatter + identity entry for shared expert (e=8)
__global__ __launch_bounds__(64) void router_k(
    const float* __restrict__ h, const float* __restrict__ rw,
    const float* __restrict__ rb, int* __restrict__ cnt,
    int* __restrict__ idxl, float* __restrict__ wl)
{
    int t = blockIdx.x;
    int l = threadIdx.x;
    const float* hr = h + (long)t * H_;
    float pe[8] = {0, 0, 0, 0, 0, 0, 0, 0};
    for (int k = l; k < H_; k += 64) {
        float hv = hr[k];
#pragma unroll
        for (int e = 0; e < 8; e++) pe[e] += hv * rw[e * H_ + k];
    }
#pragma unroll
    for (int e = 0; e < 8; e++)
        for (int o = 32; o; o >>= 1) pe[e] += __shfl_down(pe[e], o);
    if (l == 0) {
        float sr[8], sc[8];
#pragma unroll
        for (int e = 0; e < 8; e++) {
            sr[e] = 1.f / (1.f + __expf(-pe[e]));
            sc[e] = sr[e] + rb[e];
        }
        float gs[4];
        for (int g = 0; g < 4; g++) gs[g] = sc[2 * g] + sc[2 * g + 1];
        int g0 = 0;
        for (int g = 1; g < 4; g++) if (gs[g] > gs[g0]) g0 = g;
        int g1 = -1;
        for (int g = 0; g < 4; g++) {
            if (g == g0) continue;
            if (g1 < 0 || gs[g] > gs[g1]) g1 = g;
        }
        int i0 = -1, i1 = -1;
        for (int e = 0; e < 8; e++) {
            int g = e >> 1;
            if (g != g0 && g != g1) continue;
            if (i0 < 0 || sc[e] > sc[i0]) i0 = e;
        }
        for (int e = 0; e < 8; e++) {
            int g = e >> 1;
            if (g != g0 && g != g1) continue;
            if (e == i0) continue;
            if (i1 < 0 || sc[e] > sc[i1]) i1 = e;
        }
        float w0 = sr[i0], w1 = sr[i1];
        float inv = 2.5f / (w0 + w1 + 1e-20f);
        int p0 = atomicAdd(&cnt[i0], 1);
        idxl[i0 * T_ + p0] = t;
        wl[i0 * T_ + p0] = w0 * inv;
        int p1 = atomicAdd(&cnt[i1], 1);
        idxl[i1 * T_ + p1] = t;
        wl[i1 * T_ + p1] = w1 * inv;
        idxl[8 * T_ + t] = t;      // shared expert: identity list, weight 1
        wl[8 * T_ + t] = 1.0f;
    }
}

// act[r][c] = silu(gu[r][c]) * gu[r][768+c]; grid (rows, 3) x 256
__global__ __launch_bounds__(256) void silugu_k(
    const unsigned short* __restrict__ gu, unsigned short* __restrict__ act)
{
    int r = blockIdx.x;
    int c = blockIdx.y * 256 + threadIdx.x;
    float g = bf2f(gu[(long)r * (2 * INTER_) + c]);
    float u = bf2f(gu[(long)r * (2 * INTER_) + INTER_ + c]);
    act[(long)r * INTER_ + c] = f2bf(g / (1.f + __expf(-g)) * u);
}

// ---------------------------------------------------------------------------
extern "C" void kernel_launch(void* const* d_in, const int* in_sizes, int n_in,
                              void* d_out, int out_size, void* d_ws, size_t ws_size,
                              hipStream_t stream)
{
    const float* hidden = (const float*)d_in[0];
    const float* cosb   = (const float*)d_in[1];
    const float* sinb   = (const float*)d_in[2];
    const float* ln1w   = (const float*)d_in[3];
    const float* qaw    = (const float*)d_in[4];
    const float* qalnw  = (const float*)d_in[5];
    const float* qbw    = (const float*)d_in[6];
    const float* kvaw   = (const float*)d_in[7];
    const float* kvalnw = (const float*)d_in[8];
    const float* kvbw   = (const float*)d_in[9];
    const float* ow     = (const float*)d_in[10];
    const float* ln2w   = (const float*)d_in[11];
    const float* rw     = (const float*)d_in[12];
    const float* rb     = (const float*)d_in[13];
    const float* gw     = (const float*)d_in[14];
    const float* uw     = (const float*)d_in[15];
    const float* dwn    = (const float*)d_in[16];
    const float* sgw    = (const float*)d_in[17];
    const float* suw    = (const float*)d_in[18];
    const float* sdw    = (const float*)d_in[19];
    float* out = (float*)d_out;
    (void)in_sizes; (void)n_in; (void)out_size; (void)ws_size;

    char* ws = (char*)d_ws;
    const size_t MB = 1u << 20;
    // ---- phase A (attention), MiB offsets, peak ~101 ----
    unsigned short* qkawb = (unsigned short*)(ws + 0 * MB);   // 8.5 (2176x2048)
    unsigned short* qbwb  = (unsigned short*)(ws + 9 * MB);   // 9
    unsigned short* kvbwb = (unsigned short*)(ws + 18 * MB);  // 4
    unsigned short* owb   = (unsigned short*)(ws + 22 * MB);  // 8
    unsigned short* xb    = (unsigned short*)(ws + 30 * MB);  // 8
    unsigned short* qkab  = (unsigned short*)(ws + 38 * MB);  // 8.5 (T x 2176)
    unsigned short* qb16  = (unsigned short*)(ws + 47 * MB);  // 12
    unsigned short* ckvnb = (unsigned short*)(ws + 59 * MB);  // 2
    unsigned short* kvb   = (unsigned short*)(ws + 61 * MB);  // 16
    unsigned short* qs    = (unsigned short*)(ws + 77 * MB);  // 12
    unsigned short* ks    = (unsigned short*)(ws + 89 * MB);  // 12
    unsigned short* vt    = (unsigned short*)(ws + 30 * MB);  // 8  (alias xb)
    unsigned short* ab    = (unsigned short*)(ws + 38 * MB);  // 8  (alias qkab, dead by FA)
    // ---- phase B (MoE), peak ~98 ----
    float* hbuf = (float*)(ws + 0 * MB);                      // 16 (dead after router)
    unsigned short* actm = (unsigned short*)(ws + 0 * MB);    // 9.4 (6144x768, after router)
    unsigned short* hb16 = (unsigned short*)(ws + 16 * MB);   // 8
    int*   cnt  = (int*)(ws + 24 * MB);
    int*   offb = (int*)(ws + 24 * MB + 256);
    int*   idxl = (int*)(ws + 24 * MB + 512);                 // 72 KB (9 x T)
    float* wl   = (float*)(ws + 24 * MB + 512 + 9 * T_ * 4);  // 72 KB
    unsigned short* guwb = (unsigned short*)(ws + 25 * MB);   // 54 (9x1536x2048)
    unsigned short* dwnb = (unsigned short*)(ws + 25 * MB);   // 27 (alias guwb, after gu GEMM)
    unsigned short* gu   = (unsigned short*)(ws + 79 * MB);   // 18.9 (6144x1536)

    // ---- weight conversion (attention) ----
    cvt_qka_k<<<(QKA_ * H_) / 1024, 256, 0, stream>>>(qaw, kvaw, qkawb);
    cvt_k<<<(NH_ * DQK_ * QL_) / 1024, 256, 0, stream>>>(qbw, qbwb, (long)NH_ * DQK_ * QL_);
    cvt_k<<<(NH_ * 256 * KVL_) / 1024, 256, 0, stream>>>(kvbw, kvbwb, (long)NH_ * 256 * KVL_);
    cvt_k<<<(H_ * H_) / 1024, 256, 0, stream>>>(ow, owb, (long)H_ * H_);

    // ---- attention projections ----
    rmsnorm_f2b<<<T_, 256, 0, stream>>>(hidden, ln1w, xb, nullptr, H_);

    // merged q_a | kv_a projection: qkab = xb @ qkawb^T  (N=2176)
    gemm2<0><<<dim3(T_ / 128, QKA_ / 128, 1), 256, 0, stream>>>(
        xb, qkawb, nullptr, qkab, nullptr, nullptr, nullptr, nullptr, nullptr,
        T_, QKA_, H_, H_, 0);
    rmsnorm_b2b<<<T_, 256, 0, stream>>>(qkab, qalnw, qkab, QL_, QKA_, QKA_);       // q_a norm in-place
    gemm2<0><<<dim3(T_ / 128, (NH_ * DQK_) / 128, 1), 256, 0, stream>>>(
        qkab, qbwb, nullptr, qb16, nullptr, nullptr, nullptr, nullptr, nullptr,
        T_, NH_ * DQK_, QL_, QKA_, 0);
    rmsnorm_b2b<<<T_, 256, 0, stream>>>(qkab + QL_, kvalnw, ckvnb, KVL_, QKA_, KVL_); // kv_a norm
    gemm2<0><<<dim3(T_ / 128, (NH_ * 256) / 128, 1), 256, 0, stream>>>(
        ckvnb, kvbwb, nullptr, kvb, nullptr, nullptr, nullptr, nullptr, nullptr,
        T_, NH_ * 256, KVL_, KVL_, 0);

    // ---- assemble qs / ks / vt ----
    rope_q_k<<<T_ * NH_, 64, 0, stream>>>(qb16, cosb, sinb, qs);
    rope_k_k<<<T_, 64, 0, stream>>>(qkab, cosb, sinb, ks);
    kpass_k<<<T_ * NH_, 128, 0, stream>>>(kvb, ks);
    vt_k<<<dim3(S_ / 64, B_ * NH_), 256, 0, stream>>>(kvb, vt);

    // ---- flash attention ----
    fa_k<<<dim3(S_ / 64, B_ * NH_), 256, 0, stream>>>(qs, ks, vt, ab);

    // ---- o-proj + residual: out = attn @ ow^T + hidden ----
    gemm2<0><<<dim3(T_ / 128, H_ / 128, 1), 256, 0, stream>>>(
        ab, owb, out, nullptr, hidden, nullptr, nullptr, nullptr, nullptr,
        T_, H_, H_, H_, 0);

    // ---- MoE prep ----
    rmsnorm_f2b<<<T_, 256, 0, stream>>>(out, ln2w, hb16, hbuf, H_);
    zero9_k<<<1, 64, 0, stream>>>(cnt);
    router_k<<<T_, 64, 0, stream>>>(hbuf, rw, rb, cnt, idxl, wl);
    offs_k<<<1, 64, 0, stream>>>(cnt, offb);

    // ---- 9-expert (8 routed + shared) gate+up -> silu -> down+scatter ----
    cvt_cat9_k<<<dim3((2 * INTER_ * H_) / 1024, NE9_), 256, 0, stream>>>(gw, uw, sgw, suw, guwb);
    gemm2<1><<<dim3(T_ / 128, (2 * INTER_) / 128, NE9_), 256, 0, stream>>>(
        hb16, guwb, nullptr, gu, nullptr, cnt, offb, idxl, nullptr,
        T_, 2 * INTER_, H_, H_, (long)(2 * INTER_) * H_);
    silugu_k<<<dim3(3 * T_, INTER_ / 256), 256, 0, stream>>>(gu, actm);
    cvt_k<<<(NEXP_ * H_ * INTER_) / 1024, 256, 0, stream>>>(dwn, dwnb, (long)NEXP_ * H_ * INTER_);
    cvt_k<<<(H_ * INTER_) / 1024, 256, 0, stream>>>(sdw, dwnb + (long)NEXP_ * H_ * INTER_, (long)H_ * INTER_);
    gemm2<2><<<dim3(T_ / 128, H_ / 128, NE9_), 256, 0, stream>>>(
        actm, dwnb, out, nullptr, nullptr, cnt, offb, idxl, wl,
        T_, H_, INTER_, INTER_, (long)H_ * INTER_);
}

// Round 7
// 615.731 us; speedup vs baseline: 4.1516x; 1.1840x over previous
//
#include <hip/hip_runtime.h>

typedef float f4 __attribute__((ext_vector_type(4)));
typedef float f32x4 __attribute__((ext_vector_type(4)));
typedef unsigned short us8 __attribute__((ext_vector_type(8)));
typedef __bf16 bf8 __attribute__((ext_vector_type(8)));

static constexpr int B_ = 2, S_ = 1024, H_ = 2048, T_ = B_ * S_;
static constexpr int NH_ = 16, DN_ = 128, DR_ = 64, DV_ = 128, DQK_ = 192;
static constexpr int KVL_ = 512, QL_ = 1536, INTER_ = 768, NEXP_ = 8, NE9_ = 9;
static constexpr int QKA_ = 2176;  // 1536 (q_a) + 576 (kv_a) + 64 pad
static constexpr float SCALING_ = 0.07216878364870322f; // 192^-0.5
static constexpr float EPS_ = 1e-6f;

__device__ __forceinline__ unsigned short f2bf(float f) {
    unsigned u = __float_as_uint(f);
    u += 0x7fffu + ((u >> 16) & 1u);
    return (unsigned short)(u >> 16);
}
__device__ __forceinline__ float bf2f(unsigned short h) {
    return __uint_as_float(((unsigned)h) << 16);
}

// async 16B/lane global->LDS. LDS dest = wave-uniform base + lane*16 (HW).
__device__ __forceinline__ void gload16(const unsigned short* g, unsigned short* lds) {
    __builtin_amdgcn_global_load_lds(
        (const __attribute__((address_space(1))) void*)g,
        (__attribute__((address_space(3))) void*)lds, 16, 0, 0);
}

// ---------------------------------------------------------------------------
// gemm2: C[M,N] = A[M,K] * B[N,K]^T, bf16 in, 128x128 tile, BK=32.
// 3-buffer depth-2 pipeline with COUNTED vmcnt (T4): per K-step
//   waitcnt vmcnt(4) -> s_barrier -> stage(t+2) -> compute(t).
// T1: XCD-chunked (bx,by) swizzle so same-B-panel blocks share one XCD L2.
// T5: setprio(1) around the MFMA cluster.
// MODE 0: plain. Cb -> bf16; else Cf (+add) fp32.
// MODE 1: MoE gate+up: A rows gathered via idxl[e], C bf16 compacted at off[e].
// MODE 2: MoE down: A rows compacted at off[e], atomic scatter out[tok] += w*acc.
// ---------------------------------------------------------------------------
template <int MODE>
__global__ __launch_bounds__(256) void gemm2(
    const unsigned short* __restrict__ A, const unsigned short* __restrict__ Bw,
    float* __restrict__ Cf, unsigned short* __restrict__ Cb,
    const float* __restrict__ add,
    const int* __restrict__ cnt, const int* __restrict__ off,
    const int* __restrict__ idxl, const float* __restrict__ wl,
    int M, int N, int K, int ldA, long sB)
{
    constexpr int BM = 128, BN = 128, BK = 32;
    __shared__ __align__(16) unsigned short As[3][BM * BK];
    __shared__ __align__(16) unsigned short Bs[3][BN * BK];
    const int tid = threadIdx.x, lane = tid & 63, wv = tid >> 6;
    const int wm = (wv >> 1) * 64, wn = (wv & 1) * 64;

    // T1: XCD-chunked bijective swizzle (all call sites: gridDim.x=16 -> nb%8==0)
    const int nb = gridDim.x * gridDim.y;
    const int lin = blockIdx.y * gridDim.x + blockIdx.x;
    const int swz = (lin & 7) * (nb >> 3) + (lin >> 3);
    const int bx = swz % gridDim.x;
    const int by = swz / gridDim.x;
    const int m0 = bx * BM, n0 = by * BN;

    int mcnt = M, obase = 0;
    if constexpr (MODE != 0) {
        mcnt = cnt[blockIdx.z];
        if (m0 >= mcnt) return;
        obase = off[blockIdx.z];
    }

    const int srow = tid >> 2, scol = (tid & 3) * 8;
    long aoff0, aoff1;
    if constexpr (MODE == 1) {
        const int e = blockIdx.z;
        int r0 = m0 + srow, r1 = r0 + 64;
        int t0 = idxl[(long)e * T_ + (r0 < mcnt ? r0 : mcnt - 1)];
        int t1 = idxl[(long)e * T_ + (r1 < mcnt ? r1 : mcnt - 1)];
        aoff0 = (long)t0 * ldA + scol;
        aoff1 = (long)t1 * ldA + scol;
    } else if constexpr (MODE == 2) {
        aoff0 = (long)(obase + m0 + srow) * ldA + scol;
        aoff1 = aoff0 + 64L * ldA;
    } else {
        aoff0 = (long)(m0 + srow) * ldA + scol;
        aoff1 = aoff0 + 64L * ldA;
    }
    long boff0 = (long)blockIdx.z * sB + (long)(n0 + srow) * K + scol;
    long boff1 = boff0 + 64L * K;

    f32x4 acc[4][4];
#pragma unroll
    for (int m = 0; m < 4; m++)
#pragma unroll
        for (int n = 0; n < 4; n++) acc[m][n] = f32x4{0.f, 0.f, 0.f, 0.f};

    const int fr = lane & 15, ko = (lane >> 4) * 8;

    auto stage = [&](int buf, int k0) {
        gload16(A + aoff0 + k0, &As[buf][wv * 512]);
        gload16(A + aoff1 + k0, &As[buf][2048 + wv * 512]);
        gload16(Bw + boff0 + k0, &Bs[buf][wv * 512]);
        gload16(Bw + boff1 + k0, &Bs[buf][2048 + wv * 512]);
    };
    auto compute = [&](int buf) {
        __builtin_amdgcn_s_setprio(1);
        bf8 af[4], bfv[4];
#pragma unroll
        for (int m = 0; m < 4; m++) af[m] = *(const bf8*)&As[buf][(wm + m * 16 + fr) * 32 + ko];
#pragma unroll
        for (int n = 0; n < 4; n++) bfv[n] = *(const bf8*)&Bs[buf][(wn + n * 16 + fr) * 32 + ko];
#pragma unroll
        for (int m = 0; m < 4; m++)
#pragma unroll
            for (int n = 0; n < 4; n++)
                acc[m][n] = __builtin_amdgcn_mfma_f32_16x16x32_bf16(af[m], bfv[n], acc[m][n], 0, 0, 0);
        __builtin_amdgcn_s_setprio(0);
    };

    const int nt = K / BK;     // >= 16 at every call site
    stage(0, 0);
    stage(1, BK);
    for (int t = 0; t < nt; t++) {
        if (t < nt - 1) {
            asm volatile("s_waitcnt vmcnt(4)" ::: "memory");   // tile t landed; t+1 in flight
        } else {
            asm volatile("s_waitcnt vmcnt(0)" ::: "memory");
        }
        __builtin_amdgcn_s_barrier();
        if (t + 2 < nt) stage((t + 2) % 3, (t + 2) * BK);
        compute(t % 3);
    }

#pragma unroll
    for (int m = 0; m < 4; m++) {
#pragma unroll
        for (int n = 0; n < 4; n++) {
#pragma unroll
            for (int i = 0; i < 4; i++) {
                int row = wm + m * 16 + (lane >> 4) * 4 + i;   // local row
                int col = n0 + wn + n * 16 + (lane & 15);
                float v = acc[m][n][i];
                if constexpr (MODE == 0) {
                    long idx = (long)(m0 + row) * N + col;
                    if (Cb)       Cb[idx] = f2bf(v);
                    else if (add) Cf[idx] = v + add[idx];
                    else          Cf[idx] = v;
                } else if constexpr (MODE == 1) {
                    if (m0 + row < mcnt)
                        Cb[(long)(obase + m0 + row) * N + col] = f2bf(v);
                } else {
                    if (m0 + row < mcnt) {
                        int e = blockIdx.z;
                        int tok = idxl[(long)e * T_ + m0 + row];
                        float w = wl[(long)e * T_ + m0 + row];
                        atomicAdd(&Cf[(long)tok * N + col], w * v);
                    }
                }
            }
        }
    }
}

// ---------------------------------------------------------------------------
// Flash attention (causal). grid (S/64, B*NH), 256 threads (4 waves).
// ---------------------------------------------------------------------------
__global__ __launch_bounds__(256) void fa_k(
    const unsigned short* __restrict__ qs, const unsigned short* __restrict__ ks,
    const unsigned short* __restrict__ vt, unsigned short* __restrict__ ab)
{
    constexpr int KB = 64;
    const int q0 = blockIdx.x * 64;
    const int bh = blockIdx.y;
    const int b = bh >> 4, h = bh & 15;
    const int tid = threadIdx.x, lane = tid & 63, wv = tid >> 6;
    const int fr = lane & 15, lg = lane >> 4;
    const int ko = lg * 8;

    __shared__ __align__(16) unsigned short Kl[KB][200];
    __shared__ __align__(16) unsigned short Vl[128][72];
    __shared__ __align__(16) unsigned short Pl[4][16][72];

    const unsigned short* qp = qs + ((long)bh * S_ + q0 + wv * 16 + fr) * DQK_ + ko;
    bf8 qf[6];
#pragma unroll
    for (int s = 0; s < 6; s++) qf[s] = *(const bf8*)(qp + s * 32);

    f32x4 o[8];
#pragma unroll
    for (int n = 0; n < 8; n++) o[n] = f32x4{0.f, 0.f, 0.f, 0.f};
    float mrow[4] = {-3e38f, -3e38f, -3e38f, -3e38f};
    float lrow[4] = {0.f, 0.f, 0.f, 0.f};

    const int nt = q0 / KB + 1;

    const unsigned short* kg = ks + ((long)bh * S_ + (tid >> 2)) * DQK_ + (tid & 3) * 48;
    const unsigned short* vg = vt + ((long)bh * DV_ + (tid >> 1)) * S_ + (tid & 1) * 32;

    us8 krg[6], vrg[4];
#pragma unroll
    for (int j = 0; j < 6; j++) krg[j] = *(const us8*)(kg + j * 8);
#pragma unroll
    for (int j = 0; j < 4; j++) vrg[j] = *(const us8*)(vg + j * 8);

    for (int t = 0; t < nt; t++) {
        __syncthreads();
        {
            int r = tid >> 2, c = (tid & 3) * 48;
#pragma unroll
            for (int j = 0; j < 6; j++) *(us8*)&Kl[r][c + j * 8] = krg[j];
            int dv = tid >> 1, c2 = (tid & 1) * 32;
#pragma unroll
            for (int j = 0; j < 4; j++) *(us8*)&Vl[dv][c2 + j * 8] = vrg[j];
        }
        __syncthreads();
        if (t + 1 < nt) {
            long kof = (long)(t + 1) * KB;
#pragma unroll
            for (int j = 0; j < 6; j++) krg[j] = *(const us8*)(kg + kof * DQK_ + j * 8);
#pragma unroll
            for (int j = 0; j < 4; j++) vrg[j] = *(const us8*)(vg + kof + j * 8);
        }
        f32x4 ps[4];
#pragma unroll
        for (int ct = 0; ct < 4; ct++) {
            f32x4 a = f32x4{0.f, 0.f, 0.f, 0.f};
#pragma unroll
            for (int s = 0; s < 6; s++) {
                bf8 kf = *(const bf8*)&Kl[ct * 16 + fr][s * 32 + ko];
                a = __builtin_amdgcn_mfma_f32_16x16x32_bf16(qf[s], kf, a, 0, 0, 0);
            }
            ps[ct] = a;
        }
        const int kv0 = t * KB;
        const bool diag = (kv0 == q0);
#pragma unroll
        for (int ct = 0; ct < 4; ct++)
#pragma unroll
            for (int i = 0; i < 4; i++) {
                float v = ps[ct][i] * SCALING_;
                if (diag && (kv0 + ct * 16 + fr) > (q0 + wv * 16 + lg * 4 + i)) v = -3e38f;
                ps[ct][i] = v;
            }
        float scl[4];
#pragma unroll
        for (int i = 0; i < 4; i++) {
            float v = fmaxf(fmaxf(ps[0][i], ps[1][i]), fmaxf(ps[2][i], ps[3][i]));
#pragma unroll
            for (int x = 8; x; x >>= 1) v = fmaxf(v, __shfl_xor(v, x, 16));
            float mn = fmaxf(mrow[i], v);
            scl[i] = __expf(mrow[i] - mn);
            mrow[i] = mn;
        }
        float tsum[4] = {0.f, 0.f, 0.f, 0.f};
#pragma unroll
        for (int ct = 0; ct < 4; ct++)
#pragma unroll
            for (int i = 0; i < 4; i++) {
                float e = __expf(ps[ct][i] - mrow[i]);
                tsum[i] += e;
                Pl[wv][lg * 4 + i][ct * 16 + fr] = f2bf(e);
            }
#pragma unroll
        for (int i = 0; i < 4; i++) {
            float v = tsum[i];
#pragma unroll
            for (int x = 8; x; x >>= 1) v += __shfl_xor(v, x, 16);
            lrow[i] = lrow[i] * scl[i] + v;
        }
#pragma unroll
        for (int n = 0; n < 8; n++)
#pragma unroll
            for (int i = 0; i < 4; i++) o[n][i] *= scl[i];
        bf8 pf[2];
#pragma unroll
        for (int ksl = 0; ksl < 2; ksl++)
            pf[ksl] = *(const bf8*)&Pl[wv][fr][ksl * 32 + ko];
#pragma unroll
        for (int n = 0; n < 8; n++)
#pragma unroll
            for (int ksl = 0; ksl < 2; ksl++) {
                bf8 vf = *(const bf8*)&Vl[n * 16 + fr][ksl * 32 + ko];
                o[n] = __builtin_amdgcn_mfma_f32_16x16x32_bf16(pf[ksl], vf, o[n], 0, 0, 0);
            }
    }
#pragma unroll
    for (int i = 0; i < 4; i++) {
        float inv = 1.f / lrow[i];
        long rbase = ((long)b * S_ + q0 + wv * 16 + lg * 4 + i) * H_ + h * DV_;
#pragma unroll
        for (int n = 0; n < 8; n++)
            ab[rbase + n * 16 + fr] = f2bf(o[n][i] * inv);
    }
}

// ---------------------------------------------------------------------------
// conversion kernels (fp32 -> bf16)
// ---------------------------------------------------------------------------
__global__ __launch_bounds__(256) void cvt_k(
    const float* __restrict__ s, unsigned short* __restrict__ d, long n)
{
    long i = ((long)blockIdx.x * 256 + threadIdx.x) * 4;
    if (i < n) {
        f4 v = *(const f4*)(s + i);
        d[i] = f2bf(v[0]); d[i + 1] = f2bf(v[1]); d[i + 2] = f2bf(v[2]); d[i + 3] = f2bf(v[3]);
    }
}

// merged q_a|kv_a weights: rows [0,1536)=qaw, [1536,2112)=kvaw, [2112,2176)=0
__global__ __launch_bounds__(256) void cvt_qka_k(
    const float* __restrict__ qa, const float* __restrict__ kva,
    unsigned short* __restrict__ d)
{
    long i = ((long)blockIdx.x * 256 + threadIdx.x) * 4;   // over 2176*2048
    long row = i >> 11, col = i & 2047;
    unsigned short* dd = d + i;
    if (row < QL_) {
        f4 v = *(const f4*)(qa + row * H_ + col);
        dd[0] = f2bf(v[0]); dd[1] = f2bf(v[1]); dd[2] = f2bf(v[2]); dd[3] = f2bf(v[3]);
    } else if (row < QL_ + 576) {
        f4 v = *(const f4*)(kva + (row - QL_) * H_ + col);
        dd[0] = f2bf(v[0]); dd[1] = f2bf(v[1]); dd[2] = f2bf(v[2]); dd[3] = f2bf(v[3]);
    } else {
        dd[0] = 0; dd[1] = 0; dd[2] = 0; dd[3] = 0;
    }
}

// 9-expert gate|up concat: z<8 routed (gw/uw), z==8 shared (sgw/suw)
__global__ __launch_bounds__(256) void cvt_cat9_k(
    const float* __restrict__ g, const float* __restrict__ u,
    const float* __restrict__ sg, const float* __restrict__ su,
    unsigned short* __restrict__ d)
{
    long ii = ((long)blockIdx.x * 256 + threadIdx.x) * 4;   // 1536*2048 per expert
    int e = blockIdx.y;
    long row = ii >> 11, col = ii & 2047;
    const float* src;
    if (row < INTER_)
        src = (e < 8) ? (g + ((long)e * INTER_ + row) * H_ + col) : (sg + row * H_ + col);
    else
        src = (e < 8) ? (u + ((long)e * INTER_ + row - INTER_) * H_ + col)
                      : (su + (row - INTER_) * H_ + col);
    f4 v = *(const f4*)src;
    unsigned short* dd = d + (long)e * (2 * INTER_) * H_ + ii;
    dd[0] = f2bf(v[0]); dd[1] = f2bf(v[1]); dd[2] = f2bf(v[2]); dd[3] = f2bf(v[3]);
}

// ---------------------------------------------------------------------------
__global__ __launch_bounds__(256) void rmsnorm_f2b(
    const float* __restrict__ in, const float* __restrict__ w,
    unsigned short* __restrict__ ob, float* __restrict__ of, int cols)
{
    const long base = (long)blockIdx.x * cols;
    float ss = 0.f;
    for (int c = threadIdx.x; c < cols; c += 256) {
        float v = in[base + c];
        ss += v * v;
    }
#pragma unroll
    for (int o = 32; o; o >>= 1) ss += __shfl_down(ss, o);
    __shared__ float red[4];
    if ((threadIdx.x & 63) == 0) red[threadIdx.x >> 6] = ss;
    __syncthreads();
    float r = rsqrtf((red[0] + red[1] + red[2] + red[3]) / cols + EPS_);
    for (int c = threadIdx.x; c < cols; c += 256) {
        float v = in[base + c] * r * w[c];
        ob[base + c] = f2bf(v);
        if (of) of[base + c] = v;
    }
}

// bf16 in (istride) -> bf16 out (ostride); in==out (same strides) is safe
__global__ __launch_bounds__(256) void rmsnorm_b2b(
    const unsigned short* __restrict__ in, const float* __restrict__ w,
    unsigned short* __restrict__ out, int cols, int istride, int ostride)
{
    const long ib = (long)blockIdx.x * istride;
    const long ob = (long)blockIdx.x * ostride;
    float ss = 0.f;
    for (int c = threadIdx.x; c < cols; c += 256) {
        float v = bf2f(in[ib + c]);
        ss += v * v;
    }
#pragma unroll
    for (int o = 32; o; o >>= 1) ss += __shfl_down(ss, o);
    __shared__ float red[4];
    if ((threadIdx.x & 63) == 0) red[threadIdx.x >> 6] = ss;
    __syncthreads();
    float r = rsqrtf((red[0] + red[1] + red[2] + red[3]) / cols + EPS_);
    for (int c = threadIdx.x; c < cols; c += 256)
        out[ob + c] = f2bf(bf2f(in[ib + c]) * r * w[c]);
}

// ---------------------------------------------------------------------------
__global__ __launch_bounds__(64) void rope_q_k(
    const unsigned short* __restrict__ q, const float* __restrict__ cs,
    const float* __restrict__ sn, unsigned short* __restrict__ qs)
{
    int t = blockIdx.x;            // (b*S+s)*16 + h
    int h = t & 15;
    int bs = t >> 4;
    int s = bs & (S_ - 1);
    int b = bs >> 10;
    const unsigned short* qrow = q + (long)bs * (NH_ * DQK_) + h * DQK_;
    unsigned short* orow = qs + ((long)(b * NH_ + h) * S_ + s) * DQK_;
    int l = threadIdx.x;
    orow[l] = qrow[l];
    orow[l + 64] = qrow[l + 64];
    int j = l & 31;
    float x0 = bf2f(qrow[DN_ + 2 * j]), x1 = bf2f(qrow[DN_ + 2 * j + 1]);
    float c = cs[(long)bs * DR_ + j], si = sn[(long)bs * DR_ + j];
    if (l < 32) orow[DN_ + j] = f2bf(x0 * c - x1 * si);
    else        orow[DN_ + 32 + j] = f2bf(x1 * c + x0 * si);
}

// k_rot lives in qkab cols [QL_+512, QL_+576), row stride QKA_
__global__ __launch_bounds__(64) void rope_k_k(
    const unsigned short* __restrict__ qkab, const float* __restrict__ cs,
    const float* __restrict__ sn, unsigned short* __restrict__ ks)
{
    int bs = blockIdx.x;
    int s = bs & (S_ - 1);
    int b = bs >> 10;
    const unsigned short* kr = qkab + (long)bs * QKA_ + QL_ + KVL_;
    int l = threadIdx.x;
    int j = l & 31;
    float x0 = bf2f(kr[2 * j]), x1 = bf2f(kr[2 * j + 1]);
    float c = cs[(long)bs * DR_ + j], si = sn[(long)bs * DR_ + j];
    float val = (l < 32) ? (x0 * c - x1 * si) : (x1 * c + x0 * si);
    int off = (l < 32) ? (DN_ + j) : (DN_ + 32 + j);
    unsigned short bv = f2bf(val);
    for (int h = 0; h < NH_; h++)
        ks[((long)(b * NH_ + h) * S_ + s) * DQK_ + off] = bv;
}

__global__ __launch_bounds__(128) void kpass_k(
    const unsigned short* __restrict__ kv, unsigned short* __restrict__ ks)
{
    int t = blockIdx.x; // (b*S+s)*16 + h
    int h = t & 15;
    int bs = t >> 4;
    int s = bs & (S_ - 1);
    int b = bs >> 10;
    ks[((long)(b * NH_ + h) * S_ + s) * DQK_ + threadIdx.x] = kv[(long)t * 256 + threadIdx.x];
}

__global__ __launch_bounds__(256) void vt_k(
    const unsigned short* __restrict__ kv, unsigned short* __restrict__ vt)
{
    __shared__ unsigned short tile[64][DV_ + 8];
    int s0 = blockIdx.x * 64;
    int bh = blockIdx.y;
    int b = bh >> 4, h = bh & 15;
    for (int it = 0; it < 32; it++) {
        int idx = it * 256 + threadIdx.x;
        int sl = idx >> 7, d = idx & 127;
        tile[sl][d] = kv[((long)(b * S_ + s0 + sl) * NH_ + h) * 256 + DN_ + d];
    }
    __syncthreads();
    for (int it = 0; it < 32; it++) {
        int idx = it * 256 + threadIdx.x;
        int d = idx >> 6, sl = idx & 63;
        vt[((long)bh * DV_ + d) * S_ + s0 + sl] = tile[sl][d];
    }
}

__global__ void zero9_k(int* __restrict__ cnt)
{
    if (threadIdx.x < NE9_) cnt[threadIdx.x] = (threadIdx.x == 8) ? T_ : 0;
}

__global__ void offs_k(const int* __restrict__ cnt, int* __restrict__ off)
{
    if (threadIdx.x == 0) {
        int a = 0;
        for (int e = 0; e < NE9_; e++) { off[e] = a; a += cnt[e]; }
    }
}

// router: top-2-of-grouped-8 scatter + identity entry for shared expert (e=8)
__global__ __launch_bounds__(64) void router_k(
    const float* __restrict__ h, const float* __restrict__ rw,
    const float* __restrict__ rb, int* __restrict__ cnt,
    int* __restrict__ idxl, float* __restrict__ wl)
{
    int t = blockIdx.x;
    int l = threadIdx.x;
    const float* hr = h + (long)t * H_;
    float pe[8] = {0, 0, 0, 0, 0, 0, 0, 0};
    for (int k = l; k < H_; k += 64) {
        float hv = hr[k];
#pragma unroll
        for (int e = 0; e < 8; e++) pe[e] += hv * rw[e * H_ + k];
    }
#pragma unroll
    for (int e = 0; e < 8; e++)
        for (int o = 32; o; o >>= 1) pe[e] += __shfl_down(pe[e], o);
    if (l == 0) {
        float sr[8], sc[8];
#pragma unroll
        for (int e = 0; e < 8; e++) {
            sr[e] = 1.f / (1.f + __expf(-pe[e]));
            sc[e] = sr[e] + rb[e];
        }
        float gs[4];
        for (int g = 0; g < 4; g++) gs[g] = sc[2 * g] + sc[2 * g + 1];
        int g0 = 0;
        for (int g = 1; g < 4; g++) if (gs[g] > gs[g0]) g0 = g;
        int g1 = -1;
        for (int g = 0; g < 4; g++) {
            if (g == g0) continue;
            if (g1 < 0 || gs[g] > gs[g1]) g1 = g;
        }
        int i0 = -1, i1 = -1;
        for (int e = 0; e < 8; e++) {
            int g = e >> 1;
            if (g != g0 && g != g1) continue;
            if (i0 < 0 || sc[e] > sc[i0]) i0 = e;
        }
        for (int e = 0; e < 8; e++) {
            int g = e >> 1;
            if (g != g0 && g != g1) continue;
            if (e == i0) continue;
            if (i1 < 0 || sc[e] > sc[i1]) i1 = e;
        }
        float w0 = sr[i0], w1 = sr[i1];
        float inv = 2.5f / (w0 + w1 + 1e-20f);
        int p0 = atomicAdd(&cnt[i0], 1);
        idxl[i0 * T_ + p0] = t;
        wl[i0 * T_ + p0] = w0 * inv;
        int p1 = atomicAdd(&cnt[i1], 1);
        idxl[i1 * T_ + p1] = t;
        wl[i1 * T_ + p1] = w1 * inv;
        idxl[8 * T_ + t] = t;      // shared expert: identity list, weight 1
        wl[8 * T_ + t] = 1.0f;
    }
}

// act[r][c] = silu(gu[r][c]) * gu[r][768+c]; grid (rows, 3) x 256
__global__ __launch_bounds__(256) void silugu_k(
    const unsigned short* __restrict__ gu, unsigned short* __restrict__ act)
{
    int r = blockIdx.x;
    int c = blockIdx.y * 256 + threadIdx.x;
    float g = bf2f(gu[(long)r * (2 * INTER_) + c]);
    float u = bf2f(gu[(long)r * (2 * INTER_) + INTER_ + c]);
    act[(long)r * INTER_ + c] = f2bf(g / (1.f + __expf(-g)) * u);
}

// ---------------------------------------------------------------------------
extern "C" void kernel_launch(void* const* d_in, const int* in_sizes, int n_in,
                              void* d_out, int out_size, void* d_ws, size_t ws_size,
                              hipStream_t stream)
{
    const float* hidden = (const float*)d_in[0];
    const float* cosb   = (const float*)d_in[1];
    const float* sinb   = (const float*)d_in[2];
    const float* ln1w   = (const float*)d_in[3];
    const float* qaw    = (const float*)d_in[4];
    const float* qalnw  = (const float*)d_in[5];
    const float* qbw    = (const float*)d_in[6];
    const float* kvaw   = (const float*)d_in[7];
    const float* kvalnw = (const float*)d_in[8];
    const float* kvbw   = (const float*)d_in[9];
    const float* ow     = (const float*)d_in[10];
    const float* ln2w   = (const float*)d_in[11];
    const float* rw     = (const float*)d_in[12];
    const float* rb     = (const float*)d_in[13];
    const float* gw     = (const float*)d_in[14];
    const float* uw     = (const float*)d_in[15];
    const float* dwn    = (const float*)d_in[16];
    const float* sgw    = (const float*)d_in[17];
    const float* suw    = (const float*)d_in[18];
    const float* sdw    = (const float*)d_in[19];
    float* out = (float*)d_out;
    (void)in_sizes; (void)n_in; (void)out_size; (void)ws_size;

    char* ws = (char*)d_ws;
    const size_t MB = 1u << 20;
    // ---- phase A (attention), MiB offsets, peak ~101 ----
    unsigned short* qkawb = (unsigned short*)(ws + 0 * MB);   // 8.5 (2176x2048)
    unsigned short* qbwb  = (unsigned short*)(ws + 9 * MB);   // 9
    unsigned short* kvbwb = (unsigned short*)(ws + 18 * MB);  // 4
    unsigned short* owb   = (unsigned short*)(ws + 22 * MB);  // 8
    unsigned short* xb    = (unsigned short*)(ws + 30 * MB);  // 8
    unsigned short* qkab  = (unsigned short*)(ws + 38 * MB);  // 8.5 (T x 2176)
    unsigned short* qb16  = (unsigned short*)(ws + 47 * MB);  // 12
    unsigned short* ckvnb = (unsigned short*)(ws + 59 * MB);  // 2
    unsigned short* kvb   = (unsigned short*)(ws + 61 * MB);  // 16
    unsigned short* qs    = (unsigned short*)(ws + 77 * MB);  // 12
    unsigned short* ks    = (unsigned short*)(ws + 89 * MB);  // 12
    unsigned short* vt    = (unsigned short*)(ws + 30 * MB);  // 8  (alias xb)
    unsigned short* ab    = (unsigned short*)(ws + 38 * MB);  // 8  (alias qkab, dead by FA)
    // ---- phase B (MoE), peak ~98 ----
    float* hbuf = (float*)(ws + 0 * MB);                      // 16 (dead after router)
    unsigned short* actm = (unsigned short*)(ws + 0 * MB);    // 9.4 (6144x768, after router)
    unsigned short* hb16 = (unsigned short*)(ws + 16 * MB);   // 8
    int*   cnt  = (int*)(ws + 24 * MB);
    int*   offb = (int*)(ws + 24 * MB + 256);
    int*   idxl = (int*)(ws + 24 * MB + 512);                 // 72 KB (9 x T)
    float* wl   = (float*)(ws + 24 * MB + 512 + 9 * T_ * 4);  // 72 KB
    unsigned short* guwb = (unsigned short*)(ws + 25 * MB);   // 54 (9x1536x2048)
    unsigned short* dwnb = (unsigned short*)(ws + 25 * MB);   // 27 (alias guwb, after gu GEMM)
    unsigned short* gu   = (unsigned short*)(ws + 79 * MB);   // 18.9 (6144x1536)

    // ---- weight conversion (attention) ----
    cvt_qka_k<<<(QKA_ * H_) / 1024, 256, 0, stream>>>(qaw, kvaw, qkawb);
    cvt_k<<<(NH_ * DQK_ * QL_) / 1024, 256, 0, stream>>>(qbw, qbwb, (long)NH_ * DQK_ * QL_);
    cvt_k<<<(NH_ * 256 * KVL_) / 1024, 256, 0, stream>>>(kvbw, kvbwb, (long)NH_ * 256 * KVL_);
    cvt_k<<<(H_ * H_) / 1024, 256, 0, stream>>>(ow, owb, (long)H_ * H_);

    // ---- attention projections ----
    rmsnorm_f2b<<<T_, 256, 0, stream>>>(hidden, ln1w, xb, nullptr, H_);

    // merged q_a | kv_a projection: qkab = xb @ qkawb^T  (N=2176)
    gemm2<0><<<dim3(T_ / 128, QKA_ / 128, 1), 256, 0, stream>>>(
        xb, qkawb, nullptr, qkab, nullptr, nullptr, nullptr, nullptr, nullptr,
        T_, QKA_, H_, H_, 0);
    rmsnorm_b2b<<<T_, 256, 0, stream>>>(qkab, qalnw, qkab, QL_, QKA_, QKA_);       // q_a norm in-place
    gemm2<0><<<dim3(T_ / 128, (NH_ * DQK_) / 128, 1), 256, 0, stream>>>(
        qkab, qbwb, nullptr, qb16, nullptr, nullptr, nullptr, nullptr, nullptr,
        T_, NH_ * DQK_, QL_, QKA_, 0);
    rmsnorm_b2b<<<T_, 256, 0, stream>>>(qkab + QL_, kvalnw, ckvnb, KVL_, QKA_, KVL_); // kv_a norm
    gemm2<0><<<dim3(T_ / 128, (NH_ * 256) / 128, 1), 256, 0, stream>>>(
        ckvnb, kvbwb, nullptr, kvb, nullptr, nullptr, nullptr, nullptr, nullptr,
        T_, NH_ * 256, KVL_, KVL_, 0);

    // ---- assemble qs / ks / vt ----
    rope_q_k<<<T_ * NH_, 64, 0, stream>>>(qb16, cosb, sinb, qs);
    rope_k_k<<<T_, 64, 0, stream>>>(qkab, cosb, sinb, ks);
    kpass_k<<<T_ * NH_, 128, 0, stream>>>(kvb, ks);
    vt_k<<<dim3(S_ / 64, B_ * NH_), 256, 0, stream>>>(kvb, vt);

    // ---- flash attention ----
    fa_k<<<dim3(S_ / 64, B_ * NH_), 256, 0, stream>>>(qs, ks, vt, ab);

    // ---- o-proj + residual: out = attn @ ow^T + hidden ----
    gemm2<0><<<dim3(T_ / 128, H_ / 128, 1), 256, 0, stream>>>(
        ab, owb, out, nullptr, hidden, nullptr, nullptr, nullptr, nullptr,
        T_, H_, H_, H_, 0);

    // ---- MoE prep ----
    rmsnorm_f2b<<<T_, 256, 0, stream>>>(out, ln2w, hb16, hbuf, H_);
    zero9_k<<<1, 64, 0, stream>>>(cnt);
    router_k<<<T_, 64, 0, stream>>>(hbuf, rw, rb, cnt, idxl, wl);
    offs_k<<<1, 64, 0, stream>>>(cnt, offb);

    // ---- 9-expert (8 routed + shared) gate+up -> silu -> down+scatter ----
    cvt_cat9_k<<<dim3((2 * INTER_ * H_) / 1024, NE9_), 256, 0, stream>>>(gw, uw, sgw, suw, guwb);
    gemm2<1><<<dim3(T_ / 128, (2 * INTER_) / 128, NE9_), 256, 0, stream>>>(
        hb16, guwb, nullptr, gu, nullptr, cnt, offb, idxl, nullptr,
        T_, 2 * INTER_, H_, H_, (long)(2 * INTER_) * H_);
    silugu_k<<<dim3(3 * T_, INTER_ / 256), 256, 0, stream>>>(gu, actm);
    cvt_k<<<(NEXP_ * H_ * INTER_) / 1024, 256, 0, stream>>>(dwn, dwnb, (long)NEXP_ * H_ * INTER_);
    cvt_k<<<(H_ * INTER_) / 1024, 256, 0, stream>>>(sdw, dwnb + (long)NEXP_ * H_ * INTER_, (long)H_ * INTER_);
    gemm2<2><<<dim3(T_ / 128, H_ / 128, NE9_), 256, 0, stream>>>(
        actm, dwnb, out, nullptr, nullptr, cnt, offb, idxl, wl,
        T_, H_, INTER_, INTER_, (long)H_ * INTER_);
}

// Round 8
// 600.536 us; speedup vs baseline: 4.2567x; 1.0253x over previous
//
#include <hip/hip_runtime.h>

typedef float f4 __attribute__((ext_vector_type(4)));
typedef float f32x4 __attribute__((ext_vector_type(4)));
typedef unsigned short us8 __attribute__((ext_vector_type(8)));
typedef __bf16 bf8 __attribute__((ext_vector_type(8)));

static constexpr int B_ = 2, S_ = 1024, H_ = 2048, T_ = B_ * S_;
static constexpr int NH_ = 16, DN_ = 128, DR_ = 64, DV_ = 128, DQK_ = 192;
static constexpr int KVL_ = 512, QL_ = 1536, INTER_ = 768, NEXP_ = 8, NE9_ = 9;
static constexpr int QKA_ = 2176;  // 1536 (q_a) + 576 (kv_a) + 64 pad
static constexpr float SCALING_ = 0.07216878364870322f; // 192^-0.5
static constexpr float EPS_ = 1e-6f;

__device__ __forceinline__ unsigned short f2bf(float f) {
    unsigned u = __float_as_uint(f);
    u += 0x7fffu + ((u >> 16) & 1u);
    return (unsigned short)(u >> 16);
}
__device__ __forceinline__ float bf2f(unsigned short h) {
    return __uint_as_float(((unsigned)h) << 16);
}
__device__ __forceinline__ us8 pack8(f4 a, f4 b) {
    us8 r;
    r[0] = f2bf(a[0]); r[1] = f2bf(a[1]); r[2] = f2bf(a[2]); r[3] = f2bf(a[3]);
    r[4] = f2bf(b[0]); r[5] = f2bf(b[1]); r[6] = f2bf(b[2]); r[7] = f2bf(b[3]);
    return r;
}

// async 16B/lane global->LDS. LDS dest = wave-uniform base + lane*16 (HW).
__device__ __forceinline__ void gload16(const unsigned short* g, unsigned short* lds) {
    __builtin_amdgcn_global_load_lds(
        (const __attribute__((address_space(1))) void*)g,
        (__attribute__((address_space(3))) void*)lds, 16, 0, 0);
}

// ---------------------------------------------------------------------------
// gemm2: C[M,N] = A[M,K] * B[N,K]^T, bf16 in, 128x128 tile, BK=32.
// 5-buffer depth-4 pipeline with COUNTED vmcnt (T4): per K-step
//   waitcnt vmcnt(12) -> s_barrier -> stage(t+4) -> compute(t)
// (tail: vmcnt 8/4/0). 3 tiles stay in flight across each barrier.
// T1: XCD-chunked (bx,by) swizzle so same-B-panel blocks share one XCD L2.
// T5: setprio(1) around the MFMA cluster.
// MODE 0: plain. Cb -> bf16; else Cf (+add) fp32.
// MODE 1: MoE gate+up: A rows gathered via idxl[e], C bf16 compacted at off[e].
// MODE 2: MoE down: A rows compacted at off[e], atomic scatter out[tok] += w*acc.
// ---------------------------------------------------------------------------
template <int MODE>
__global__ __launch_bounds__(256) void gemm2(
    const unsigned short* __restrict__ A, const unsigned short* __restrict__ Bw,
    float* __restrict__ Cf, unsigned short* __restrict__ Cb,
    const float* __restrict__ add,
    const int* __restrict__ cnt, const int* __restrict__ off,
    const int* __restrict__ idxl, const float* __restrict__ wl,
    int M, int N, int K, int ldA, long sB)
{
    constexpr int BM = 128, BN = 128, BK = 32;
    __shared__ __align__(16) unsigned short As[5][BM * BK];
    __shared__ __align__(16) unsigned short Bs[5][BN * BK];
    const int tid = threadIdx.x, lane = tid & 63, wv = tid >> 6;
    const int wm = (wv >> 1) * 64, wn = (wv & 1) * 64;

    // T1: XCD-chunked bijective swizzle (all call sites: gridDim.x=16 -> nb%8==0)
    const int nb = gridDim.x * gridDim.y;
    const int lin = blockIdx.y * gridDim.x + blockIdx.x;
    const int swz = (lin & 7) * (nb >> 3) + (lin >> 3);
    const int bx = swz % gridDim.x;
    const int by = swz / gridDim.x;
    const int m0 = bx * BM, n0 = by * BN;

    int mcnt = M, obase = 0;
    if constexpr (MODE != 0) {
        mcnt = cnt[blockIdx.z];
        if (m0 >= mcnt) return;
        obase = off[blockIdx.z];
    }

    const int srow = tid >> 2, scol = (tid & 3) * 8;
    long aoff0, aoff1;
    if constexpr (MODE == 1) {
        const int e = blockIdx.z;
        int r0 = m0 + srow, r1 = r0 + 64;
        int t0 = idxl[(long)e * T_ + (r0 < mcnt ? r0 : mcnt - 1)];
        int t1 = idxl[(long)e * T_ + (r1 < mcnt ? r1 : mcnt - 1)];
        aoff0 = (long)t0 * ldA + scol;
        aoff1 = (long)t1 * ldA + scol;
    } else if constexpr (MODE == 2) {
        aoff0 = (long)(obase + m0 + srow) * ldA + scol;
        aoff1 = aoff0 + 64L * ldA;
    } else {
        aoff0 = (long)(m0 + srow) * ldA + scol;
        aoff1 = aoff0 + 64L * ldA;
    }
    long boff0 = (long)blockIdx.z * sB + (long)(n0 + srow) * K + scol;
    long boff1 = boff0 + 64L * K;

    f32x4 acc[4][4];
#pragma unroll
    for (int m = 0; m < 4; m++)
#pragma unroll
        for (int n = 0; n < 4; n++) acc[m][n] = f32x4{0.f, 0.f, 0.f, 0.f};

    const int fr = lane & 15, ko = (lane >> 4) * 8;

    auto stage = [&](int buf, int k0) {
        gload16(A + aoff0 + k0, &As[buf][wv * 512]);
        gload16(A + aoff1 + k0, &As[buf][2048 + wv * 512]);
        gload16(Bw + boff0 + k0, &Bs[buf][wv * 512]);
        gload16(Bw + boff1 + k0, &Bs[buf][2048 + wv * 512]);
    };
    auto compute = [&](int buf) {
        __builtin_amdgcn_s_setprio(1);
        bf8 af[4], bfv[4];
#pragma unroll
        for (int m = 0; m < 4; m++) af[m] = *(const bf8*)&As[buf][(wm + m * 16 + fr) * 32 + ko];
#pragma unroll
        for (int n = 0; n < 4; n++) bfv[n] = *(const bf8*)&Bs[buf][(wn + n * 16 + fr) * 32 + ko];
#pragma unroll
        for (int m = 0; m < 4; m++)
#pragma unroll
            for (int n = 0; n < 4; n++)
                acc[m][n] = __builtin_amdgcn_mfma_f32_16x16x32_bf16(af[m], bfv[n], acc[m][n], 0, 0, 0);
        __builtin_amdgcn_s_setprio(0);
    };

    const int nt = K / BK;     // >= 16 at every call site
    stage(0, 0);
    stage(1, BK);
    stage(2, 2 * BK);
    stage(3, 3 * BK);
    for (int t = 0; t < nt; t++) {
        if (t + 3 < nt)      asm volatile("s_waitcnt vmcnt(12)" ::: "memory");
        else if (t + 2 < nt) asm volatile("s_waitcnt vmcnt(8)" ::: "memory");
        else if (t + 1 < nt) asm volatile("s_waitcnt vmcnt(4)" ::: "memory");
        else                 asm volatile("s_waitcnt vmcnt(0)" ::: "memory");
        __builtin_amdgcn_s_barrier();
        if (t + 4 < nt) stage((t + 4) % 5, (t + 4) * BK);
        compute(t % 5);
    }

#pragma unroll
    for (int m = 0; m < 4; m++) {
#pragma unroll
        for (int n = 0; n < 4; n++) {
#pragma unroll
            for (int i = 0; i < 4; i++) {
                int row = wm + m * 16 + (lane >> 4) * 4 + i;   // local row
                int col = n0 + wn + n * 16 + (lane & 15);
                float v = acc[m][n][i];
                if constexpr (MODE == 0) {
                    long idx = (long)(m0 + row) * N + col;
                    if (Cb)       Cb[idx] = f2bf(v);
                    else if (add) Cf[idx] = v + add[idx];
                    else          Cf[idx] = v;
                } else if constexpr (MODE == 1) {
                    if (m0 + row < mcnt)
                        Cb[(long)(obase + m0 + row) * N + col] = f2bf(v);
                } else {
                    if (m0 + row < mcnt) {
                        int e = blockIdx.z;
                        int tok = idxl[(long)e * T_ + m0 + row];
                        float w = wl[(long)e * T_ + m0 + row];
                        atomicAdd(&Cf[(long)tok * N + col], w * v);
                    }
                }
            }
        }
    }
}

// ---------------------------------------------------------------------------
// Flash attention (causal). grid (S/64, B*NH), 256 threads (4 waves).
// ---------------------------------------------------------------------------
__global__ __launch_bounds__(256) void fa_k(
    const unsigned short* __restrict__ qs, const unsigned short* __restrict__ ks,
    const unsigned short* __restrict__ vt, unsigned short* __restrict__ ab)
{
    constexpr int KB = 64;
    const int q0 = blockIdx.x * 64;
    const int bh = blockIdx.y;
    const int b = bh >> 4, h = bh & 15;
    const int tid = threadIdx.x, lane = tid & 63, wv = tid >> 6;
    const int fr = lane & 15, lg = lane >> 4;
    const int ko = lg * 8;

    __shared__ __align__(16) unsigned short Kl[KB][200];
    __shared__ __align__(16) unsigned short Vl[128][72];
    __shared__ __align__(16) unsigned short Pl[4][16][72];

    const unsigned short* qp = qs + ((long)bh * S_ + q0 + wv * 16 + fr) * DQK_ + ko;
    bf8 qf[6];
#pragma unroll
    for (int s = 0; s < 6; s++) qf[s] = *(const bf8*)(qp + s * 32);

    f32x4 o[8];
#pragma unroll
    for (int n = 0; n < 8; n++) o[n] = f32x4{0.f, 0.f, 0.f, 0.f};
    float mrow[4] = {-3e38f, -3e38f, -3e38f, -3e38f};
    float lrow[4] = {0.f, 0.f, 0.f, 0.f};

    const int nt = q0 / KB + 1;

    const unsigned short* kg = ks + ((long)bh * S_ + (tid >> 2)) * DQK_ + (tid & 3) * 48;
    const unsigned short* vg = vt + ((long)bh * DV_ + (tid >> 1)) * S_ + (tid & 1) * 32;

    us8 krg[6], vrg[4];
#pragma unroll
    for (int j = 0; j < 6; j++) krg[j] = *(const us8*)(kg + j * 8);
#pragma unroll
    for (int j = 0; j < 4; j++) vrg[j] = *(const us8*)(vg + j * 8);

    for (int t = 0; t < nt; t++) {
        __syncthreads();
        {
            int r = tid >> 2, c = (tid & 3) * 48;
#pragma unroll
            for (int j = 0; j < 6; j++) *(us8*)&Kl[r][c + j * 8] = krg[j];
            int dv = tid >> 1, c2 = (tid & 1) * 32;
#pragma unroll
            for (int j = 0; j < 4; j++) *(us8*)&Vl[dv][c2 + j * 8] = vrg[j];
        }
        __syncthreads();
        if (t + 1 < nt) {
            long kof = (long)(t + 1) * KB;
#pragma unroll
            for (int j = 0; j < 6; j++) krg[j] = *(const us8*)(kg + kof * DQK_ + j * 8);
#pragma unroll
            for (int j = 0; j < 4; j++) vrg[j] = *(const us8*)(vg + kof + j * 8);
        }
        f32x4 ps[4];
#pragma unroll
        for (int ct = 0; ct < 4; ct++) {
            f32x4 a = f32x4{0.f, 0.f, 0.f, 0.f};
#pragma unroll
            for (int s = 0; s < 6; s++) {
                bf8 kf = *(const bf8*)&Kl[ct * 16 + fr][s * 32 + ko];
                a = __builtin_amdgcn_mfma_f32_16x16x32_bf16(qf[s], kf, a, 0, 0, 0);
            }
            ps[ct] = a;
        }
        const int kv0 = t * KB;
        const bool diag = (kv0 == q0);
#pragma unroll
        for (int ct = 0; ct < 4; ct++)
#pragma unroll
            for (int i = 0; i < 4; i++) {
                float v = ps[ct][i] * SCALING_;
                if (diag && (kv0 + ct * 16 + fr) > (q0 + wv * 16 + lg * 4 + i)) v = -3e38f;
                ps[ct][i] = v;
            }
        float scl[4];
#pragma unroll
        for (int i = 0; i < 4; i++) {
            float v = fmaxf(fmaxf(ps[0][i], ps[1][i]), fmaxf(ps[2][i], ps[3][i]));
#pragma unroll
            for (int x = 8; x; x >>= 1) v = fmaxf(v, __shfl_xor(v, x, 16));
            float mn = fmaxf(mrow[i], v);
            scl[i] = __expf(mrow[i] - mn);
            mrow[i] = mn;
        }
        float tsum[4] = {0.f, 0.f, 0.f, 0.f};
#pragma unroll
        for (int ct = 0; ct < 4; ct++)
#pragma unroll
            for (int i = 0; i < 4; i++) {
                float e = __expf(ps[ct][i] - mrow[i]);
                tsum[i] += e;
                Pl[wv][lg * 4 + i][ct * 16 + fr] = f2bf(e);
            }
#pragma unroll
        for (int i = 0; i < 4; i++) {
            float v = tsum[i];
#pragma unroll
            for (int x = 8; x; x >>= 1) v += __shfl_xor(v, x, 16);
            lrow[i] = lrow[i] * scl[i] + v;
        }
#pragma unroll
        for (int n = 0; n < 8; n++)
#pragma unroll
            for (int i = 0; i < 4; i++) o[n][i] *= scl[i];
        bf8 pf[2];
#pragma unroll
        for (int ksl = 0; ksl < 2; ksl++)
            pf[ksl] = *(const bf8*)&Pl[wv][fr][ksl * 32 + ko];
#pragma unroll
        for (int n = 0; n < 8; n++)
#pragma unroll
            for (int ksl = 0; ksl < 2; ksl++) {
                bf8 vf = *(const bf8*)&Vl[n * 16 + fr][ksl * 32 + ko];
                o[n] = __builtin_amdgcn_mfma_f32_16x16x32_bf16(pf[ksl], vf, o[n], 0, 0, 0);
            }
    }
#pragma unroll
    for (int i = 0; i < 4; i++) {
        float inv = 1.f / lrow[i];
        long rbase = ((long)b * S_ + q0 + wv * 16 + lg * 4 + i) * H_ + h * DV_;
#pragma unroll
        for (int n = 0; n < 8; n++)
            ab[rbase + n * 16 + fr] = f2bf(o[n][i] * inv);
    }
}

// ---------------------------------------------------------------------------
// conversion kernels (fp32 -> bf16), 8 elems/thread
// ---------------------------------------------------------------------------
__global__ __launch_bounds__(256) void cvt_k(
    const float* __restrict__ s, unsigned short* __restrict__ d, long n)
{
    long i = ((long)blockIdx.x * 256 + threadIdx.x) * 8;
    if (i < n) {
        f4 a = *(const f4*)(s + i);
        f4 b = *(const f4*)(s + i + 4);
        *(us8*)(d + i) = pack8(a, b);
    }
}

// merged q_a|kv_a weights: rows [0,1536)=qaw, [1536,2112)=kvaw, [2112,2176)=0
__global__ __launch_bounds__(256) void cvt_qka_k(
    const float* __restrict__ qa, const float* __restrict__ kva,
    unsigned short* __restrict__ d)
{
    long i = ((long)blockIdx.x * 256 + threadIdx.x) * 8;   // over 2176*2048
    long row = i >> 11, col = i & 2047;
    us8 o;
    if (row < QL_) {
        const float* s = qa + row * H_ + col;
        o = pack8(*(const f4*)s, *(const f4*)(s + 4));
    } else if (row < QL_ + 576) {
        const float* s = kva + (row - QL_) * H_ + col;
        o = pack8(*(const f4*)s, *(const f4*)(s + 4));
    } else {
        o = us8{0, 0, 0, 0, 0, 0, 0, 0};
    }
    *(us8*)(d + i) = o;
}

// 9-expert gate|up concat: z<8 routed (gw/uw), z==8 shared (sgw/suw)
__global__ __launch_bounds__(256) void cvt_cat9_k(
    const float* __restrict__ g, const float* __restrict__ u,
    const float* __restrict__ sg, const float* __restrict__ su,
    unsigned short* __restrict__ d)
{
    long ii = ((long)blockIdx.x * 256 + threadIdx.x) * 8;   // 1536*2048 per expert
    int e = blockIdx.y;
    long row = ii >> 11, col = ii & 2047;
    const float* src;
    if (row < INTER_)
        src = (e < 8) ? (g + ((long)e * INTER_ + row) * H_ + col) : (sg + row * H_ + col);
    else
        src = (e < 8) ? (u + ((long)e * INTER_ + row - INTER_) * H_ + col)
                      : (su + (row - INTER_) * H_ + col);
    *(us8*)(d + (long)e * (2 * INTER_) * H_ + ii) = pack8(*(const f4*)src, *(const f4*)(src + 4));
}

// ---------------------------------------------------------------------------
// rmsnorm fp32->bf16 (+ optional fp32 copy); cols == H_ == 2048 (8/thread)
__global__ __launch_bounds__(256) void rmsnorm_f2b(
    const float* __restrict__ in, const float* __restrict__ w,
    unsigned short* __restrict__ ob, float* __restrict__ of)
{
    const long base = (long)blockIdx.x * H_;
    const int c = threadIdx.x * 8;
    f4 v0 = *(const f4*)(in + base + c);
    f4 v1 = *(const f4*)(in + base + c + 4);
    float ss = v0[0] * v0[0] + v0[1] * v0[1] + v0[2] * v0[2] + v0[3] * v0[3]
             + v1[0] * v1[0] + v1[1] * v1[1] + v1[2] * v1[2] + v1[3] * v1[3];
#pragma unroll
    for (int o = 32; o; o >>= 1) ss += __shfl_down(ss, o);
    __shared__ float red[4];
    if ((threadIdx.x & 63) == 0) red[threadIdx.x >> 6] = ss;
    __syncthreads();
    float r = rsqrtf((red[0] + red[1] + red[2] + red[3]) / H_ + EPS_);
    f4 w0 = *(const f4*)(w + c);
    f4 w1 = *(const f4*)(w + c + 4);
    f4 a, b;
#pragma unroll
    for (int j = 0; j < 4; j++) { a[j] = v0[j] * r * w0[j]; b[j] = v1[j] * r * w1[j]; }
    *(us8*)(ob + base + c) = pack8(a, b);
    if (of) {
        *(f4*)(of + base + c) = a;
        *(f4*)(of + base + c + 4) = b;
    }
}

// bf16 in (istride) -> bf16 out (ostride); in==out safe (per-thread RBW)
__global__ __launch_bounds__(256) void rmsnorm_b2b(
    const unsigned short* __restrict__ in, const float* __restrict__ w,
    unsigned short* __restrict__ out, int cols, int istride, int ostride)
{
    const long ib = (long)blockIdx.x * istride;
    const long ob = (long)blockIdx.x * ostride;
    const int nu = cols >> 3;
    float ss = 0.f;
    for (int u = threadIdx.x; u < nu; u += 256) {
        us8 v = *(const us8*)(in + ib + u * 8);
#pragma unroll
        for (int j = 0; j < 8; j++) { float f = bf2f(v[j]); ss += f * f; }
    }
#pragma unroll
    for (int o = 32; o; o >>= 1) ss += __shfl_down(ss, o);
    __shared__ float red[4];
    if ((threadIdx.x & 63) == 0) red[threadIdx.x >> 6] = ss;
    __syncthreads();
    float r = rsqrtf((red[0] + red[1] + red[2] + red[3]) / cols + EPS_);
    for (int u = threadIdx.x; u < nu; u += 256) {
        us8 v = *(const us8*)(in + ib + u * 8);
        f4 w0 = *(const f4*)(w + u * 8);
        f4 w1 = *(const f4*)(w + u * 8 + 4);
        us8 o;
#pragma unroll
        for (int j = 0; j < 4; j++) o[j] = f2bf(bf2f(v[j]) * r * w0[j]);
#pragma unroll
        for (int j = 0; j < 4; j++) o[4 + j] = f2bf(bf2f(v[4 + j]) * r * w1[j]);
        *(us8*)(out + ob + u * 8) = o;
    }
}

// ---------------------------------------------------------------------------
__global__ __launch_bounds__(64) void rope_q_k(
    const unsigned short* __restrict__ q, const float* __restrict__ cs,
    const float* __restrict__ sn, unsigned short* __restrict__ qs)
{
    int t = blockIdx.x;            // (b*S+s)*16 + h
    int h = t & 15;
    int bs = t >> 4;
    int s = bs & (S_ - 1);
    int b = bs >> 10;
    const unsigned short* qrow = q + (long)bs * (NH_ * DQK_) + h * DQK_;
    unsigned short* orow = qs + ((long)(b * NH_ + h) * S_ + s) * DQK_;
    int l = threadIdx.x;
    orow[l] = qrow[l];
    orow[l + 64] = qrow[l + 64];
    int j = l & 31;
    float x0 = bf2f(qrow[DN_ + 2 * j]), x1 = bf2f(qrow[DN_ + 2 * j + 1]);
    float c = cs[(long)bs * DR_ + j], si = sn[(long)bs * DR_ + j];
    if (l < 32) orow[DN_ + j] = f2bf(x0 * c - x1 * si);
    else        orow[DN_ + 32 + j] = f2bf(x1 * c + x0 * si);
}

// k_rot lives in qkab cols [QL_+512, QL_+576), row stride QKA_
__global__ __launch_bounds__(64) void rope_k_k(
    const unsigned short* __restrict__ qkab, const float* __restrict__ cs,
    const float* __restrict__ sn, unsigned short* __restrict__ ks)
{
    int bs = blockIdx.x;
    int s = bs & (S_ - 1);
    int b = bs >> 10;
    const unsigned short* kr = qkab + (long)bs * QKA_ + QL_ + KVL_;
    int l = threadIdx.x;
    int j = l & 31;
    float x0 = bf2f(kr[2 * j]), x1 = bf2f(kr[2 * j + 1]);
    float c = cs[(long)bs * DR_ + j], si = sn[(long)bs * DR_ + j];
    float val = (l < 32) ? (x0 * c - x1 * si) : (x1 * c + x0 * si);
    int off = (l < 32) ? (DN_ + j) : (DN_ + 32 + j);
    unsigned short bv = f2bf(val);
    for (int h = 0; h < NH_; h++)
        ks[((long)(b * NH_ + h) * S_ + s) * DQK_ + off] = bv;
}

__global__ __launch_bounds__(128) void kpass_k(
    const unsigned short* __restrict__ kv, unsigned short* __restrict__ ks)
{
    int t = blockIdx.x; // (b*S+s)*16 + h
    int h = t & 15;
    int bs = t >> 4;
    int s = bs & (S_ - 1);
    int b = bs >> 10;
    ks[((long)(b * NH_ + h) * S_ + s) * DQK_ + threadIdx.x] = kv[(long)t * 256 + threadIdx.x];
}

// V transpose: kv (B,S,NH,256)[:,128:] -> vt (B,NH,128,S), vectorized
__global__ __launch_bounds__(256) void vt_k(
    const unsigned short* __restrict__ kv, unsigned short* __restrict__ vt)
{
    __shared__ unsigned short tile[64][DV_ + 8];
    int s0 = blockIdx.x * 64;
    int bh = blockIdx.y;
    int b = bh >> 4, h = bh & 15;
#pragma unroll
    for (int it = 0; it < 4; it++) {
        int idx = it * 256 + threadIdx.x;          // 1024 us8 units: 64 rows x 16
        int sl = idx >> 4, du = idx & 15;
        *(us8*)&tile[sl][du * 8] =
            *(const us8*)(kv + ((long)(b * S_ + s0 + sl) * NH_ + h) * 256 + DN_ + du * 8);
    }
    __syncthreads();
#pragma unroll
    for (int it = 0; it < 4; it++) {
        int idx = it * 256 + threadIdx.x;          // 1024 units: 128 d x 8 s-chunks
        int d = idx >> 3, su = idx & 7;
        us8 o;
#pragma unroll
        for (int j = 0; j < 8; j++) o[j] = tile[su * 8 + j][d];
        *(us8*)(vt + ((long)bh * DV_ + d) * S_ + s0 + su * 8) = o;
    }
}

__global__ void zero9_k(int* __restrict__ cnt)
{
    if (threadIdx.x < NE9_) cnt[threadIdx.x] = (threadIdx.x == 8) ? T_ : 0;
}

__global__ void offs_k(const int* __restrict__ cnt, int* __restrict__ off)
{
    if (threadIdx.x == 0) {
        int a = 0;
        for (int e = 0; e < NE9_; e++) { off[e] = a; a += cnt[e]; }
    }
}

// router: top-2-of-grouped-8 scatter + identity entry for shared expert (e=8)
__global__ __launch_bounds__(64) void router_k(
    const float* __restrict__ h, const float* __restrict__ rw,
    const float* __restrict__ rb, int* __restrict__ cnt,
    int* __restrict__ idxl, float* __restrict__ wl)
{
    int t = blockIdx.x;
    int l = threadIdx.x;
    const float* hr = h + (long)t * H_;
    float pe[8] = {0, 0, 0, 0, 0, 0, 0, 0};
    for (int k = l; k < H_; k += 64) {
        float hv = hr[k];
#pragma unroll
        for (int e = 0; e < 8; e++) pe[e] += hv * rw[e * H_ + k];
    }
#pragma unroll
    for (int e = 0; e < 8; e++)
        for (int o = 32; o; o >>= 1) pe[e] += __shfl_down(pe[e], o);
    if (l == 0) {
        float sr[8], sc[8];
#pragma unroll
        for (int e = 0; e < 8; e++) {
            sr[e] = 1.f / (1.f + __expf(-pe[e]));
            sc[e] = sr[e] + rb[e];
        }
        float gs[4];
        for (int g = 0; g < 4; g++) gs[g] = sc[2 * g] + sc[2 * g + 1];
        int g0 = 0;
        for (int g = 1; g < 4; g++) if (gs[g] > gs[g0]) g0 = g;
        int g1 = -1;
        for (int g = 0; g < 4; g++) {
            if (g == g0) continue;
            if (g1 < 0 || gs[g] > gs[g1]) g1 = g;
        }
        int i0 = -1, i1 = -1;
        for (int e = 0; e < 8; e++) {
            int g = e >> 1;
            if (g != g0 && g != g1) continue;
            if (i0 < 0 || sc[e] > sc[i0]) i0 = e;
        }
        for (int e = 0; e < 8; e++) {
            int g = e >> 1;
            if (g != g0 && g != g1) continue;
            if (e == i0) continue;
            if (i1 < 0 || sc[e] > sc[i1]) i1 = e;
        }
        float w0 = sr[i0], w1 = sr[i1];
        float inv = 2.5f / (w0 + w1 + 1e-20f);
        int p0 = atomicAdd(&cnt[i0], 1);
        idxl[i0 * T_ + p0] = t;
        wl[i0 * T_ + p0] = w0 * inv;
        int p1 = atomicAdd(&cnt[i1], 1);
        idxl[i1 * T_ + p1] = t;
        wl[i1 * T_ + p1] = w1 * inv;
        idxl[8 * T_ + t] = t;      // shared expert: identity list, weight 1
        wl[8 * T_ + t] = 1.0f;
    }
}

// act[r][c] = silu(gu[r][c]) * gu[r][768+c]; vectorized us8, linear grid
// rows = 6144; 96 us8-units per row; grid = 6144*96/256 = 2304
__global__ __launch_bounds__(256) void silugu_k(
    const unsigned short* __restrict__ gu, unsigned short* __restrict__ act)
{
    long idx = (long)blockIdx.x * 256 + threadIdx.x;
    int r = (int)(idx / 96);
    int c = (int)(idx - (long)r * 96) * 8;
    us8 g8 = *(const us8*)(gu + (long)r * (2 * INTER_) + c);
    us8 u8 = *(const us8*)(gu + (long)r * (2 * INTER_) + INTER_ + c);
    us8 o;
#pragma unroll
    for (int j = 0; j < 8; j++) {
        float g = bf2f(g8[j]);
        o[j] = f2bf(g / (1.f + __expf(-g)) * bf2f(u8[j]));
    }
    *(us8*)(act + (long)r * INTER_ + c) = o;
}

// ---------------------------------------------------------------------------
extern "C" void kernel_launch(void* const* d_in, const int* in_sizes, int n_in,
                              void* d_out, int out_size, void* d_ws, size_t ws_size,
                              hipStream_t stream)
{
    const float* hidden = (const float*)d_in[0];
    const float* cosb   = (const float*)d_in[1];
    const float* sinb   = (const float*)d_in[2];
    const float* ln1w   = (const float*)d_in[3];
    const float* qaw    = (const float*)d_in[4];
    const float* qalnw  = (const float*)d_in[5];
    const float* qbw    = (const float*)d_in[6];
    const float* kvaw   = (const float*)d_in[7];
    const float* kvalnw = (const float*)d_in[8];
    const float* kvbw   = (const float*)d_in[9];
    const float* ow     = (const float*)d_in[10];
    const float* ln2w   = (const float*)d_in[11];
    const float* rw     = (const float*)d_in[12];
    const float* rb     = (const float*)d_in[13];
    const float* gw     = (const float*)d_in[14];
    const float* uw     = (const float*)d_in[15];
    const float* dwn    = (const float*)d_in[16];
    const float* sgw    = (const float*)d_in[17];
    const float* suw    = (const float*)d_in[18];
    const float* sdw    = (const float*)d_in[19];
    float* out = (float*)d_out;
    (void)in_sizes; (void)n_in; (void)out_size; (void)ws_size;

    char* ws = (char*)d_ws;
    const size_t MB = 1u << 20;
    // ---- phase A (attention), MiB offsets, peak ~101 ----
    unsigned short* qkawb = (unsigned short*)(ws + 0 * MB);   // 8.5 (2176x2048)
    unsigned short* qbwb  = (unsigned short*)(ws + 9 * MB);   // 9
    unsigned short* kvbwb = (unsigned short*)(ws + 18 * MB);  // 4
    unsigned short* owb   = (unsigned short*)(ws + 22 * MB);  // 8
    unsigned short* xb    = (unsigned short*)(ws + 30 * MB);  // 8
    unsigned short* qkab  = (unsigned short*)(ws + 38 * MB);  // 8.5 (T x 2176)
    unsigned short* qb16  = (unsigned short*)(ws + 47 * MB);  // 12
    unsigned short* ckvnb = (unsigned short*)(ws + 59 * MB);  // 2
    unsigned short* kvb   = (unsigned short*)(ws + 61 * MB);  // 16
    unsigned short* qs    = (unsigned short*)(ws + 77 * MB);  // 12
    unsigned short* ks    = (unsigned short*)(ws + 89 * MB);  // 12
    unsigned short* vt    = (unsigned short*)(ws + 30 * MB);  // 8  (alias xb)
    unsigned short* ab    = (unsigned short*)(ws + 38 * MB);  // 8  (alias qkab, dead by FA)
    // ---- phase B (MoE), peak ~98 ----
    float* hbuf = (float*)(ws + 0 * MB);                      // 16 (dead after router)
    unsigned short* actm = (unsigned short*)(ws + 0 * MB);    // 9.4 (6144x768, after router)
    unsigned short* hb16 = (unsigned short*)(ws + 16 * MB);   // 8
    int*   cnt  = (int*)(ws + 24 * MB);
    int*   offb = (int*)(ws + 24 * MB + 256);
    int*   idxl = (int*)(ws + 24 * MB + 512);                 // 72 KB (9 x T)
    float* wl   = (float*)(ws + 24 * MB + 512 + 9 * T_ * 4);  // 72 KB
    unsigned short* guwb = (unsigned short*)(ws + 25 * MB);   // 54 (9x1536x2048)
    unsigned short* dwnb = (unsigned short*)(ws + 25 * MB);   // 27 (alias guwb, after gu GEMM)
    unsigned short* gu   = (unsigned short*)(ws + 79 * MB);   // 18.9 (6144x1536)

    // ---- weight conversion (attention) ----
    cvt_qka_k<<<(QKA_ * H_) / 2048, 256, 0, stream>>>(qaw, kvaw, qkawb);
    cvt_k<<<(NH_ * DQK_ * QL_) / 2048, 256, 0, stream>>>(qbw, qbwb, (long)NH_ * DQK_ * QL_);
    cvt_k<<<(NH_ * 256 * KVL_) / 2048, 256, 0, stream>>>(kvbw, kvbwb, (long)NH_ * 256 * KVL_);
    cvt_k<<<(H_ * H_) / 2048, 256, 0, stream>>>(ow, owb, (long)H_ * H_);

    // ---- attention projections ----
    rmsnorm_f2b<<<T_, 256, 0, stream>>>(hidden, ln1w, xb, nullptr);

    // merged q_a | kv_a projection: qkab = xb @ qkawb^T  (N=2176)
    gemm2<0><<<dim3(T_ / 128, QKA_ / 128, 1), 256, 0, stream>>>(
        xb, qkawb, nullptr, qkab, nullptr, nullptr, nullptr, nullptr, nullptr,
        T_, QKA_, H_, H_, 0);
    rmsnorm_b2b<<<T_, 256, 0, stream>>>(qkab, qalnw, qkab, QL_, QKA_, QKA_);       // q_a norm in-place
    gemm2<0><<<dim3(T_ / 128, (NH_ * DQK_) / 128, 1), 256, 0, stream>>>(
        qkab, qbwb, nullptr, qb16, nullptr, nullptr, nullptr, nullptr, nullptr,
        T_, NH_ * DQK_, QL_, QKA_, 0);
    rmsnorm_b2b<<<T_, 256, 0, stream>>>(qkab + QL_, kvalnw, ckvnb, KVL_, QKA_, KVL_); // kv_a norm
    gemm2<0><<<dim3(T_ / 128, (NH_ * 256) / 128, 1), 256, 0, stream>>>(
        ckvnb, kvbwb, nullptr, kvb, nullptr, nullptr, nullptr, nullptr, nullptr,
        T_, NH_ * 256, KVL_, KVL_, 0);

    // ---- assemble qs / ks / vt ----
    rope_q_k<<<T_ * NH_, 64, 0, stream>>>(qb16, cosb, sinb, qs);
    rope_k_k<<<T_, 64, 0, stream>>>(qkab, cosb, sinb, ks);
    kpass_k<<<T_ * NH_, 128, 0, stream>>>(kvb, ks);
    vt_k<<<dim3(S_ / 64, B_ * NH_), 256, 0, stream>>>(kvb, vt);

    // ---- flash attention ----
    fa_k<<<dim3(S_ / 64, B_ * NH_), 256, 0, stream>>>(qs, ks, vt, ab);

    // ---- o-proj + residual: out = attn @ ow^T + hidden ----
    gemm2<0><<<dim3(T_ / 128, H_ / 128, 1), 256, 0, stream>>>(
        ab, owb, out, nullptr, hidden, nullptr, nullptr, nullptr, nullptr,
        T_, H_, H_, H_, 0);

    // ---- MoE prep ----
    rmsnorm_f2b<<<T_, 256, 0, stream>>>(out, ln2w, hb16, hbuf);
    zero9_k<<<1, 64, 0, stream>>>(cnt);
    router_k<<<T_, 64, 0, stream>>>(hbuf, rw, rb, cnt, idxl, wl);
    offs_k<<<1, 64, 0, stream>>>(cnt, offb);

    // ---- 9-expert (8 routed + shared) gate+up -> silu -> down+scatter ----
    cvt_cat9_k<<<dim3((2 * INTER_ * H_) / 2048, NE9_), 256, 0, stream>>>(gw, uw, sgw, suw, guwb);
    gemm2<1><<<dim3(T_ / 128, (2 * INTER_) / 128, NE9_), 256, 0, stream>>>(
        hb16, guwb, nullptr, gu, nullptr, cnt, offb, idxl, nullptr,
        T_, 2 * INTER_, H_, H_, (long)(2 * INTER_) * H_);
    silugu_k<<<(3 * T_ * 96) / 256, 256, 0, stream>>>(gu, actm);
    cvt_k<<<(NEXP_ * H_ * INTER_) / 2048, 256, 0, stream>>>(dwn, dwnb, (long)NEXP_ * H_ * INTER_);
    cvt_k<<<(H_ * INTER_) / 2048, 256, 0, stream>>>(sdw, dwnb + (long)NEXP_ * H_ * INTER_, (long)H_ * INTER_);
    gemm2<2><<<dim3(T_ / 128, H_ / 128, NE9_), 256, 0, stream>>>(
        actm, dwnb, out, nullptr, nullptr, cnt, offb, idxl, wl,
        T_, H_, INTER_, INTER_, (long)H_ * INTER_);
}

// Round 9
// 534.392 us; speedup vs baseline: 4.7835x; 1.1238x over previous
//
#include <hip/hip_runtime.h>

typedef float f4 __attribute__((ext_vector_type(4)));
typedef float f32x4 __attribute__((ext_vector_type(4)));
typedef unsigned short us8 __attribute__((ext_vector_type(8)));
typedef __bf16 bf8 __attribute__((ext_vector_type(8)));

static constexpr int B_ = 2, S_ = 1024, H_ = 2048, T_ = B_ * S_;
static constexpr int NH_ = 16, DN_ = 128, DR_ = 64, DV_ = 128, DQK_ = 192;
static constexpr int KVL_ = 512, QL_ = 1536, INTER_ = 768, NEXP_ = 8, NE9_ = 9;
static constexpr int QKA_ = 2176;  // 1536 (q_a) + 576 (kv_a) + 64 pad
static constexpr float SCALING_ = 0.07216878364870322f; // 192^-0.5
static constexpr float EPS_ = 1e-6f;

__device__ __forceinline__ unsigned short f2bf(float f) {
    unsigned u = __float_as_uint(f);
    u += 0x7fffu + ((u >> 16) & 1u);
    return (unsigned short)(u >> 16);
}
__device__ __forceinline__ float bf2f(unsigned short h) {
    return __uint_as_float(((unsigned)h) << 16);
}
__device__ __forceinline__ us8 pack8(f4 a, f4 b) {
    us8 r;
    r[0] = f2bf(a[0]); r[1] = f2bf(a[1]); r[2] = f2bf(a[2]); r[3] = f2bf(a[3]);
    r[4] = f2bf(b[0]); r[5] = f2bf(b[1]); r[6] = f2bf(b[2]); r[7] = f2bf(b[3]);
    return r;
}

// async 16B/lane global->LDS. LDS dest = wave-uniform base + lane*16 (HW).
__device__ __forceinline__ void gload16(const unsigned short* g, unsigned short* lds) {
    __builtin_amdgcn_global_load_lds(
        (const __attribute__((address_space(1))) void*)g,
        (__attribute__((address_space(3))) void*)lds, 16, 0, 0);
}

// ---------------------------------------------------------------------------
// gemm2: C[M,N] = A[M,K] * B[N,K]^T, bf16 in, 128x128 tile, BK=64.
// 2-buffer depth-1 counted pipeline: per K-step
//   stage(t+1) -> waitcnt vmcnt(8) -> s_barrier -> compute(t) -> s_barrier
// (next tile's 8 loads stay in flight across compute).
// LDS tile is [128][64] elements, chunk-XOR swizzled via pre-swizzled GLOBAL
// source (LDS[R][c] = G[R][c ^ (R&7)], chunks of 8 elems) so fragment reads
// are bank-balanced 2-way. T1 XCD swizzle; T5 setprio.
// MODE 0: plain. Cb -> bf16; else Cf (+add) fp32.
// MODE 1: MoE gate+up: A rows gathered via idxl[e], C bf16 compacted at off[e].
// MODE 2: MoE down: A rows compacted at off[e], atomic scatter out[tok] += w*acc.
// ---------------------------------------------------------------------------
template <int MODE>
__global__ __launch_bounds__(256) void gemm2(
    const unsigned short* __restrict__ A, const unsigned short* __restrict__ Bw,
    float* __restrict__ Cf, unsigned short* __restrict__ Cb,
    const float* __restrict__ add,
    const int* __restrict__ cnt, const int* __restrict__ off,
    const int* __restrict__ idxl, const float* __restrict__ wl,
    int M, int N, int K, int ldA, long sB)
{
    constexpr int BM = 128, BN = 128, BK = 64;
    __shared__ __align__(16) unsigned short As[2][BM * BK];
    __shared__ __align__(16) unsigned short Bs[2][BN * BK];
    const int tid = threadIdx.x, lane = tid & 63, wv = tid >> 6;
    const int wm = (wv >> 1) * 64, wn = (wv & 1) * 64;

    // T1: XCD-chunked bijective swizzle (all call sites: gridDim.x=16 -> nb%8==0)
    const int nb = gridDim.x * gridDim.y;
    const int lin = blockIdx.y * gridDim.x + blockIdx.x;
    const int swz = (lin & 7) * (nb >> 3) + (lin >> 3);
    const int bx = swz % gridDim.x;
    const int by = swz / gridDim.x;
    const int m0 = bx * BM, n0 = by * BN;

    int mcnt = M, obase = 0;
    if constexpr (MODE != 0) {
        mcnt = cnt[blockIdx.z];
        if (m0 >= mcnt) return;
        obase = off[blockIdx.z];
    }

    // staging: per site s (32 rows), thread t covers row s*32 + (t>>3),
    // LDS chunk (t&7); global source chunk = (t&7) ^ ((t>>3)&7)  [swizzle]
    const int srow = tid >> 3;                       // 0..31 within site
    const int scol = (((tid & 7) ^ (srow & 7)) * 8); // pre-swizzled global col
    long aoff[4], boff[4];
#pragma unroll
    for (int s = 0; s < 4; s++) {
        int r = m0 + s * 32 + srow;
        if constexpr (MODE == 1) {
            int rc = (r < mcnt) ? r : mcnt - 1;
            aoff[s] = (long)idxl[(long)blockIdx.z * T_ + rc] * ldA + scol;
        } else if constexpr (MODE == 2) {
            aoff[s] = (long)(obase + r) * ldA + scol;
        } else {
            aoff[s] = (long)r * ldA + scol;
        }
        boff[s] = (long)blockIdx.z * sB + (long)(n0 + s * 32 + srow) * K + scol;
    }

    f32x4 acc[4][4];
#pragma unroll
    for (int m = 0; m < 4; m++)
#pragma unroll
        for (int n = 0; n < 4; n++) acc[m][n] = f32x4{0.f, 0.f, 0.f, 0.f};

    const int fr = lane & 15, lg = lane >> 4;
    const int xr = fr & 7;   // read-side XOR (R&7 == fr&7 for all frag rows)

    auto stage = [&](int buf, int k0) {
#pragma unroll
        for (int s = 0; s < 4; s++)
            gload16(A + aoff[s] + k0, &As[buf][s * 2048 + wv * 512]);
#pragma unroll
        for (int s = 0; s < 4; s++)
            gload16(Bw + boff[s] + k0, &Bs[buf][s * 2048 + wv * 512]);
    };
    auto compute = [&](int buf) {
        __builtin_amdgcn_s_setprio(1);
        bf8 af[4][2], bfv[4][2];
#pragma unroll
        for (int m = 0; m < 4; m++) {
            int R = wm + m * 16 + fr;
#pragma unroll
            for (int ks = 0; ks < 2; ks++)
                af[m][ks] = *(const bf8*)&As[buf][R * 64 + ((ks * 4 + lg) ^ xr) * 8];
        }
#pragma unroll
        for (int n = 0; n < 4; n++) {
            int R = wn + n * 16 + fr;
#pragma unroll
            for (int ks = 0; ks < 2; ks++)
                bfv[n][ks] = *(const bf8*)&Bs[buf][R * 64 + ((ks * 4 + lg) ^ xr) * 8];
        }
#pragma unroll
        for (int m = 0; m < 4; m++)
#pragma unroll
            for (int n = 0; n < 4; n++) {
                acc[m][n] = __builtin_amdgcn_mfma_f32_16x16x32_bf16(af[m][0], bfv[n][0], acc[m][n], 0, 0, 0);
                acc[m][n] = __builtin_amdgcn_mfma_f32_16x16x32_bf16(af[m][1], bfv[n][1], acc[m][n], 0, 0, 0);
            }
        __builtin_amdgcn_s_setprio(0);
    };

    const int nt = K / BK;     // >= 8 at every call site
    stage(0, 0);
    for (int t = 0; t < nt; t++) {
        if (t + 1 < nt) {
            stage((t & 1) ^ 1, (t + 1) * BK);   // issue next tile (8 loads/wave)
            asm volatile("s_waitcnt vmcnt(8)" ::: "memory");  // tile t landed
        } else {
            asm volatile("s_waitcnt vmcnt(0)" ::: "memory");
        }
        __builtin_amdgcn_s_barrier();
        compute(t & 1);
        __builtin_amdgcn_s_barrier();          // all reads of buf done before restage
    }

#pragma unroll
    for (int m = 0; m < 4; m++) {
#pragma unroll
        for (int n = 0; n < 4; n++) {
#pragma unroll
            for (int i = 0; i < 4; i++) {
                int row = wm + m * 16 + (lane >> 4) * 4 + i;   // local row
                int col = n0 + wn + n * 16 + (lane & 15);
                float v = acc[m][n][i];
                if constexpr (MODE == 0) {
                    long idx = (long)(m0 + row) * N + col;
                    if (Cb)       Cb[idx] = f2bf(v);
                    else if (add) Cf[idx] = v + add[idx];
                    else          Cf[idx] = v;
                } else if constexpr (MODE == 1) {
                    if (m0 + row < mcnt)
                        Cb[(long)(obase + m0 + row) * N + col] = f2bf(v);
                } else {
                    if (m0 + row < mcnt) {
                        int e = blockIdx.z;
                        int tok = idxl[(long)e * T_ + m0 + row];
                        float w = wl[(long)e * T_ + m0 + row];
                        atomicAdd(&Cf[(long)tok * N + col], w * v);
                    }
                }
            }
        }
    }
}

// ---------------------------------------------------------------------------
// Flash attention (causal). grid (S/64, B*NH), 256 threads (4 waves).
// ---------------------------------------------------------------------------
__global__ __launch_bounds__(256) void fa_k(
    const unsigned short* __restrict__ qs, const unsigned short* __restrict__ ks,
    const unsigned short* __restrict__ vt, unsigned short* __restrict__ ab)
{
    constexpr int KB = 64;
    const int q0 = blockIdx.x * 64;
    const int bh = blockIdx.y;
    const int b = bh >> 4, h = bh & 15;
    const int tid = threadIdx.x, lane = tid & 63, wv = tid >> 6;
    const int fr = lane & 15, lg = lane >> 4;
    const int ko = lg * 8;

    __shared__ __align__(16) unsigned short Kl[KB][200];
    __shared__ __align__(16) unsigned short Vl[128][72];
    __shared__ __align__(16) unsigned short Pl[4][16][72];

    const unsigned short* qp = qs + ((long)bh * S_ + q0 + wv * 16 + fr) * DQK_ + ko;
    bf8 qf[6];
#pragma unroll
    for (int s = 0; s < 6; s++) qf[s] = *(const bf8*)(qp + s * 32);

    f32x4 o[8];
#pragma unroll
    for (int n = 0; n < 8; n++) o[n] = f32x4{0.f, 0.f, 0.f, 0.f};
    float mrow[4] = {-3e38f, -3e38f, -3e38f, -3e38f};
    float lrow[4] = {0.f, 0.f, 0.f, 0.f};

    const int nt = q0 / KB + 1;

    const unsigned short* kg = ks + ((long)bh * S_ + (tid >> 2)) * DQK_ + (tid & 3) * 48;
    const unsigned short* vg = vt + ((long)bh * DV_ + (tid >> 1)) * S_ + (tid & 1) * 32;

    us8 krg[6], vrg[4];
#pragma unroll
    for (int j = 0; j < 6; j++) krg[j] = *(const us8*)(kg + j * 8);
#pragma unroll
    for (int j = 0; j < 4; j++) vrg[j] = *(const us8*)(vg + j * 8);

    for (int t = 0; t < nt; t++) {
        __syncthreads();
        {
            int r = tid >> 2, c = (tid & 3) * 48;
#pragma unroll
            for (int j = 0; j < 6; j++) *(us8*)&Kl[r][c + j * 8] = krg[j];
            int dv = tid >> 1, c2 = (tid & 1) * 32;
#pragma unroll
            for (int j = 0; j < 4; j++) *(us8*)&Vl[dv][c2 + j * 8] = vrg[j];
        }
        __syncthreads();
        if (t + 1 < nt) {
            long kof = (long)(t + 1) * KB;
#pragma unroll
            for (int j = 0; j < 6; j++) krg[j] = *(const us8*)(kg + kof * DQK_ + j * 8);
#pragma unroll
            for (int j = 0; j < 4; j++) vrg[j] = *(const us8*)(vg + kof + j * 8);
        }
        f32x4 ps[4];
#pragma unroll
        for (int ct = 0; ct < 4; ct++) {
            f32x4 a = f32x4{0.f, 0.f, 0.f, 0.f};
#pragma unroll
            for (int s = 0; s < 6; s++) {
                bf8 kf = *(const bf8*)&Kl[ct * 16 + fr][s * 32 + ko];
                a = __builtin_amdgcn_mfma_f32_16x16x32_bf16(qf[s], kf, a, 0, 0, 0);
            }
            ps[ct] = a;
        }
        const int kv0 = t * KB;
        const bool diag = (kv0 == q0);
#pragma unroll
        for (int ct = 0; ct < 4; ct++)
#pragma unroll
            for (int i = 0; i < 4; i++) {
                float v = ps[ct][i] * SCALING_;
                if (diag && (kv0 + ct * 16 + fr) > (q0 + wv * 16 + lg * 4 + i)) v = -3e38f;
                ps[ct][i] = v;
            }
        float scl[4];
#pragma unroll
        for (int i = 0; i < 4; i++) {
            float v = fmaxf(fmaxf(ps[0][i], ps[1][i]), fmaxf(ps[2][i], ps[3][i]));
#pragma unroll
            for (int x = 8; x; x >>= 1) v = fmaxf(v, __shfl_xor(v, x, 16));
            float mn = fmaxf(mrow[i], v);
            scl[i] = __expf(mrow[i] - mn);
            mrow[i] = mn;
        }
        float tsum[4] = {0.f, 0.f, 0.f, 0.f};
#pragma unroll
        for (int ct = 0; ct < 4; ct++)
#pragma unroll
            for (int i = 0; i < 4; i++) {
                float e = __expf(ps[ct][i] - mrow[i]);
                tsum[i] += e;
                Pl[wv][lg * 4 + i][ct * 16 + fr] = f2bf(e);
            }
#pragma unroll
        for (int i = 0; i < 4; i++) {
            float v = tsum[i];
#pragma unroll
            for (int x = 8; x; x >>= 1) v += __shfl_xor(v, x, 16);
            lrow[i] = lrow[i] * scl[i] + v;
        }
#pragma unroll
        for (int n = 0; n < 8; n++)
#pragma unroll
            for (int i = 0; i < 4; i++) o[n][i] *= scl[i];
        bf8 pf[2];
#pragma unroll
        for (int ksl = 0; ksl < 2; ksl++)
            pf[ksl] = *(const bf8*)&Pl[wv][fr][ksl * 32 + ko];
#pragma unroll
        for (int n = 0; n < 8; n++)
#pragma unroll
            for (int ksl = 0; ksl < 2; ksl++) {
                bf8 vf = *(const bf8*)&Vl[n * 16 + fr][ksl * 32 + ko];
                o[n] = __builtin_amdgcn_mfma_f32_16x16x32_bf16(pf[ksl], vf, o[n], 0, 0, 0);
            }
    }
#pragma unroll
    for (int i = 0; i < 4; i++) {
        float inv = 1.f / lrow[i];
        long rbase = ((long)b * S_ + q0 + wv * 16 + lg * 4 + i) * H_ + h * DV_;
#pragma unroll
        for (int n = 0; n < 8; n++)
            ab[rbase + n * 16 + fr] = f2bf(o[n][i] * inv);
    }
}

// ---------------------------------------------------------------------------
// conversion kernels (fp32 -> bf16), 8 elems/thread
// ---------------------------------------------------------------------------
__global__ __launch_bounds__(256) void cvt_k(
    const float* __restrict__ s, unsigned short* __restrict__ d, long n)
{
    long i = ((long)blockIdx.x * 256 + threadIdx.x) * 8;
    if (i < n) {
        f4 a = *(const f4*)(s + i);
        f4 b = *(const f4*)(s + i + 4);
        *(us8*)(d + i) = pack8(a, b);
    }
}

// merged q_a|kv_a weights: rows [0,1536)=qaw, [1536,2112)=kvaw, [2112,2176)=0
__global__ __launch_bounds__(256) void cvt_qka_k(
    const float* __restrict__ qa, const float* __restrict__ kva,
    unsigned short* __restrict__ d)
{
    long i = ((long)blockIdx.x * 256 + threadIdx.x) * 8;   // over 2176*2048
    long row = i >> 11, col = i & 2047;
    us8 o;
    if (row < QL_) {
        const float* s = qa + row * H_ + col;
        o = pack8(*(const f4*)s, *(const f4*)(s + 4));
    } else if (row < QL_ + 576) {
        const float* s = kva + (row - QL_) * H_ + col;
        o = pack8(*(const f4*)s, *(const f4*)(s + 4));
    } else {
        o = us8{0, 0, 0, 0, 0, 0, 0, 0};
    }
    *(us8*)(d + i) = o;
}

// 9-expert gate|up concat: z<8 routed (gw/uw), z==8 shared (sgw/suw)
__global__ __launch_bounds__(256) void cvt_cat9_k(
    const float* __restrict__ g, const float* __restrict__ u,
    const float* __restrict__ sg, const float* __restrict__ su,
    unsigned short* __restrict__ d)
{
    long ii = ((long)blockIdx.x * 256 + threadIdx.x) * 8;   // 1536*2048 per expert
    int e = blockIdx.y;
    long row = ii >> 11, col = ii & 2047;
    const float* src;
    if (row < INTER_)
        src = (e < 8) ? (g + ((long)e * INTER_ + row) * H_ + col) : (sg + row * H_ + col);
    else
        src = (e < 8) ? (u + ((long)e * INTER_ + row - INTER_) * H_ + col)
                      : (su + (row - INTER_) * H_ + col);
    *(us8*)(d + (long)e * (2 * INTER_) * H_ + ii) = pack8(*(const f4*)src, *(const f4*)(src + 4));
}

// ---------------------------------------------------------------------------
// rmsnorm fp32->bf16 (+ optional fp32 copy); cols == H_ == 2048 (8/thread)
__global__ __launch_bounds__(256) void rmsnorm_f2b(
    const float* __restrict__ in, const float* __restrict__ w,
    unsigned short* __restrict__ ob, float* __restrict__ of)
{
    const long base = (long)blockIdx.x * H_;
    const int c = threadIdx.x * 8;
    f4 v0 = *(const f4*)(in + base + c);
    f4 v1 = *(const f4*)(in + base + c + 4);
    float ss = v0[0] * v0[0] + v0[1] * v0[1] + v0[2] * v0[2] + v0[3] * v0[3]
             + v1[0] * v1[0] + v1[1] * v1[1] + v1[2] * v1[2] + v1[3] * v1[3];
#pragma unroll
    for (int o = 32; o; o >>= 1) ss += __shfl_down(ss, o);
    __shared__ float red[4];
    if ((threadIdx.x & 63) == 0) red[threadIdx.x >> 6] = ss;
    __syncthreads();
    float r = rsqrtf((red[0] + red[1] + red[2] + red[3]) / H_ + EPS_);
    f4 w0 = *(const f4*)(w + c);
    f4 w1 = *(const f4*)(w + c + 4);
    f4 a, b;
#pragma unroll
    for (int j = 0; j < 4; j++) { a[j] = v0[j] * r * w0[j]; b[j] = v1[j] * r * w1[j]; }
    *(us8*)(ob + base + c) = pack8(a, b);
    if (of) {
        *(f4*)(of + base + c) = a;
        *(f4*)(of + base + c + 4) = b;
    }
}

// bf16 in (istride) -> bf16 out (ostride); in==out safe (per-thread RBW)
__global__ __launch_bounds__(256) void rmsnorm_b2b(
    const unsigned short* __restrict__ in, const float* __restrict__ w,
    unsigned short* __restrict__ out, int cols, int istride, int ostride)
{
    const long ib = (long)blockIdx.x * istride;
    const long ob = (long)blockIdx.x * ostride;
    const int nu = cols >> 3;
    float ss = 0.f;
    for (int u = threadIdx.x; u < nu; u += 256) {
        us8 v = *(const us8*)(in + ib + u * 8);
#pragma unroll
        for (int j = 0; j < 8; j++) { float f = bf2f(v[j]); ss += f * f; }
    }
#pragma unroll
    for (int o = 32; o; o >>= 1) ss += __shfl_down(ss, o);
    __shared__ float red[4];
    if ((threadIdx.x & 63) == 0) red[threadIdx.x >> 6] = ss;
    __syncthreads();
    float r = rsqrtf((red[0] + red[1] + red[2] + red[3]) / cols + EPS_);
    for (int u = threadIdx.x; u < nu; u += 256) {
        us8 v = *(const us8*)(in + ib + u * 8);
        f4 w0 = *(const f4*)(w + u * 8);
        f4 w1 = *(const f4*)(w + u * 8 + 4);
        us8 o;
#pragma unroll
        for (int j = 0; j < 4; j++) o[j] = f2bf(bf2f(v[j]) * r * w0[j]);
#pragma unroll
        for (int j = 0; j < 4; j++) o[4 + j] = f2bf(bf2f(v[4 + j]) * r * w1[j]);
        *(us8*)(out + ob + u * 8) = o;
    }
}

// ---------------------------------------------------------------------------
__global__ __launch_bounds__(64) void rope_q_k(
    const unsigned short* __restrict__ q, const float* __restrict__ cs,
    const float* __restrict__ sn, unsigned short* __restrict__ qs)
{
    int t = blockIdx.x;            // (b*S+s)*16 + h
    int h = t & 15;
    int bs = t >> 4;
    int s = bs & (S_ - 1);
    int b = bs >> 10;
    const unsigned short* qrow = q + (long)bs * (NH_ * DQK_) + h * DQK_;
    unsigned short* orow = qs + ((long)(b * NH_ + h) * S_ + s) * DQK_;
    int l = threadIdx.x;
    orow[l] = qrow[l];
    orow[l + 64] = qrow[l + 64];
    int j = l & 31;
    float x0 = bf2f(qrow[DN_ + 2 * j]), x1 = bf2f(qrow[DN_ + 2 * j + 1]);
    float c = cs[(long)bs * DR_ + j], si = sn[(long)bs * DR_ + j];
    if (l < 32) orow[DN_ + j] = f2bf(x0 * c - x1 * si);
    else        orow[DN_ + 32 + j] = f2bf(x1 * c + x0 * si);
}

// k_rot lives in qkab cols [QL_+512, QL_+576), row stride QKA_
__global__ __launch_bounds__(64) void rope_k_k(
    const unsigned short* __restrict__ qkab, const float* __restrict__ cs,
    const float* __restrict__ sn, unsigned short* __restrict__ ks)
{
    int bs = blockIdx.x;
    int s = bs & (S_ - 1);
    int b = bs >> 10;
    const unsigned short* kr = qkab + (long)bs * QKA_ + QL_ + KVL_;
    int l = threadIdx.x;
    int j = l & 31;
    float x0 = bf2f(kr[2 * j]), x1 = bf2f(kr[2 * j + 1]);
    float c = cs[(long)bs * DR_ + j], si = sn[(long)bs * DR_ + j];
    float val = (l < 32) ? (x0 * c - x1 * si) : (x1 * c + x0 * si);
    int off = (l < 32) ? (DN_ + j) : (DN_ + 32 + j);
    unsigned short bv = f2bf(val);
    for (int h = 0; h < NH_; h++)
        ks[((long)(b * NH_ + h) * S_ + s) * DQK_ + off] = bv;
}

__global__ __launch_bounds__(128) void kpass_k(
    const unsigned short* __restrict__ kv, unsigned short* __restrict__ ks)
{
    int t = blockIdx.x; // (b*S+s)*16 + h
    int h = t & 15;
    int bs = t >> 4;
    int s = bs & (S_ - 1);
    int b = bs >> 10;
    ks[((long)(b * NH_ + h) * S_ + s) * DQK_ + threadIdx.x] = kv[(long)t * 256 + threadIdx.x];
}

// V transpose: kv (B,S,NH,256)[:,128:] -> vt (B,NH,128,S), vectorized
__global__ __launch_bounds__(256) void vt_k(
    const unsigned short* __restrict__ kv, unsigned short* __restrict__ vt)
{
    __shared__ unsigned short tile[64][DV_ + 8];
    int s0 = blockIdx.x * 64;
    int bh = blockIdx.y;
    int b = bh >> 4, h = bh & 15;
#pragma unroll
    for (int it = 0; it < 4; it++) {
        int idx = it * 256 + threadIdx.x;          // 1024 us8 units: 64 rows x 16
        int sl = idx >> 4, du = idx & 15;
        *(us8*)&tile[sl][du * 8] =
            *(const us8*)(kv + ((long)(b * S_ + s0 + sl) * NH_ + h) * 256 + DN_ + du * 8);
    }
    __syncthreads();
#pragma unroll
    for (int it = 0; it < 4; it++) {
        int idx = it * 256 + threadIdx.x;          // 1024 units: 128 d x 8 s-chunks
        int d = idx >> 3, su = idx & 7;
        us8 o;
#pragma unroll
        for (int j = 0; j < 8; j++) o[j] = tile[su * 8 + j][d];
        *(us8*)(vt + ((long)bh * DV_ + d) * S_ + s0 + su * 8) = o;
    }
}

__global__ void zero9_k(int* __restrict__ cnt)
{
    if (threadIdx.x < NE9_) cnt[threadIdx.x] = (threadIdx.x == 8) ? T_ : 0;
}

__global__ void offs_k(const int* __restrict__ cnt, int* __restrict__ off)
{
    if (threadIdx.x == 0) {
        int a = 0;
        for (int e = 0; e < NE9_; e++) { off[e] = a; a += cnt[e]; }
    }
}

// router: top-2-of-grouped-8 scatter + identity entry for shared expert (e=8)
__global__ __launch_bounds__(64) void router_k(
    const float* __restrict__ h, const float* __restrict__ rw,
    const float* __restrict__ rb, int* __restrict__ cnt,
    int* __restrict__ idxl, float* __restrict__ wl)
{
    int t = blockIdx.x;
    int l = threadIdx.x;
    const float* hr = h + (long)t * H_;
    float pe[8] = {0, 0, 0, 0, 0, 0, 0, 0};
    for (int k = l; k < H_; k += 64) {
        float hv = hr[k];
#pragma unroll
        for (int e = 0; e < 8; e++) pe[e] += hv * rw[e * H_ + k];
    }
#pragma unroll
    for (int e = 0; e < 8; e++)
        for (int o = 32; o; o >>= 1) pe[e] += __shfl_down(pe[e], o);
    if (l == 0) {
        float sr[8], sc[8];
#pragma unroll
        for (int e = 0; e < 8; e++) {
            sr[e] = 1.f / (1.f + __expf(-pe[e]));
            sc[e] = sr[e] + rb[e];
        }
        float gs[4];
        for (int g = 0; g < 4; g++) gs[g] = sc[2 * g] + sc[2 * g + 1];
        int g0 = 0;
        for (int g = 1; g < 4; g++) if (gs[g] > gs[g0]) g0 = g;
        int g1 = -1;
        for (int g = 0; g < 4; g++) {
            if (g == g0) continue;
            if (g1 < 0 || gs[g] > gs[g1]) g1 = g;
        }
        int i0 = -1, i1 = -1;
        for (int e = 0; e < 8; e++) {
            int g = e >> 1;
            if (g != g0 && g != g1) continue;
            if (i0 < 0 || sc[e] > sc[i0]) i0 = e;
        }
        for (int e = 0; e < 8; e++) {
            int g = e >> 1;
            if (g != g0 && g != g1) continue;
            if (e == i0) continue;
            if (i1 < 0 || sc[e] > sc[i1]) i1 = e;
        }
        float w0 = sr[i0], w1 = sr[i1];
        float inv = 2.5f / (w0 + w1 + 1e-20f);
        int p0 = atomicAdd(&cnt[i0], 1);
        idxl[i0 * T_ + p0] = t;
        wl[i0 * T_ + p0] = w0 * inv;
        int p1 = atomicAdd(&cnt[i1], 1);
        idxl[i1 * T_ + p1] = t;
        wl[i1 * T_ + p1] = w1 * inv;
        idxl[8 * T_ + t] = t;      // shared expert: identity list, weight 1
        wl[8 * T_ + t] = 1.0f;
    }
}

// act[r][c] = silu(gu[r][c]) * gu[r][768+c]; vectorized us8, linear grid
// rows = 6144; 96 us8-units per row; grid = 6144*96/256 = 2304
__global__ __launch_bounds__(256) void silugu_k(
    const unsigned short* __restrict__ gu, unsigned short* __restrict__ act)
{
    long idx = (long)blockIdx.x * 256 + threadIdx.x;
    int r = (int)(idx / 96);
    int c = (int)(idx - (long)r * 96) * 8;
    us8 g8 = *(const us8*)(gu + (long)r * (2 * INTER_) + c);
    us8 u8 = *(const us8*)(gu + (long)r * (2 * INTER_) + INTER_ + c);
    us8 o;
#pragma unroll
    for (int j = 0; j < 8; j++) {
        float g = bf2f(g8[j]);
        o[j] = f2bf(g / (1.f + __expf(-g)) * bf2f(u8[j]));
    }
    *(us8*)(act + (long)r * INTER_ + c) = o;
}

// ---------------------------------------------------------------------------
extern "C" void kernel_launch(void* const* d_in, const int* in_sizes, int n_in,
                              void* d_out, int out_size, void* d_ws, size_t ws_size,
                              hipStream_t stream)
{
    const float* hidden = (const float*)d_in[0];
    const float* cosb   = (const float*)d_in[1];
    const float* sinb   = (const float*)d_in[2];
    const float* ln1w   = (const float*)d_in[3];
    const float* qaw    = (const float*)d_in[4];
    const float* qalnw  = (const float*)d_in[5];
    const float* qbw    = (const float*)d_in[6];
    const float* kvaw   = (const float*)d_in[7];
    const float* kvalnw = (const float*)d_in[8];
    const float* kvbw   = (const float*)d_in[9];
    const float* ow     = (const float*)d_in[10];
    const float* ln2w   = (const float*)d_in[11];
    const float* rw     = (const float*)d_in[12];
    const float* rb     = (const float*)d_in[13];
    const float* gw     = (const float*)d_in[14];
    const float* uw     = (const float*)d_in[15];
    const float* dwn    = (const float*)d_in[16];
    const float* sgw    = (const float*)d_in[17];
    const float* suw    = (const float*)d_in[18];
    const float* sdw    = (const float*)d_in[19];
    float* out = (float*)d_out;
    (void)in_sizes; (void)n_in; (void)out_size; (void)ws_size;

    char* ws = (char*)d_ws;
    const size_t MB = 1u << 20;
    // ---- phase A (attention), MiB offsets, peak ~101 ----
    unsigned short* qkawb = (unsigned short*)(ws + 0 * MB);   // 8.5 (2176x2048)
    unsigned short* qbwb  = (unsigned short*)(ws + 9 * MB);   // 9
    unsigned short* kvbwb = (unsigned short*)(ws + 18 * MB);  // 4
    unsigned short* owb   = (unsigned short*)(ws + 22 * MB);  // 8
    unsigned short* xb    = (unsigned short*)(ws + 30 * MB);  // 8
    unsigned short* qkab  = (unsigned short*)(ws + 38 * MB);  // 8.5 (T x 2176)
    unsigned short* qb16  = (unsigned short*)(ws + 47 * MB);  // 12
    unsigned short* ckvnb = (unsigned short*)(ws + 59 * MB);  // 2
    unsigned short* kvb   = (unsigned short*)(ws + 61 * MB);  // 16
    unsigned short* qs    = (unsigned short*)(ws + 77 * MB);  // 12
    unsigned short* ks    = (unsigned short*)(ws + 89 * MB);  // 12
    unsigned short* vt    = (unsigned short*)(ws + 30 * MB);  // 8  (alias xb)
    unsigned short* ab    = (unsigned short*)(ws + 38 * MB);  // 8  (alias qkab, dead by FA)
    // ---- phase B (MoE), peak ~98 ----
    float* hbuf = (float*)(ws + 0 * MB);                      // 16 (dead after router)
    unsigned short* actm = (unsigned short*)(ws + 0 * MB);    // 9.4 (6144x768, after router)
    unsigned short* hb16 = (unsigned short*)(ws + 16 * MB);   // 8
    int*   cnt  = (int*)(ws + 24 * MB);
    int*   offb = (int*)(ws + 24 * MB + 256);
    int*   idxl = (int*)(ws + 24 * MB + 512);                 // 72 KB (9 x T)
    float* wl   = (float*)(ws + 24 * MB + 512 + 9 * T_ * 4);  // 72 KB
    unsigned short* guwb = (unsigned short*)(ws + 25 * MB);   // 54 (9x1536x2048)
    unsigned short* dwnb = (unsigned short*)(ws + 25 * MB);   // 27 (alias guwb, after gu GEMM)
    unsigned short* gu   = (unsigned short*)(ws + 79 * MB);   // 18.9 (6144x1536)

    // ---- weight conversion (attention) ----
    cvt_qka_k<<<(QKA_ * H_) / 2048, 256, 0, stream>>>(qaw, kvaw, qkawb);
    cvt_k<<<(NH_ * DQK_ * QL_) / 2048, 256, 0, stream>>>(qbw, qbwb, (long)NH_ * DQK_ * QL_);
    cvt_k<<<(NH_ * 256 * KVL_) / 2048, 256, 0, stream>>>(kvbw, kvbwb, (long)NH_ * 256 * KVL_);
    cvt_k<<<(H_ * H_) / 2048, 256, 0, stream>>>(ow, owb, (long)H_ * H_);

    // ---- attention projections ----
    rmsnorm_f2b<<<T_, 256, 0, stream>>>(hidden, ln1w, xb, nullptr);

    // merged q_a | kv_a projection: qkab = xb @ qkawb^T  (N=2176)
    gemm2<0><<<dim3(T_ / 128, QKA_ / 128, 1), 256, 0, stream>>>(
        xb, qkawb, nullptr, qkab, nullptr, nullptr, nullptr, nullptr, nullptr,
        T_, QKA_, H_, H_, 0);
    rmsnorm_b2b<<<T_, 256, 0, stream>>>(qkab, qalnw, qkab, QL_, QKA_, QKA_);       // q_a norm in-place
    gemm2<0><<<dim3(T_ / 128, (NH_ * DQK_) / 128, 1), 256, 0, stream>>>(
        qkab, qbwb, nullptr, qb16, nullptr, nullptr, nullptr, nullptr, nullptr,
        T_, NH_ * DQK_, QL_, QKA_, 0);
    rmsnorm_b2b<<<T_, 256, 0, stream>>>(qkab + QL_, kvalnw, ckvnb, KVL_, QKA_, KVL_); // kv_a norm
    gemm2<0><<<dim3(T_ / 128, (NH_ * 256) / 128, 1), 256, 0, stream>>>(
        ckvnb, kvbwb, nullptr, kvb, nullptr, nullptr, nullptr, nullptr, nullptr,
        T_, NH_ * 256, KVL_, KVL_, 0);

    // ---- assemble qs / ks / vt ----
    rope_q_k<<<T_ * NH_, 64, 0, stream>>>(qb16, cosb, sinb, qs);
    rope_k_k<<<T_, 64, 0, stream>>>(qkab, cosb, sinb, ks);
    kpass_k<<<T_ * NH_, 128, 0, stream>>>(kvb, ks);
    vt_k<<<dim3(S_ / 64, B_ * NH_), 256, 0, stream>>>(kvb, vt);

    // ---- flash attention ----
    fa_k<<<dim3(S_ / 64, B_ * NH_), 256, 0, stream>>>(qs, ks, vt, ab);

    // ---- o-proj + residual: out = attn @ ow^T + hidden ----
    gemm2<0><<<dim3(T_ / 128, H_ / 128, 1), 256, 0, stream>>>(
        ab, owb, out, nullptr, hidden, nullptr, nullptr, nullptr, nullptr,
        T_, H_, H_, H_, 0);

    // ---- MoE prep ----
    rmsnorm_f2b<<<T_, 256, 0, stream>>>(out, ln2w, hb16, hbuf);
    zero9_k<<<1, 64, 0, stream>>>(cnt);
    router_k<<<T_, 64, 0, stream>>>(hbuf, rw, rb, cnt, idxl, wl);
    offs_k<<<1, 64, 0, stream>>>(cnt, offb);

    // ---- 9-expert (8 routed + shared) gate+up -> silu -> down+scatter ----
    cvt_cat9_k<<<dim3((2 * INTER_ * H_) / 2048, NE9_), 256, 0, stream>>>(gw, uw, sgw, suw, guwb);
    gemm2<1><<<dim3(T_ / 128, (2 * INTER_) / 128, NE9_), 256, 0, stream>>>(
        hb16, guwb, nullptr, gu, nullptr, cnt, offb, idxl, nullptr,
        T_, 2 * INTER_, H_, H_, (long)(2 * INTER_) * H_);
    silugu_k<<<(3 * T_ * 96) / 256, 256, 0, stream>>>(gu, actm);
    cvt_k<<<(NEXP_ * H_ * INTER_) / 2048, 256, 0, stream>>>(dwn, dwnb, (long)NEXP_ * H_ * INTER_);
    cvt_k<<<(H_ * INTER_) / 2048, 256, 0, stream>>>(sdw, dwnb + (long)NEXP_ * H_ * INTER_, (long)H_ * INTER_);
    gemm2<2><<<dim3(T_ / 128, H_ / 128, NE9_), 256, 0, stream>>>(
        actm, dwnb, out, nullptr, nullptr, cnt, offb, idxl, wl,
        T_, H_, INTER_, INTER_, (long)H_ * INTER_);
}